// Round 1
// baseline (5523.420 us; speedup 1.0000x reference)
//
#include <hip/hip_runtime.h>
#include <hip/hip_bf16.h>

typedef __hip_bfloat16 bf16;

static constexpr int BN = 2;
static constexpr int H0 = 480, W0 = 640;
static constexpr int HW1 = H0 * W0;

__device__ __forceinline__ float cvt(float v) { return v; }
__device__ __forceinline__ float cvt(bf16 v) { return __bfloat162float(v); }

// ---------------- weight transpose: (O,I,3,3) -> [(i*3+ky)*3+kx][o] ----------------
__global__ void wtr_k(const float* __restrict__ w, float* __restrict__ wT, int CINT, int COUT) {
    int gid = blockIdx.x * 256 + threadIdx.x;
    int total = COUT * CINT * 9;
    if (gid >= total) return;
    int o = gid / (CINT * 9);
    int r = gid - o * (CINT * 9);
    wT[r * COUT + o] = w[gid];
}

// ---------------- antialiased "linear" resize (JAX semantics), factor f in {1,2,4} ----------------
// writes into xbuf plane (b*6 + c0 + c)
__global__ void resize_aa_k(const float* __restrict__ in, int Hin, int Win,
                            float* __restrict__ xout, int Hs, int Ws, int f,
                            int C, int c0, int clip01) {
    int gid = blockIdx.x * 256 + threadIdx.x;
    int HWs = Hs * Ws;
    int total = BN * C * HWs;
    if (gid >= total) return;
    int ox = gid % Ws;
    int t1 = gid / Ws;
    int oy = t1 % Hs;
    int t2 = t1 / Hs;
    int c = t2 % C;
    int b = t2 / C;
    const float* ip = in + (size_t)(b * C + c) * Hin * Win;

    float wy[8], wx[8];
    int nt = 2 * f;
    float sy = (oy + 0.5f) * f - 0.5f;
    int jly = f * oy - (f + 1) / 2;
    float wys = 0.f;
    for (int t = 0; t < nt; t++) {
        int j = jly + t;
        float w = 1.f - fabsf(sy - (float)j) / (float)f;
        w = fmaxf(w, 0.f);
        if (j < 0 || j >= Hin) w = 0.f;
        wy[t] = w; wys += w;
    }
    float sx = (ox + 0.5f) * f - 0.5f;
    int jlx = f * ox - (f + 1) / 2;
    float wxs = 0.f;
    for (int t = 0; t < nt; t++) {
        int j = jlx + t;
        float w = 1.f - fabsf(sx - (float)j) / (float)f;
        w = fmaxf(w, 0.f);
        if (j < 0 || j >= Win) w = 0.f;
        wx[t] = w; wxs += w;
    }
    float acc = 0.f;
    for (int ty = 0; ty < nt; ty++) {
        if (wy[ty] == 0.f) continue;
        const float* row = ip + (size_t)(jly + ty) * Win;
        float r = 0.f;
        for (int tx = 0; tx < nt; tx++) {
            if (wx[tx] == 0.f) continue;
            r += wx[tx] * row[jlx + tx];
        }
        acc += wy[ty] * r;
    }
    acc /= (wys * wxs);
    if (clip01) acc = fminf(fmaxf(acc, 0.f), 1.f);
    xout[(size_t)(b * 6 + c0 + c) * HWs + (size_t)oy * Ws + ox] = acc;
}

// ---------------- sparse-depth valid-mean pooling -> xbuf planes 3 (DL) and 4 (ML) ----------------
__global__ void downsp_k(const float* __restrict__ DL, const float* __restrict__ ML,
                         float* __restrict__ xout, int Hs, int Ws, int k) {
    int gid = blockIdx.x * 256 + threadIdx.x;
    int HWs = Hs * Ws;
    if (gid >= BN * HWs) return;
    int ox = gid % Ws;
    int oy = (gid / Ws) % Hs;
    int b = gid / HWs;
    float s = 0.f, c = 0.f;
    for (int dy = 0; dy < k; dy++) {
        for (int dx = 0; dx < k; dx++) {
            size_t idx = ((size_t)b * H0 + (oy * k + dy)) * W0 + (ox * k + dx);
            float m = ML[idx] > 0.f ? 1.f : 0.f;
            s += DL[idx] * m;
            c += m;
        }
    }
    int p = oy * Ws + ox;
    float mls = c > 0.f ? 1.f : 0.f;
    float dls = c > 0.f ? s / (c + 1e-6f) : 0.f;
    xout[(size_t)(b * 6 + 3) * HWs + p] = dls;
    xout[(size_t)(b * 6 + 4) * HWs + p] = mls;
}

// ---------------- D init, first scale: D = clip(E*10, 0, 10) ----------------
__global__ void dinit_first_k(const float* __restrict__ xbuf, float* __restrict__ D0,
                              int Hs, int Ws) {
    int gid = blockIdx.x * 256 + threadIdx.x;
    int HW = Hs * Ws;
    if (gid >= BN * HW) return;
    int b = gid / HW;
    int p = gid - b * HW;
    float e = xbuf[(size_t)(b * 6 + 5) * HW + p];
    D0[gid] = fminf(fmaxf(e * 10.f, 0.f), 10.f);
}

// ---------------- D init, later scales: edge-aware blend of 2x-upsampled prev with P ----------------
__global__ void dinit_blend_k(const float* __restrict__ Dp, const float* __restrict__ xbuf,
                              float* __restrict__ D0, int Hs, int Ws) {
    int gid = blockIdx.x * 256 + threadIdx.x;
    int HW = Hs * Ws;
    if (gid >= BN * HW) return;
    int ox = gid % Ws;
    int oy = (gid / Ws) % Hs;
    int b = gid / HW;
    int hp = Hs / 2, wp = Ws / 2;
    const float* P = Dp + (size_t)b * hp * wp;

    float ty = 0.5f * oy - 0.25f;
    int jy = (int)floorf(ty);
    float fy = ty - jy;
    float wy0 = 1.f - fy, wy1 = fy;
    bool v0 = (jy >= 0) && (jy < hp);
    bool v1 = (jy + 1 >= 0) && (jy + 1 < hp);
    if (!v0) wy0 = 0.f;
    if (!v1) wy1 = 0.f;
    float wys = wy0 + wy1;

    float tx = 0.5f * ox - 0.25f;
    int jx = (int)floorf(tx);
    float fx = tx - jx;
    float wx0 = 1.f - fx, wx1 = fx;
    bool u0 = (jx >= 0) && (jx < wp);
    bool u1 = (jx + 1 >= 0) && (jx + 1 < wp);
    if (!u0) wx0 = 0.f;
    if (!u1) wx1 = 0.f;
    float wxs = wx0 + wx1;

    int jy0c = v0 ? jy : 0, jy1c = v1 ? (jy + 1) : 0;
    int jx0c = u0 ? jx : 0, jx1c = u1 ? (jx + 1) : 0;
    float up = wy0 * (wx0 * P[(size_t)jy0c * wp + jx0c] + wx1 * P[(size_t)jy0c * wp + jx1c])
             + wy1 * (wx0 * P[(size_t)jy1c * wp + jx0c] + wx1 * P[(size_t)jy1c * wp + jx1c]);
    up /= (wys * wxs);

    const float* E = xbuf + (size_t)(b * 6 + 5) * HW;
    float e = E[(size_t)oy * Ws + ox];
    float gx = (ox > 0) ? fabsf(e - E[(size_t)oy * Ws + ox - 1]) : 0.f;
    float gy = (oy > 0) ? fabsf(e - E[(size_t)(oy - 1) * Ws + ox]) : 0.f;
    float g = fminf(fmaxf(0.5f * (gx + gy), 0.f), 1.f);
    float w = 0.7f * fminf(fmaxf(1.f - g * 10.f, 0.f), 1.f);   // BLEND * clip(1-g/tau,0,1)^1
    float Pv = fminf(fmaxf(e * 10.f, 0.f), 10.f);
    D0[gid] = w * up + (1.f - w) * Pv;
}

// ---------------- direct 3x3 SAME conv, epilogue-fused ----------------
// EPI: 1 = relu->bf16 planes; 2 = affinity normalize (out0=A fp32 24ch, out1=center 3ch);
//      3 = softmax3 (out0 fp32 3ch); 4 = kappa sigmoid (out0 fp32 3ch)
template <typename TIN, int CIN, int COUT, bool EXTRA, int EPI>
__global__ __launch_bounds__(256) void conv3x3_k(
        const TIN* __restrict__ in, const float* __restrict__ wT,
        const float* __restrict__ bias, const float* __restrict__ extra, float escale,
        void* __restrict__ out0, float* __restrict__ out1, int H, int W) {
    int gid = blockIdx.x * 256 + threadIdx.x;
    int HW = H * W;
    if (gid >= BN * HW) return;
    int b = gid / HW;
    int p = gid - b * HW;
    int y = p / W;
    int x = p - y * W;

    float acc[COUT];
#pragma unroll
    for (int o = 0; o < COUT; o++) acc[o] = bias[o];

    const TIN* inb = in + (size_t)b * CIN * HW;
    for (int i = 0; i < CIN; i++) {
        const TIN* ic = inb + (size_t)i * HW;
#pragma unroll
        for (int ky = 0; ky < 3; ky++) {
            int yy = y + ky - 1;
            if ((unsigned)yy >= (unsigned)H) continue;
            const TIN* irow = ic + (size_t)yy * W;
            const float* wr = wT + (size_t)((i * 3 + ky) * 3) * COUT;
#pragma unroll
            for (int kx = 0; kx < 3; kx++) {
                int xx = x + kx - 1;
                float v = ((unsigned)xx < (unsigned)W) ? cvt(irow[xx]) : 0.f;
                const float* wro = wr + kx * COUT;
#pragma unroll
                for (int o = 0; o < COUT; o++) acc[o] = fmaf(v, wro[o], acc[o]);
            }
        }
    }
    if (EXTRA) {
        const float* eb = extra + (size_t)b * HW;
#pragma unroll
        for (int ky = 0; ky < 3; ky++) {
            int yy = y + ky - 1;
            if ((unsigned)yy >= (unsigned)H) continue;
#pragma unroll
            for (int kx = 0; kx < 3; kx++) {
                int xx = x + kx - 1;
                float v = ((unsigned)xx < (unsigned)W) ? eb[(size_t)yy * W + xx] * escale : 0.f;
                const float* wro = wT + (size_t)((CIN * 3 + ky) * 3 + kx) * COUT;
#pragma unroll
                for (int o = 0; o < COUT; o++) acc[o] = fmaf(v, wro[o], acc[o]);
            }
        }
    }

    if (EPI == 1) {
        bf16* out = (bf16*)out0;
#pragma unroll
        for (int o = 0; o < COUT; o++)
            out[(size_t)(b * COUT + o) * HW + p] = __float2bfloat16(fmaxf(acc[o], 0.f));
    } else if (EPI == 2) {
        float* A = (float*)out0;
#pragma unroll
        for (int k = 0; k < 3; k++) {
            float sa = 1e-6f;
#pragma unroll
            for (int j = 0; j < 8; j++) sa += fabsf(acc[k * 8 + j]);
            float csum = 0.f;
#pragma unroll
            for (int j = 0; j < 8; j++) {
                float a = acc[k * 8 + j] / sa;
                A[(size_t)(b * 24 + k * 8 + j) * HW + p] = a;
                csum += a;
            }
            out1[(size_t)(b * 3 + k) * HW + p] = 1.f - csum;
        }
    } else if (EPI == 3) {
        float* S = (float*)out0;
        float m = fmaxf(acc[0], fmaxf(acc[1], acc[2]));
        float e0 = expf(acc[0] - m), e1 = expf(acc[1] - m), e2 = expf(acc[2] - m);
        float is = 1.f / (e0 + e1 + e2);
        S[(size_t)(b * 3 + 0) * HW + p] = e0 * is;
        S[(size_t)(b * 3 + 1) * HW + p] = e1 * is;
        S[(size_t)(b * 3 + 2) * HW + p] = e2 * is;
    } else if (EPI == 4) {
        float* Kp = (float*)out0;
#pragma unroll
        for (int k = 0; k < 3; k++) {
            float sg = 1.f / (1.f + expf(-acc[k]));
            Kp[(size_t)(b * 3 + k) * HW + p] = 0.1f + 0.9f * sg;
        }
    }
}

// ---------------- one CSPN propagation step ----------------
__global__ __launch_bounds__(256) void prop_k(const float* __restrict__ D,
        const float* __restrict__ A, const float* __restrict__ cen,
        const float* __restrict__ sig, const float* __restrict__ kap,
        const float* __restrict__ xbuf, float* __restrict__ Dn, int Hs, int Ws) {
    int gid = blockIdx.x * 256 + threadIdx.x;
    int HW = Hs * Ws;
    if (gid >= BN * HW) return;
    int b = gid / HW;
    int p = gid - b * HW;
    int y = p / Ws;
    int x = p - y * Ws;
    const float* Db = D + (size_t)b * HW;
    float Dc = Db[p];
    const int dy_[8] = {-1, -1, -1, 0, 0, 1, 1, 1};
    const int dx_[8] = {-1, 0, 1, -1, 1, -1, 0, 1};
    float mix = 0.f;
#pragma unroll
    for (int k = 0; k < 3; k++) {
        int d = 1 << k;  // DILS = (1,2,4)
        float s = cen[(size_t)(b * 3 + k) * HW + p] * Dc;
#pragma unroll
        for (int j = 0; j < 8; j++) {
            int yy = y + dy_[j] * d;
            int xx = x + dx_[j] * d;
            float nb = ((unsigned)yy < (unsigned)Hs && (unsigned)xx < (unsigned)Ws)
                           ? Db[(size_t)yy * Ws + xx] : 0.f;
            s = fmaf(A[(size_t)(b * 24 + k * 8 + j) * HW + p], nb, s);
        }
        float kp = kap[(size_t)(b * 3 + k) * HW + p];
        mix += sig[(size_t)(b * 3 + k) * HW + p] * (Dc + kp * (s - Dc));
    }
    float dl = xbuf[(size_t)(b * 6 + 3) * HW + p];
    float ml = xbuf[(size_t)(b * 6 + 4) * HW + p];
    Dn[(size_t)b * HW + p] = ml * (0.9f * dl + 0.1f * mix) + (1.f - ml) * mix;
}

extern "C" void kernel_launch(void* const* d_in, const int* in_sizes, int n_in,
                              void* d_out, int out_size, void* d_ws, size_t ws_size,
                              hipStream_t stream) {
    const float* I  = (const float*)d_in[0];
    const float* DL = (const float*)d_in[1];
    const float* ML = (const float*)d_in[2];
    const float* E  = (const float*)d_in[3];
    const float* w0 = (const float*)d_in[4];  const float* b0 = (const float*)d_in[5];
    const float* w1 = (const float*)d_in[6];  const float* b1 = (const float*)d_in[7];
    const float* w2 = (const float*)d_in[8];  const float* b2 = (const float*)d_in[9];
    const float* wa = (const float*)d_in[10]; const float* ba = (const float*)d_in[11];
    const float* wg = (const float*)d_in[12]; const float* bg = (const float*)d_in[13];
    const float* wc = (const float*)d_in[14]; const float* bc = (const float*)d_in[15];

    size_t off = 0;
    auto carve = [&](size_t bytes) -> void* {
        void* pp = (char*)d_ws + off;
        off = (off + bytes + 255) & ~(size_t)255;
        return pp;
    };
    float* xbuf  = (float*)carve((size_t)BN * 6 * HW1 * 4);
    float* Abuf  = (float*)carve((size_t)BN * 24 * HW1 * 4);
    float* cen   = (float*)carve((size_t)BN * 3 * HW1 * 4);
    float* sig   = (float*)carve((size_t)BN * 3 * HW1 * 4);
    float* kap   = (float*)carve((size_t)BN * 3 * HW1 * 4);
    float* D0    = (float*)carve((size_t)BN * HW1 * 4);
    float* D1    = (float*)carve((size_t)BN * HW1 * 4);
    float* Dprev = (float*)carve((size_t)BN * HW1 * 4);
    bf16*  bufA  = (bf16*)carve((size_t)BN * 64 * HW1 * 2);
    bf16*  bufB  = (bf16*)carve((size_t)BN * 64 * HW1 * 2);
    float* wT0 = (float*)carve((size_t)6 * 9 * 64 * 4);
    float* wT1 = (float*)carve((size_t)64 * 9 * 64 * 4);
    float* wT2 = (float*)carve((size_t)64 * 9 * 64 * 4);
    float* wTa = (float*)carve((size_t)64 * 9 * 24 * 4);
    float* wTg = (float*)carve((size_t)64 * 9 * 3 * 4);
    float* wTc = (float*)carve((size_t)65 * 9 * 3 * 4);
    if (off > ws_size) return;  // insufficient scratch — fail cleanly

    auto tr = [&](const float* w, float* wT, int ci, int co) {
        int tot = co * ci * 9;
        wtr_k<<<(tot + 255) / 256, 256, 0, stream>>>(w, wT, ci, co);
    };
    tr(w0, wT0, 6, 64);
    tr(w1, wT1, 64, 64);
    tr(w2, wT2, 64, 64);
    tr(wa, wTa, 64, 24);
    tr(wg, wTg, 64, 3);
    tr(wc, wTc, 65, 3);

    const int scales[3] = {4, 2, 1};
    for (int si = 0; si < 3; si++) {
        int s = scales[si];
        int Hs = H0 / s, Ws = W0 / s, HW = Hs * Ws;
        int nb3 = (BN * 3 * HW + 255) / 256;
        int nb1 = (BN * 1 * HW + 255) / 256;
        int nbp = (BN * HW + 255) / 256;

        resize_aa_k<<<nb3, 256, 0, stream>>>(I, H0, W0, xbuf, Hs, Ws, s, 3, 0, 0);
        resize_aa_k<<<nb1, 256, 0, stream>>>(E, H0, W0, xbuf, Hs, Ws, s, 1, 5, 1);
        downsp_k<<<nbp, 256, 0, stream>>>(DL, ML, xbuf, Hs, Ws, s);
        if (si == 0)
            dinit_first_k<<<nbp, 256, 0, stream>>>(xbuf, D0, Hs, Ws);
        else
            dinit_blend_k<<<nbp, 256, 0, stream>>>(Dprev, xbuf, D0, Hs, Ws);

        conv3x3_k<float, 6, 64, false, 1><<<nbp, 256, 0, stream>>>(
            xbuf, wT0, b0, nullptr, 0.f, bufA, nullptr, Hs, Ws);
        conv3x3_k<bf16, 64, 64, false, 1><<<nbp, 256, 0, stream>>>(
            bufA, wT1, b1, nullptr, 0.f, bufB, nullptr, Hs, Ws);
        conv3x3_k<bf16, 64, 64, false, 1><<<nbp, 256, 0, stream>>>(
            bufB, wT2, b2, nullptr, 0.f, bufA, nullptr, Hs, Ws);
        conv3x3_k<bf16, 64, 24, false, 2><<<nbp, 256, 0, stream>>>(
            bufA, wTa, ba, nullptr, 0.f, Abuf, cen, Hs, Ws);
        conv3x3_k<bf16, 64, 3, false, 3><<<nbp, 256, 0, stream>>>(
            bufA, wTg, bg, nullptr, 0.f, sig, nullptr, Hs, Ws);
        conv3x3_k<bf16, 64, 3, true, 4><<<nbp, 256, 0, stream>>>(
            bufA, wTc, bc, D0, 0.1f, kap, nullptr, Hs, Ws);

        float* Dc = D0;
        float* Dn = D1;
        for (int t = 0; t < 6; t++) {
            prop_k<<<nbp, 256, 0, stream>>>(Dc, Abuf, cen, sig, kap, xbuf, Dn, Hs, Ws);
            float* tmp = Dc; Dc = Dn; Dn = tmp;
        }
        // 6 steps (even) -> result is back in D0 (== Dc)
        if (si < 2)
            hipMemcpyAsync(Dprev, Dc, (size_t)BN * HW * 4, hipMemcpyDeviceToDevice, stream);
        else
            hipMemcpyAsync(d_out, Dc, (size_t)BN * HW * 4, hipMemcpyDeviceToDevice, stream);
    }
}

// Round 2
// 1160.906 us; speedup vs baseline: 4.7579x; 4.7579x over previous
//
#include <hip/hip_runtime.h>
#include <hip/hip_bf16.h>

typedef __hip_bfloat16 bf16;
typedef __attribute__((ext_vector_type(8))) short short8v;
typedef __attribute__((ext_vector_type(4))) float f32x4;

static constexpr int BN = 2;
static constexpr int H0 = 480, W0 = 640;
static constexpr int HW1 = H0 * W0;

__device__ __forceinline__ unsigned short f2bf(float f) {
    bf16 h = __float2bfloat16(f);
    return reinterpret_cast<unsigned short&>(h);
}
__device__ __forceinline__ float bf2f(unsigned short u) {
    bf16 h; reinterpret_cast<unsigned short&>(h) = u;
    return __bfloat162float(h);
}

// ---------------- conv0 weight transpose: (O,I,3,3) -> [(i*3+ky)*3+kx][o] ----------------
__global__ void wtr_k(const float* __restrict__ w, float* __restrict__ wT, int CINT, int COUT) {
    int gid = blockIdx.x * 256 + threadIdx.x;
    int total = COUT * CINT * 9;
    if (gid >= total) return;
    int o = gid / (CINT * 9);
    int r = gid - o * (CINT * 9);
    wT[r * COUT + o] = w[gid];
}

// ---------------- MFMA weight transform (64->64), hi/lo split ----------------
// WB flat: (((tap*2+ks)*2+hl)*4+n)*512 + lane*8 + i    (NF=4)
__global__ void wtr2_k(const float* __restrict__ w, short* __restrict__ WB) {
    int gid = blockIdx.x * 256 + threadIdx.x;
    if (gid >= 18 * 2 * 4 * 512) return;
    int ie = gid & 7;
    int l  = (gid >> 3) & 63;
    int n  = (gid >> 9) & 3;
    int hl = (gid >> 11) & 1;
    int t2 = gid >> 12;            // 0..17
    int tap = t2 >> 1, ks = t2 & 1;
    int o = 16 * n + (l & 15);
    int c = 32 * ks + (l >> 4) * 8 + ie;
    float wv = w[(size_t)(o * 64 + c) * 9 + tap];
    bf16 hi = __float2bfloat16(wv);
    float hif = __bfloat162float(hi);
    bf16 lo = __float2bfloat16(wv - hif);
    WB[gid] = hl ? reinterpret_cast<short&>(lo) : reinterpret_cast<short&>(hi);
}

// ---------------- head weight transform (aff24+gate3+curv3 -> 32ch), hi/lo ----------------
// WB flat: (((tap*2+ks)*2+hl)*2+n)*512 + lane*8 + i    (NF=2)
__global__ void whb_k(const float* __restrict__ wa, const float* __restrict__ wg,
                      const float* __restrict__ wc, short* __restrict__ WB) {
    int gid = blockIdx.x * 256 + threadIdx.x;
    if (gid >= 18 * 2 * 2 * 512) return;
    int ie = gid & 7;
    int l  = (gid >> 3) & 63;
    int n  = (gid >> 9) & 1;
    int hl = (gid >> 10) & 1;
    int t2 = gid >> 11;
    int tap = t2 >> 1, ks = t2 & 1;
    int o = 16 * n + (l & 15);     // 0..31
    int c = 32 * ks + (l >> 4) * 8 + ie;
    float wv = 0.f;
    if (o < 24)                 wv = wa[(size_t)(o * 64 + c) * 9 + tap];
    else if (o >= 24 && o < 27) wv = wg[(size_t)((o - 24) * 64 + c) * 9 + tap];
    else if (o >= 28 && o < 31) wv = wc[(size_t)((o - 28) * 65 + c) * 9 + tap];
    bf16 hi = __float2bfloat16(wv);
    float hif = __bfloat162float(hi);
    bf16 lo = __float2bfloat16(wv - hif);
    WB[gid] = hl ? reinterpret_cast<short&>(lo) : reinterpret_cast<short&>(hi);
}

__global__ void hbias_k(const float* __restrict__ ba, const float* __restrict__ bg,
                        const float* __restrict__ bc, float* __restrict__ hb) {
    int o = threadIdx.x;
    if (o >= 32) return;
    float v = 0.f;
    if (o < 24) v = ba[o];
    else if (o < 27) v = bg[o - 24];
    else if (o >= 28 && o < 31) v = bc[o - 28];
    hb[o] = v;
}

// ---------------- antialiased "linear" resize (JAX semantics), factor f in {1,2,4} ----------------
__global__ void resize_aa_k(const float* __restrict__ in, int Hin, int Win,
                            float* __restrict__ xout, int Hs, int Ws, int f,
                            int C, int c0, int clip01) {
    int gid = blockIdx.x * 256 + threadIdx.x;
    int HWs = Hs * Ws;
    int total = BN * C * HWs;
    if (gid >= total) return;
    int ox = gid % Ws;
    int t1 = gid / Ws;
    int oy = t1 % Hs;
    int t2 = t1 / Hs;
    int c = t2 % C;
    int b = t2 / C;
    const float* ip = in + (size_t)(b * C + c) * Hin * Win;

    float wy[8], wx[8];
    int nt = 2 * f;
    float sy = (oy + 0.5f) * f - 0.5f;
    int jly = f * oy - (f + 1) / 2;
    float wys = 0.f;
    for (int t = 0; t < nt; t++) {
        int j = jly + t;
        float w = 1.f - fabsf(sy - (float)j) / (float)f;
        w = fmaxf(w, 0.f);
        if (j < 0 || j >= Hin) w = 0.f;
        wy[t] = w; wys += w;
    }
    float sx = (ox + 0.5f) * f - 0.5f;
    int jlx = f * ox - (f + 1) / 2;
    float wxs = 0.f;
    for (int t = 0; t < nt; t++) {
        int j = jlx + t;
        float w = 1.f - fabsf(sx - (float)j) / (float)f;
        w = fmaxf(w, 0.f);
        if (j < 0 || j >= Win) w = 0.f;
        wx[t] = w; wxs += w;
    }
    float acc = 0.f;
    for (int ty = 0; ty < nt; ty++) {
        if (wy[ty] == 0.f) continue;
        const float* row = ip + (size_t)(jly + ty) * Win;
        float r = 0.f;
        for (int tx = 0; tx < nt; tx++) {
            if (wx[tx] == 0.f) continue;
            r += wx[tx] * row[jlx + tx];
        }
        acc += wy[ty] * r;
    }
    acc /= (wys * wxs);
    if (clip01) acc = fminf(fmaxf(acc, 0.f), 1.f);
    xout[(size_t)(b * 6 + c0 + c) * HWs + (size_t)oy * Ws + ox] = acc;
}

// ---------------- sparse-depth valid-mean pooling -> xbuf planes 3 (DL) and 4 (ML) ----------------
__global__ void downsp_k(const float* __restrict__ DL, const float* __restrict__ ML,
                         float* __restrict__ xout, int Hs, int Ws, int k) {
    int gid = blockIdx.x * 256 + threadIdx.x;
    int HWs = Hs * Ws;
    if (gid >= BN * HWs) return;
    int ox = gid % Ws;
    int oy = (gid / Ws) % Hs;
    int b = gid / HWs;
    float s = 0.f, c = 0.f;
    for (int dy = 0; dy < k; dy++) {
        for (int dx = 0; dx < k; dx++) {
            size_t idx = ((size_t)b * H0 + (oy * k + dy)) * W0 + (ox * k + dx);
            float m = ML[idx] > 0.f ? 1.f : 0.f;
            s += DL[idx] * m;
            c += m;
        }
    }
    int p = oy * Ws + ox;
    float mls = c > 0.f ? 1.f : 0.f;
    float dls = c > 0.f ? s / (c + 1e-6f) : 0.f;
    xout[(size_t)(b * 6 + 3) * HWs + p] = dls;
    xout[(size_t)(b * 6 + 4) * HWs + p] = mls;
}

// ---------------- D init, first scale ----------------
__global__ void dinit_first_k(const float* __restrict__ xbuf, float* __restrict__ D0,
                              int Hs, int Ws) {
    int gid = blockIdx.x * 256 + threadIdx.x;
    int HW = Hs * Ws;
    if (gid >= BN * HW) return;
    int b = gid / HW;
    int p = gid - b * HW;
    float e = xbuf[(size_t)(b * 6 + 5) * HW + p];
    D0[gid] = fminf(fmaxf(e * 10.f, 0.f), 10.f);
}

// ---------------- D init, later scales ----------------
__global__ void dinit_blend_k(const float* __restrict__ Dp, const float* __restrict__ xbuf,
                              float* __restrict__ D0, int Hs, int Ws) {
    int gid = blockIdx.x * 256 + threadIdx.x;
    int HW = Hs * Ws;
    if (gid >= BN * HW) return;
    int ox = gid % Ws;
    int oy = (gid / Ws) % Hs;
    int b = gid / HW;
    int hp = Hs / 2, wp = Ws / 2;
    const float* P = Dp + (size_t)b * hp * wp;

    float ty = 0.5f * oy - 0.25f;
    int jy = (int)floorf(ty);
    float fy = ty - jy;
    float wy0 = 1.f - fy, wy1 = fy;
    bool v0 = (jy >= 0) && (jy < hp);
    bool v1 = (jy + 1 >= 0) && (jy + 1 < hp);
    if (!v0) wy0 = 0.f;
    if (!v1) wy1 = 0.f;
    float wys = wy0 + wy1;

    float tx = 0.5f * ox - 0.25f;
    int jx = (int)floorf(tx);
    float fx = tx - jx;
    float wx0 = 1.f - fx, wx1 = fx;
    bool u0 = (jx >= 0) && (jx < wp);
    bool u1 = (jx + 1 >= 0) && (jx + 1 < wp);
    if (!u0) wx0 = 0.f;
    if (!u1) wx1 = 0.f;
    float wxs = wx0 + wx1;

    int jy0c = v0 ? jy : 0, jy1c = v1 ? (jy + 1) : 0;
    int jx0c = u0 ? jx : 0, jx1c = u1 ? (jx + 1) : 0;
    float up = wy0 * (wx0 * P[(size_t)jy0c * wp + jx0c] + wx1 * P[(size_t)jy0c * wp + jx1c])
             + wy1 * (wx0 * P[(size_t)jy1c * wp + jx0c] + wx1 * P[(size_t)jy1c * wp + jx1c]);
    up /= (wys * wxs);

    const float* E = xbuf + (size_t)(b * 6 + 5) * HW;
    float e = E[(size_t)oy * Ws + ox];
    float gx = (ox > 0) ? fabsf(e - E[(size_t)oy * Ws + ox - 1]) : 0.f;
    float gy = (oy > 0) ? fabsf(e - E[(size_t)(oy - 1) * Ws + ox]) : 0.f;
    float g = fminf(fmaxf(0.5f * (gx + gy), 0.f), 1.f);
    float w = 0.7f * fminf(fmaxf(1.f - g * 10.f, 0.f), 1.f);
    float Pv = fminf(fmaxf(e * 10.f, 0.f), 10.f);
    D0[gid] = w * up + (1.f - w) * Pv;
}

// ---------------- zero halos of both padded feature buffers ----------------
__global__ void halo0_k(short* __restrict__ A, short* __restrict__ B2, int Hs, int Ws) {
    int pw = Ws + 2;
    int ne = 2 * pw + 2 * Hs;
    int total = 4 * ne;
    int gid = blockIdx.x * 256 + threadIdx.x;
    if (gid >= total) return;
    int e = gid % ne;
    int t = gid / ne;
    int b = t & 1;
    int buf = t >> 1;
    int yp, xp;
    if (e < pw)            { yp = 0;      xp = e; }
    else if (e < 2 * pw)   { yp = Hs + 1; xp = e - pw; }
    else { int e2 = e - 2 * pw; yp = 1 + (e2 >> 1); xp = (e2 & 1) ? (Ws + 1) : 0; }
    short* p = (buf ? B2 : A) + (((size_t)b * (Hs + 6) + 2 + yp) * pw + xp) * 64;
    short8v z = {0, 0, 0, 0, 0, 0, 0, 0};
#pragma unroll
    for (int j = 0; j < 8; j++) *(short8v*)(p + j * 8) = z;
}

// ---------------- conv0: 6->64 direct fp32, writes channel-last padded bf16 ----------------
__global__ __launch_bounds__(256) void conv0_k(const float* __restrict__ xbuf,
        const float* __restrict__ wT, const float* __restrict__ bias,
        short* __restrict__ Y, int Hs, int Ws) {
    int gid = blockIdx.x * 256 + threadIdx.x;
    int HW = Hs * Ws;
    if (gid >= BN * HW) return;
    int b = gid / HW;
    int p = gid - b * HW;
    int y = p / Ws;
    int x = p - y * Ws;
    float acc[64];
#pragma unroll
    for (int o = 0; o < 64; o++) acc[o] = bias[o];
    const float* xb = xbuf + (size_t)b * 6 * HW;
    for (int i = 0; i < 6; i++) {
        const float* ic = xb + (size_t)i * HW;
#pragma unroll
        for (int ky = 0; ky < 3; ky++) {
            int yy = y + ky - 1;
            if ((unsigned)yy >= (unsigned)Hs) continue;
            const float* irow = ic + (size_t)yy * Ws;
            const float* wr = wT + (size_t)((i * 3 + ky) * 3) * 64;
#pragma unroll
            for (int kx = 0; kx < 3; kx++) {
                int xx = x + kx - 1;
                float v = ((unsigned)xx < (unsigned)Ws) ? irow[xx] : 0.f;
                const float* wro = wr + kx * 64;
#pragma unroll
                for (int o = 0; o < 64; o++) acc[o] = fmaf(v, wro[o], acc[o]);
            }
        }
    }
    int pw = Ws + 2;
    short* out = Y + (((size_t)b * (Hs + 6) + 2 + (y + 1)) * pw + (x + 1)) * 64;
#pragma unroll
    for (int j = 0; j < 8; j++) {
        short8v v;
#pragma unroll
        for (int e = 0; e < 8; e++) v[e] = (short)f2bf(fmaxf(acc[j * 8 + e], 0.f));
        *(short8v*)(out + j * 8) = v;
    }
}

// ---------------- MFMA implicit-GEMM 3x3 conv ----------------
// A-operand = weights (hi/lo bf16), B-operand = channel-last padded activations.
// EPI 0: relu -> bf16 channel-last padded Y.  EPI 1: head epilogue (NF=2).
template <int NF, int EPI>
__global__ __launch_bounds__(256, 2) void convmm_k(
        const short* __restrict__ X, const short* __restrict__ WB,
        const float* __restrict__ bias, short* __restrict__ Y,
        bf16* __restrict__ Aout, float* __restrict__ cen,
        float* __restrict__ sig, float* __restrict__ kap,
        const float* __restrict__ Dcur, const float* __restrict__ wc,
        int Hs, int Ws) {
    const int pw = Ws + 2;
    const int lane = threadIdx.x & 63;
    const int wv = threadIdx.x >> 6;
    const int b = blockIdx.y;
    const int m0 = blockIdx.x * 512 + wv * 128;
    const int l15 = lane & 15;
    const int g = lane >> 4;
    const size_t bbase = ((size_t)b * (Hs + 6) + 2) * pw * 64;
    const short* Xb = X + bbase;

    f32x4 acc[NF][8];
#pragma unroll
    for (int n = 0; n < NF; n++) {
        float b0 = bias[16 * n + g * 4 + 0];
        float b1 = bias[16 * n + g * 4 + 1];
        float b2 = bias[16 * n + g * 4 + 2];
        float b3 = bias[16 * n + g * 4 + 3];
        f32x4 bv; bv[0] = b0; bv[1] = b1; bv[2] = b2; bv[3] = b3;
#pragma unroll
        for (int pf = 0; pf < 8; pf++) acc[n][pf] = bv;
    }

    const int vb = (pw + m0 + l15) * 64 + g * 8;

    for (int tap = 0; tap < 9; tap++) {
        const int toff = ((tap / 3 - 1) * pw + (tap % 3 - 1)) * 64;
#pragma unroll
        for (int ks = 0; ks < 2; ks++) {
            const short* xp = Xb + vb + toff + ks * 32;
            short8v bx[8];
#pragma unroll
            for (int pf = 0; pf < 8; pf++)
                bx[pf] = *(const short8v*)(xp + pf * 1024);
            const short* wp = WB + (size_t)((tap * 2 + ks) * 2) * (NF * 512) + lane * 8;
#pragma unroll
            for (int hl = 0; hl < 2; hl++) {
#pragma unroll
                for (int n = 0; n < NF; n++) {
                    short8v av = *(const short8v*)(wp + (hl * NF + n) * 512);
#pragma unroll
                    for (int pf = 0; pf < 8; pf++)
                        acc[n][pf] = __builtin_amdgcn_mfma_f32_16x16x32_bf16(
                            av, bx[pf], acc[n][pf], 0, 0, 0);
                }
            }
        }
    }

    const int HW = Hs * Ws;
#pragma unroll
    for (int pf = 0; pf < 8; pf++) {
        int P = pw + m0 + pf * 16 + l15;
        int yp = P / pw;
        int xp = P - yp * pw;
        bool ok = (xp >= 1) && (xp <= Ws) && (yp <= Hs);
        if (EPI == 0) {
            if (!ok) continue;
            short* out = Y + bbase + (size_t)P * 64 + 16 * 0 + g * 4;
#pragma unroll
            for (int n = 0; n < NF; n++) {
                ushort4 v;
                v.x = f2bf(fmaxf(acc[n][pf][0], 0.f));
                v.y = f2bf(fmaxf(acc[n][pf][1], 0.f));
                v.z = f2bf(fmaxf(acc[n][pf][2], 0.f));
                v.w = f2bf(fmaxf(acc[n][pf][3], 0.f));
                *(ushort4*)(out + 16 * n) = v;
            }
        } else {
            // head epilogue: ch0-23 affinity, 24-26 gate, 28-30 curv
            float t0 = fabsf(acc[0][pf][0]) + fabsf(acc[0][pf][1]) +
                       fabsf(acc[0][pf][2]) + fabsf(acc[0][pf][3]);
            float s0 = t0 + __shfl_xor(t0, 16, 64);
            float t1 = fabsf(acc[1][pf][0]) + fabsf(acc[1][pf][1]) +
                       fabsf(acc[1][pf][2]) + fabsf(acc[1][pf][3]);
            float s1 = t1 + __shfl_xor(t1, 16, 64);
            float inv0 = 1.f / (s0 + 1e-6f);
            float inv1 = 1.f / (s1 + 1e-6f);
            float a0[4], a1[4];
#pragma unroll
            for (int j = 0; j < 4; j++) { a0[j] = acc[0][pf][j] * inv0; a1[j] = acc[1][pf][j] * inv1; }
            float p0 = a0[0] + a0[1] + a0[2] + a0[3];
            float c0 = p0 + __shfl_xor(p0, 16, 64);
            float p1 = a1[0] + a1[1] + a1[2] + a1[3];
            float c1 = p1 + __shfl_xor(p1, 16, 64);

            int y = yp - 1, x = xp - 1;
            int pix = y * Ws + x;
            if (ok) {
#pragma unroll
                for (int j = 0; j < 4; j++) {
                    int ch = g * 4 + j;
                    reinterpret_cast<unsigned short*>(Aout)[((size_t)(b * 24 + ch)) * HW + pix] = f2bf(a0[j]);
                }
                if (g < 2) {
#pragma unroll
                    for (int j = 0; j < 4; j++) {
                        int ch = 16 + g * 4 + j;
                        reinterpret_cast<unsigned short*>(Aout)[((size_t)(b * 24 + ch)) * HW + pix] = f2bf(a1[j]);
                    }
                }
                if (g == 0) {
                    cen[((size_t)(b * 3 + 0)) * HW + pix] = 1.f - c0;
                    cen[((size_t)(b * 3 + 2)) * HW + pix] = 1.f - c1;
                }
                if (g == 2) {
                    cen[((size_t)(b * 3 + 1)) * HW + pix] = 1.f - c0;
                    // gate softmax over ch 24,25,26 (all local to this lane)
                    float e0 = acc[1][pf][0], e1 = acc[1][pf][1], e2 = acc[1][pf][2];
                    float m = fmaxf(e0, fmaxf(e1, e2));
                    float x0 = expf(e0 - m), x1 = expf(e1 - m), x2 = expf(e2 - m);
                    float is = 1.f / (x0 + x1 + x2);
                    sig[((size_t)(b * 3 + 0)) * HW + pix] = x0 * is;
                    sig[((size_t)(b * 3 + 1)) * HW + pix] = x1 * is;
                    sig[((size_t)(b * 3 + 2)) * HW + pix] = x2 * is;
                }
                if (g == 3) {
                    // curvature: ch 28,29,30 + D-channel 9-tap contribution
                    float dsum[3] = {0.f, 0.f, 0.f};
#pragma unroll
                    for (int t = 0; t < 9; t++) {
                        int yy = y + t / 3 - 1;
                        int xx = x + t % 3 - 1;
                        if ((unsigned)yy < (unsigned)Hs && (unsigned)xx < (unsigned)Ws) {
                            float dv = Dcur[(size_t)b * HW + (size_t)yy * Ws + xx] * 0.1f;
#pragma unroll
                            for (int j = 0; j < 3; j++)
                                dsum[j] = fmaf(wc[(size_t)(j * 65 + 64) * 9 + t], dv, dsum[j]);
                        }
                    }
#pragma unroll
                    for (int j = 0; j < 3; j++) {
                        float z = acc[1][pf][j] + dsum[j];
                        float sg = 1.f / (1.f + expf(-z));
                        kap[((size_t)(b * 3 + j)) * HW + pix] = 0.1f + 0.9f * sg;
                    }
                }
            }
        }
    }
}

// ---------------- one CSPN propagation step (A in bf16) ----------------
__global__ __launch_bounds__(256) void prop_k(const float* __restrict__ D,
        const unsigned short* __restrict__ A, const float* __restrict__ cen,
        const float* __restrict__ sig, const float* __restrict__ kap,
        const float* __restrict__ xbuf, float* __restrict__ Dn, int Hs, int Ws) {
    int gid = blockIdx.x * 256 + threadIdx.x;
    int HW = Hs * Ws;
    if (gid >= BN * HW) return;
    int b = gid / HW;
    int p = gid - b * HW;
    int y = p / Ws;
    int x = p - y * Ws;
    const float* Db = D + (size_t)b * HW;
    float Dc = Db[p];
    const int dy_[8] = {-1, -1, -1, 0, 0, 1, 1, 1};
    const int dx_[8] = {-1, 0, 1, -1, 1, -1, 0, 1};
    float mix = 0.f;
#pragma unroll
    for (int k = 0; k < 3; k++) {
        int d = 1 << k;
        float s = cen[(size_t)(b * 3 + k) * HW + p] * Dc;
#pragma unroll
        for (int j = 0; j < 8; j++) {
            int yy = y + dy_[j] * d;
            int xx = x + dx_[j] * d;
            float nb = ((unsigned)yy < (unsigned)Hs && (unsigned)xx < (unsigned)Ws)
                           ? Db[(size_t)yy * Ws + xx] : 0.f;
            s = fmaf(bf2f(A[(size_t)(b * 24 + k * 8 + j) * HW + p]), nb, s);
        }
        float kp = kap[(size_t)(b * 3 + k) * HW + p];
        mix += sig[(size_t)(b * 3 + k) * HW + p] * (Dc + kp * (s - Dc));
    }
    float dl = xbuf[(size_t)(b * 6 + 3) * HW + p];
    float ml = xbuf[(size_t)(b * 6 + 4) * HW + p];
    Dn[(size_t)b * HW + p] = ml * (0.9f * dl + 0.1f * mix) + (1.f - ml) * mix;
}

extern "C" void kernel_launch(void* const* d_in, const int* in_sizes, int n_in,
                              void* d_out, int out_size, void* d_ws, size_t ws_size,
                              hipStream_t stream) {
    const float* I  = (const float*)d_in[0];
    const float* DL = (const float*)d_in[1];
    const float* ML = (const float*)d_in[2];
    const float* E  = (const float*)d_in[3];
    const float* w0 = (const float*)d_in[4];  const float* b0 = (const float*)d_in[5];
    const float* w1 = (const float*)d_in[6];  const float* b1 = (const float*)d_in[7];
    const float* w2 = (const float*)d_in[8];  const float* b2 = (const float*)d_in[9];
    const float* wa = (const float*)d_in[10]; const float* ba = (const float*)d_in[11];
    const float* wg = (const float*)d_in[12]; const float* bg = (const float*)d_in[13];
    const float* wc = (const float*)d_in[14]; const float* bc = (const float*)d_in[15];

    size_t off = 0;
    auto carve = [&](size_t bytes) -> void* {
        void* pp = (char*)d_ws + off;
        off = (off + bytes + 255) & ~(size_t)255;
        return pp;
    };
    float* xbuf  = (float*)carve((size_t)BN * 6 * HW1 * 4);
    bf16*  Abuf  = (bf16*)carve((size_t)BN * 24 * HW1 * 2);
    float* cen   = (float*)carve((size_t)BN * 3 * HW1 * 4);
    float* sig   = (float*)carve((size_t)BN * 3 * HW1 * 4);
    float* kap   = (float*)carve((size_t)BN * 3 * HW1 * 4);
    float* D0    = (float*)carve((size_t)BN * HW1 * 4);
    float* D1    = (float*)carve((size_t)BN * HW1 * 4);
    float* Dprev = (float*)carve((size_t)BN * HW1 * 4);
    size_t padElems = (size_t)BN * (H0 + 6) * (W0 + 2) * 64;
    short* padA = (short*)carve(padElems * 2 + 4096);
    short* padB = (short*)carve(padElems * 2 + 4096);
    short* WB1  = (short*)carve((size_t)18 * 2 * 4 * 512 * 2);
    short* WB2  = (short*)carve((size_t)18 * 2 * 4 * 512 * 2);
    short* WBh  = (short*)carve((size_t)18 * 2 * 2 * 512 * 2);
    float* hb   = (float*)carve(32 * 4);
    float* wT0  = (float*)carve((size_t)6 * 9 * 64 * 4);
    if (off > ws_size) return;

    wtr_k<<<(6 * 9 * 64 + 255) / 256, 256, 0, stream>>>(w0, wT0, 6, 64);
    wtr2_k<<<(18 * 2 * 4 * 512 + 255) / 256, 256, 0, stream>>>(w1, WB1);
    wtr2_k<<<(18 * 2 * 4 * 512 + 255) / 256, 256, 0, stream>>>(w2, WB2);
    whb_k<<<(18 * 2 * 2 * 512 + 255) / 256, 256, 0, stream>>>(wa, wg, wc, WBh);
    hbias_k<<<1, 32, 0, stream>>>(ba, bg, bc, hb);

    const int scales[3] = {4, 2, 1};
    for (int si = 0; si < 3; si++) {
        int s = scales[si];
        int Hs = H0 / s, Ws = W0 / s, HW = Hs * Ws;
        int pw = Ws + 2;
        int nb3 = (BN * 3 * HW + 255) / 256;
        int nb1 = (BN * 1 * HW + 255) / 256;
        int nbp = (BN * HW + 255) / 256;

        resize_aa_k<<<nb3, 256, 0, stream>>>(I, H0, W0, xbuf, Hs, Ws, s, 3, 0, 0);
        resize_aa_k<<<nb1, 256, 0, stream>>>(E, H0, W0, xbuf, Hs, Ws, s, 1, 5, 1);
        downsp_k<<<nbp, 256, 0, stream>>>(DL, ML, xbuf, Hs, Ws, s);
        if (si == 0)
            dinit_first_k<<<nbp, 256, 0, stream>>>(xbuf, D0, Hs, Ws);
        else
            dinit_blend_k<<<nbp, 256, 0, stream>>>(Dprev, xbuf, D0, Hs, Ws);

        int nhalo = (4 * (2 * pw + 2 * Hs) + 255) / 256;
        halo0_k<<<nhalo, 256, 0, stream>>>(padA, padB, Hs, Ws);
        conv0_k<<<nbp, 256, 0, stream>>>(xbuf, wT0, b0, padA, Hs, Ws);

        int Mb = Hs * pw;
        dim3 gmm((Mb + 511) / 512, BN);
        convmm_k<4, 0><<<gmm, 256, 0, stream>>>(padA, WB1, b1, padB,
            nullptr, nullptr, nullptr, nullptr, nullptr, nullptr, Hs, Ws);
        convmm_k<4, 0><<<gmm, 256, 0, stream>>>(padB, WB2, b2, padA,
            nullptr, nullptr, nullptr, nullptr, nullptr, nullptr, Hs, Ws);
        convmm_k<2, 1><<<gmm, 256, 0, stream>>>(padA, WBh, hb, nullptr,
            Abuf, cen, sig, kap, D0, wc, Hs, Ws);

        float* Dc = D0;
        float* Dn = D1;
        for (int t = 0; t < 6; t++) {
            prop_k<<<nbp, 256, 0, stream>>>(Dc, (const unsigned short*)Abuf, cen, sig, kap,
                                            xbuf, Dn, Hs, Ws);
            float* tmp = Dc; Dc = Dn; Dn = tmp;
        }
        if (si < 2)
            hipMemcpyAsync(Dprev, Dc, (size_t)BN * HW * 4, hipMemcpyDeviceToDevice, stream);
        else
            hipMemcpyAsync(d_out, Dc, (size_t)BN * HW * 4, hipMemcpyDeviceToDevice, stream);
    }
}

// Round 3
// 1074.028 us; speedup vs baseline: 5.1427x; 1.0809x over previous
//
#include <hip/hip_runtime.h>
#include <hip/hip_bf16.h>

typedef __hip_bfloat16 bf16;
typedef __attribute__((ext_vector_type(8))) short short8v;
typedef __attribute__((ext_vector_type(4))) float f32x4;

static constexpr int BN = 2;
static constexpr int H0 = 480, W0 = 640;
static constexpr int HW1 = H0 * W0;

__device__ __forceinline__ unsigned short f2bf(float f) {
    bf16 h = __float2bfloat16(f);
    return reinterpret_cast<unsigned short&>(h);
}
__device__ __forceinline__ float bf2f(unsigned short u) {
    bf16 h; reinterpret_cast<unsigned short&>(h) = u;
    return __bfloat162float(h);
}

// ---------------- MFMA weight transform (64->64), hi/lo split ----------------
// WB flat: (((tap*2+ks)*2+hl)*4+n)*512 + lane*8 + i    (NF=4)
__global__ void wtr2_k(const float* __restrict__ w, short* __restrict__ WB) {
    int gid = blockIdx.x * 256 + threadIdx.x;
    if (gid >= 18 * 2 * 4 * 512) return;
    int ie = gid & 7;
    int l  = (gid >> 3) & 63;
    int n  = (gid >> 9) & 3;
    int hl = (gid >> 11) & 1;
    int t2 = gid >> 12;            // 0..17
    int tap = t2 >> 1, ks = t2 & 1;
    int o = 16 * n + (l & 15);
    int c = 32 * ks + (l >> 4) * 8 + ie;
    float wv = w[(size_t)(o * 64 + c) * 9 + tap];
    bf16 hi = __float2bfloat16(wv);
    float hif = __bfloat162float(hi);
    bf16 lo = __float2bfloat16(wv - hif);
    WB[gid] = hl ? reinterpret_cast<short&>(lo) : reinterpret_cast<short&>(hi);
}

// ---------------- conv0 MFMA weight transform (6ch+9tap -> K-slots), hi/lo ----------------
// WB flat: ((j*2+hl)*4+n)*512 + lane*8 + i   (j = K-chunk 0..2; tap=4j+g, ch=i)
__global__ void wtr0_k(const float* __restrict__ w, short* __restrict__ WB) {
    int gid = blockIdx.x * 256 + threadIdx.x;
    if (gid >= 3 * 2 * 4 * 512) return;
    int ie = gid & 7;
    int l  = (gid >> 3) & 63;
    int n  = (gid >> 9) & 3;
    int hl = (gid >> 11) & 1;
    int j  = gid >> 12;            // 0..2
    int o = 16 * n + (l & 15);
    int g = l >> 4;
    int tap = 4 * j + g;
    float wv = (tap < 9 && ie < 6) ? w[(size_t)(o * 6 + ie) * 9 + tap] : 0.f;
    bf16 hi = __float2bfloat16(wv);
    float hif = __bfloat162float(hi);
    bf16 lo = __float2bfloat16(wv - hif);
    WB[gid] = hl ? reinterpret_cast<short&>(lo) : reinterpret_cast<short&>(hi);
}

// ---------------- head weight transform (aff24+gate3+curv3 -> 32ch), hi/lo ----------------
__global__ void whb_k(const float* __restrict__ wa, const float* __restrict__ wg,
                      const float* __restrict__ wc, short* __restrict__ WB) {
    int gid = blockIdx.x * 256 + threadIdx.x;
    if (gid >= 18 * 2 * 2 * 512) return;
    int ie = gid & 7;
    int l  = (gid >> 3) & 63;
    int n  = (gid >> 9) & 1;
    int hl = (gid >> 10) & 1;
    int t2 = gid >> 11;
    int tap = t2 >> 1, ks = t2 & 1;
    int o = 16 * n + (l & 15);     // 0..31
    int c = 32 * ks + (l >> 4) * 8 + ie;
    float wv = 0.f;
    if (o < 24)                 wv = wa[(size_t)(o * 64 + c) * 9 + tap];
    else if (o >= 24 && o < 27) wv = wg[(size_t)((o - 24) * 64 + c) * 9 + tap];
    else if (o >= 28 && o < 31) wv = wc[(size_t)((o - 28) * 65 + c) * 9 + tap];
    bf16 hi = __float2bfloat16(wv);
    float hif = __bfloat162float(hi);
    bf16 lo = __float2bfloat16(wv - hif);
    WB[gid] = hl ? reinterpret_cast<short&>(lo) : reinterpret_cast<short&>(hi);
}

__global__ void hbias_k(const float* __restrict__ ba, const float* __restrict__ bg,
                        const float* __restrict__ bc, float* __restrict__ hb) {
    int o = threadIdx.x;
    if (o >= 32) return;
    float v = 0.f;
    if (o < 24) v = ba[o];
    else if (o < 27) v = bg[o - 24];
    else if (o >= 28 && o < 31) v = bc[o - 28];
    hb[o] = v;
}

// ---------------- antialiased "linear" resize (JAX semantics), factor f in {1,2,4} ----------------
__global__ void resize_aa_k(const float* __restrict__ in, int Hin, int Win,
                            float* __restrict__ xout, int Hs, int Ws, int f,
                            int C, int c0, int clip01) {
    int gid = blockIdx.x * 256 + threadIdx.x;
    int HWs = Hs * Ws;
    int total = BN * C * HWs;
    if (gid >= total) return;
    int ox = gid % Ws;
    int t1 = gid / Ws;
    int oy = t1 % Hs;
    int t2 = t1 / Hs;
    int c = t2 % C;
    int b = t2 / C;
    const float* ip = in + (size_t)(b * C + c) * Hin * Win;

    float wy[8], wx[8];
    int nt = 2 * f;
    float sy = (oy + 0.5f) * f - 0.5f;
    int jly = f * oy - (f + 1) / 2;
    float wys = 0.f;
    for (int t = 0; t < nt; t++) {
        int j = jly + t;
        float w = 1.f - fabsf(sy - (float)j) / (float)f;
        w = fmaxf(w, 0.f);
        if (j < 0 || j >= Hin) w = 0.f;
        wy[t] = w; wys += w;
    }
    float sx = (ox + 0.5f) * f - 0.5f;
    int jlx = f * ox - (f + 1) / 2;
    float wxs = 0.f;
    for (int t = 0; t < nt; t++) {
        int j = jlx + t;
        float w = 1.f - fabsf(sx - (float)j) / (float)f;
        w = fmaxf(w, 0.f);
        if (j < 0 || j >= Win) w = 0.f;
        wx[t] = w; wxs += w;
    }
    float acc = 0.f;
    for (int ty = 0; ty < nt; ty++) {
        if (wy[ty] == 0.f) continue;
        const float* row = ip + (size_t)(jly + ty) * Win;
        float r = 0.f;
        for (int tx = 0; tx < nt; tx++) {
            if (wx[tx] == 0.f) continue;
            r += wx[tx] * row[jlx + tx];
        }
        acc += wy[ty] * r;
    }
    acc /= (wys * wxs);
    if (clip01) acc = fminf(fmaxf(acc, 0.f), 1.f);
    xout[(size_t)(b * 6 + c0 + c) * HWs + (size_t)oy * Ws + ox] = acc;
}

// ---------------- sparse-depth valid-mean pooling -> xbuf planes 3 (DL) and 4 (ML) ----------------
__global__ void downsp_k(const float* __restrict__ DL, const float* __restrict__ ML,
                         float* __restrict__ xout, int Hs, int Ws, int k) {
    int gid = blockIdx.x * 256 + threadIdx.x;
    int HWs = Hs * Ws;
    if (gid >= BN * HWs) return;
    int ox = gid % Ws;
    int oy = (gid / Ws) % Hs;
    int b = gid / HWs;
    float s = 0.f, c = 0.f;
    for (int dy = 0; dy < k; dy++) {
        for (int dx = 0; dx < k; dx++) {
            size_t idx = ((size_t)b * H0 + (oy * k + dy)) * W0 + (ox * k + dx);
            float m = ML[idx] > 0.f ? 1.f : 0.f;
            s += DL[idx] * m;
            c += m;
        }
    }
    int p = oy * Ws + ox;
    float mls = c > 0.f ? 1.f : 0.f;
    float dls = c > 0.f ? s / (c + 1e-6f) : 0.f;
    xout[(size_t)(b * 6 + 3) * HWs + p] = dls;
    xout[(size_t)(b * 6 + 4) * HWs + p] = mls;
}

// ---------------- pack xbuf (6 fp32 planes) -> channel-last padded bf16 [b][yp][xp][8] ----------------
__global__ void xpack_k(const float* __restrict__ xbuf, short* __restrict__ Xp,
                        int Hs, int Ws) {
    int pw = Ws + 2;
    int gid = blockIdx.x * 256 + threadIdx.x;
    int total = BN * (Hs + 2) * pw;
    if (gid >= total) return;
    int xp = gid % pw;
    int yp = (gid / pw) % (Hs + 2);
    int b = gid / (pw * (Hs + 2));
    short8v v = {0, 0, 0, 0, 0, 0, 0, 0};
    if (yp >= 1 && yp <= Hs && xp >= 1 && xp <= Ws) {
        int HW = Hs * Ws;
        int p = (yp - 1) * Ws + (xp - 1);
#pragma unroll
        for (int c = 0; c < 6; c++)
            v[c] = (short)f2bf(xbuf[(size_t)(b * 6 + c) * HW + p]);
    }
    *(short8v*)(Xp + (((size_t)b * (Hs + 6) + 2 + yp) * pw + xp) * 8) = v;
}

// ---------------- D init, first scale ----------------
__global__ void dinit_first_k(const float* __restrict__ xbuf, float* __restrict__ D0,
                              int Hs, int Ws) {
    int gid = blockIdx.x * 256 + threadIdx.x;
    int HW = Hs * Ws;
    if (gid >= BN * HW) return;
    int b = gid / HW;
    int p = gid - b * HW;
    float e = xbuf[(size_t)(b * 6 + 5) * HW + p];
    D0[gid] = fminf(fmaxf(e * 10.f, 0.f), 10.f);
}

// ---------------- D init, later scales ----------------
__global__ void dinit_blend_k(const float* __restrict__ Dp, const float* __restrict__ xbuf,
                              float* __restrict__ D0, int Hs, int Ws) {
    int gid = blockIdx.x * 256 + threadIdx.x;
    int HW = Hs * Ws;
    if (gid >= BN * HW) return;
    int ox = gid % Ws;
    int oy = (gid / Ws) % Hs;
    int b = gid / HW;
    int hp = Hs / 2, wp = Ws / 2;
    const float* P = Dp + (size_t)b * hp * wp;

    float ty = 0.5f * oy - 0.25f;
    int jy = (int)floorf(ty);
    float fy = ty - jy;
    float wy0 = 1.f - fy, wy1 = fy;
    bool v0 = (jy >= 0) && (jy < hp);
    bool v1 = (jy + 1 >= 0) && (jy + 1 < hp);
    if (!v0) wy0 = 0.f;
    if (!v1) wy1 = 0.f;
    float wys = wy0 + wy1;

    float tx = 0.5f * ox - 0.25f;
    int jx = (int)floorf(tx);
    float fx = tx - jx;
    float wx0 = 1.f - fx, wx1 = fx;
    bool u0 = (jx >= 0) && (jx < wp);
    bool u1 = (jx + 1 >= 0) && (jx + 1 < wp);
    if (!u0) wx0 = 0.f;
    if (!u1) wx1 = 0.f;
    float wxs = wx0 + wx1;

    int jy0c = v0 ? jy : 0, jy1c = v1 ? (jy + 1) : 0;
    int jx0c = u0 ? jx : 0, jx1c = u1 ? (jx + 1) : 0;
    float up = wy0 * (wx0 * P[(size_t)jy0c * wp + jx0c] + wx1 * P[(size_t)jy0c * wp + jx1c])
             + wy1 * (wx0 * P[(size_t)jy1c * wp + jx0c] + wx1 * P[(size_t)jy1c * wp + jx1c]);
    up /= (wys * wxs);

    const float* E = xbuf + (size_t)(b * 6 + 5) * HW;
    float e = E[(size_t)oy * Ws + ox];
    float gx = (ox > 0) ? fabsf(e - E[(size_t)oy * Ws + ox - 1]) : 0.f;
    float gy = (oy > 0) ? fabsf(e - E[(size_t)(oy - 1) * Ws + ox]) : 0.f;
    float g = fminf(fmaxf(0.5f * (gx + gy), 0.f), 1.f);
    float w = 0.7f * fminf(fmaxf(1.f - g * 10.f, 0.f), 1.f);
    float Pv = fminf(fmaxf(e * 10.f, 0.f), 10.f);
    D0[gid] = w * up + (1.f - w) * Pv;
}

// ---------------- zero halos of both padded feature buffers ----------------
__global__ void halo0_k(short* __restrict__ A, short* __restrict__ B2, int Hs, int Ws) {
    int pw = Ws + 2;
    int ne = 2 * pw + 2 * Hs;
    int total = 4 * ne;
    int gid = blockIdx.x * 256 + threadIdx.x;
    if (gid >= total) return;
    int e = gid % ne;
    int t = gid / ne;
    int b = t & 1;
    int buf = t >> 1;
    int yp, xp;
    if (e < pw)            { yp = 0;      xp = e; }
    else if (e < 2 * pw)   { yp = Hs + 1; xp = e - pw; }
    else { int e2 = e - 2 * pw; yp = 1 + (e2 >> 1); xp = (e2 & 1) ? (Ws + 1) : 0; }
    short* p = (buf ? B2 : A) + (((size_t)b * (Hs + 6) + 2 + yp) * pw + xp) * 64;
    short8v z = {0, 0, 0, 0, 0, 0, 0, 0};
#pragma unroll
    for (int j = 0; j < 8; j++) *(short8v*)(p + j * 8) = z;
}

// bijective XCD-chunked swizzle (m204)
__device__ __forceinline__ int xcd_swz(int orig, int nwg) {
    int q = nwg >> 3, r = nwg & 7;
    int xcd = orig & 7, idx = orig >> 3;
    return (xcd < r ? xcd * (q + 1) : r * (q + 1) + (xcd - r) * q) + idx;
}

// ---------------- conv0: 6->64 MFMA implicit GEMM (K padded to 96 = 3 x K32) ----------------
__global__ __launch_bounds__(256, 2) void conv0mm_k(
        const short* __restrict__ Xp, const short* __restrict__ WB,
        const float* __restrict__ bias, short* __restrict__ Y,
        int Hs, int Ws, int tX) {
    const int pw = Ws + 2;
    const int lane = threadIdx.x & 63;
    const int wv = threadIdx.x >> 6;
    const int b = blockIdx.y;
    const int l15 = lane & 15;
    const int g = lane >> 4;
    int wg = xcd_swz(blockIdx.x, gridDim.x);
    int ty = wg / tX, txi = wg - ty * tX;
    const int y0 = ty * 8 + wv * 2;
    const int x0 = txi * 64;

    const size_t bbase8 = ((size_t)b * (Hs + 6) + 2) * pw * 8;
    const short* Xb = Xp + bbase8;

    f32x4 acc[4][8];
#pragma unroll
    for (int n = 0; n < 4; n++) {
        f32x4 bv;
#pragma unroll
        for (int j = 0; j < 4; j++) bv[j] = bias[16 * n + g * 4 + j];
#pragma unroll
        for (int pf = 0; pf < 8; pf++) acc[n][pf] = bv;
    }

    int vb[8];
#pragma unroll
    for (int pf = 0; pf < 8; pf++) {
        int rr = pf >> 2, cg = pf & 3;
        vb[pf] = ((y0 + rr + 1) * pw + (x0 + cg * 16 + l15 + 1)) * 8;
    }

#pragma unroll
    for (int j = 0; j < 3; j++) {
        int tap = 4 * j + g;
        if (tap > 8) tap = 8;          // zero-weight slots read a valid address
        int toff = ((tap / 3 - 1) * pw + (tap % 3 - 1)) * 8;
        short8v bx[8];
#pragma unroll
        for (int pf = 0; pf < 8; pf++)
            bx[pf] = *(const short8v*)(Xb + vb[pf] + toff);
        const short* wp = WB + (size_t)j * (2 * 4 * 512) + lane * 8;
#pragma unroll
        for (int hl = 0; hl < 2; hl++) {
#pragma unroll
            for (int n = 0; n < 4; n++) {
                short8v av = *(const short8v*)(wp + (hl * 4 + n) * 512);
#pragma unroll
                for (int pf = 0; pf < 8; pf++)
                    acc[n][pf] = __builtin_amdgcn_mfma_f32_16x16x32_bf16(
                        av, bx[pf], acc[n][pf], 0, 0, 0);
            }
        }
    }

    const size_t bbase = ((size_t)b * (Hs + 6) + 2) * pw * 64;
#pragma unroll
    for (int pf = 0; pf < 8; pf++) {
        int rr = pf >> 2, cg = pf & 3;
        int y = y0 + rr, x = x0 + cg * 16 + l15;
        if (x >= Ws) continue;
        short* out = Y + bbase + ((size_t)(y + 1) * pw + (x + 1)) * 64 + g * 4;
#pragma unroll
        for (int n = 0; n < 4; n++) {
            ushort4 v;
            v.x = f2bf(fmaxf(acc[n][pf][0], 0.f));
            v.y = f2bf(fmaxf(acc[n][pf][1], 0.f));
            v.z = f2bf(fmaxf(acc[n][pf][2], 0.f));
            v.w = f2bf(fmaxf(acc[n][pf][3], 0.f));
            *(ushort4*)(out + 16 * n) = v;
        }
    }
}

// ---------------- MFMA implicit-GEMM 3x3 conv, 2D-tiled ----------------
// block = 8 rows x 64 cols; wave = 2 rows x 64 cols (pf = rr*4 + colgroup)
template <int NF, int EPI>
__global__ __launch_bounds__(256, 2) void convmm_k(
        const short* __restrict__ X, const short* __restrict__ WB,
        const float* __restrict__ bias, short* __restrict__ Y,
        bf16* __restrict__ Aout, float* __restrict__ cen,
        float* __restrict__ sig, float* __restrict__ kap,
        const float* __restrict__ Dcur, const float* __restrict__ wc,
        int Hs, int Ws, int tX) {
    const int pw = Ws + 2;
    const int lane = threadIdx.x & 63;
    const int wv = threadIdx.x >> 6;
    const int b = blockIdx.y;
    const int l15 = lane & 15;
    const int g = lane >> 4;
    int wg = xcd_swz(blockIdx.x, gridDim.x);
    int ty = wg / tX, txi = wg - ty * tX;
    const int y0 = ty * 8 + wv * 2;
    const int x0 = txi * 64;

    const size_t bbase = ((size_t)b * (Hs + 6) + 2) * pw * 64;
    const short* Xb = X + bbase;

    f32x4 acc[NF][8];
#pragma unroll
    for (int n = 0; n < NF; n++) {
        f32x4 bv;
#pragma unroll
        for (int j = 0; j < 4; j++) bv[j] = bias[16 * n + g * 4 + j];
#pragma unroll
        for (int pf = 0; pf < 8; pf++) acc[n][pf] = bv;
    }

    int vb[8];
#pragma unroll
    for (int pf = 0; pf < 8; pf++) {
        int rr = pf >> 2, cg = pf & 3;
        vb[pf] = ((y0 + rr + 1) * pw + (x0 + cg * 16 + l15 + 1)) * 64 + g * 8;
    }

    for (int tap = 0; tap < 9; tap++) {
        const int toff = ((tap / 3 - 1) * pw + (tap % 3 - 1)) * 64;
#pragma unroll
        for (int ks = 0; ks < 2; ks++) {
            short8v bx[8];
#pragma unroll
            for (int pf = 0; pf < 8; pf++)
                bx[pf] = *(const short8v*)(Xb + vb[pf] + toff + ks * 32);
            const short* wp = WB + (size_t)((tap * 2 + ks) * 2) * (NF * 512) + lane * 8;
#pragma unroll
            for (int hl = 0; hl < 2; hl++) {
#pragma unroll
                for (int n = 0; n < NF; n++) {
                    short8v av = *(const short8v*)(wp + (hl * NF + n) * 512);
#pragma unroll
                    for (int pf = 0; pf < 8; pf++)
                        acc[n][pf] = __builtin_amdgcn_mfma_f32_16x16x32_bf16(
                            av, bx[pf], acc[n][pf], 0, 0, 0);
                }
            }
        }
    }

    const int HW = Hs * Ws;
#pragma unroll
    for (int pf = 0; pf < 8; pf++) {
        int rr = pf >> 2, cg = pf & 3;
        int y = y0 + rr, x = x0 + cg * 16 + l15;
        bool ok = (x < Ws);
        if (EPI == 0) {
            if (!ok) continue;
            short* out = Y + bbase + ((size_t)(y + 1) * pw + (x + 1)) * 64 + g * 4;
#pragma unroll
            for (int n = 0; n < NF; n++) {
                ushort4 v;
                v.x = f2bf(fmaxf(acc[n][pf][0], 0.f));
                v.y = f2bf(fmaxf(acc[n][pf][1], 0.f));
                v.z = f2bf(fmaxf(acc[n][pf][2], 0.f));
                v.w = f2bf(fmaxf(acc[n][pf][3], 0.f));
                *(ushort4*)(out + 16 * n) = v;
            }
        } else {
            float t0 = fabsf(acc[0][pf][0]) + fabsf(acc[0][pf][1]) +
                       fabsf(acc[0][pf][2]) + fabsf(acc[0][pf][3]);
            float s0 = t0 + __shfl_xor(t0, 16, 64);
            float t1 = fabsf(acc[1][pf][0]) + fabsf(acc[1][pf][1]) +
                       fabsf(acc[1][pf][2]) + fabsf(acc[1][pf][3]);
            float s1 = t1 + __shfl_xor(t1, 16, 64);
            float inv0 = 1.f / (s0 + 1e-6f);
            float inv1 = 1.f / (s1 + 1e-6f);
            float a0[4], a1[4];
#pragma unroll
            for (int j = 0; j < 4; j++) { a0[j] = acc[0][pf][j] * inv0; a1[j] = acc[1][pf][j] * inv1; }
            float p0 = a0[0] + a0[1] + a0[2] + a0[3];
            float c0 = p0 + __shfl_xor(p0, 16, 64);
            float p1 = a1[0] + a1[1] + a1[2] + a1[3];
            float c1 = p1 + __shfl_xor(p1, 16, 64);

            int pix = y * Ws + x;
            if (ok) {
#pragma unroll
                for (int j = 0; j < 4; j++) {
                    int ch = g * 4 + j;
                    reinterpret_cast<unsigned short*>(Aout)[((size_t)(b * 24 + ch)) * HW + pix] = f2bf(a0[j]);
                }
                if (g < 2) {
#pragma unroll
                    for (int j = 0; j < 4; j++) {
                        int ch = 16 + g * 4 + j;
                        reinterpret_cast<unsigned short*>(Aout)[((size_t)(b * 24 + ch)) * HW + pix] = f2bf(a1[j]);
                    }
                }
                if (g == 0) {
                    cen[((size_t)(b * 3 + 0)) * HW + pix] = 1.f - c0;
                    cen[((size_t)(b * 3 + 2)) * HW + pix] = 1.f - c1;
                }
                if (g == 2) {
                    cen[((size_t)(b * 3 + 1)) * HW + pix] = 1.f - c0;
                    float e0 = acc[1][pf][0], e1 = acc[1][pf][1], e2 = acc[1][pf][2];
                    float m = fmaxf(e0, fmaxf(e1, e2));
                    float x0e = expf(e0 - m), x1e = expf(e1 - m), x2e = expf(e2 - m);
                    float is = 1.f / (x0e + x1e + x2e);
                    sig[((size_t)(b * 3 + 0)) * HW + pix] = x0e * is;
                    sig[((size_t)(b * 3 + 1)) * HW + pix] = x1e * is;
                    sig[((size_t)(b * 3 + 2)) * HW + pix] = x2e * is;
                }
                if (g == 3) {
                    float dsum[3] = {0.f, 0.f, 0.f};
#pragma unroll
                    for (int t = 0; t < 9; t++) {
                        int yy = y + t / 3 - 1;
                        int xx = x + t % 3 - 1;
                        if ((unsigned)yy < (unsigned)Hs && (unsigned)xx < (unsigned)Ws) {
                            float dv = Dcur[(size_t)b * HW + (size_t)yy * Ws + xx] * 0.1f;
#pragma unroll
                            for (int j = 0; j < 3; j++)
                                dsum[j] = fmaf(wc[(size_t)(j * 65 + 64) * 9 + t], dv, dsum[j]);
                        }
                    }
#pragma unroll
                    for (int j = 0; j < 3; j++) {
                        float z = acc[1][pf][j] + dsum[j];
                        float sg = 1.f / (1.f + expf(-z));
                        kap[((size_t)(b * 3 + j)) * HW + pix] = 0.1f + 0.9f * sg;
                    }
                }
            }
        }
    }
}

// ---------------- one CSPN propagation step (A in bf16) ----------------
__global__ __launch_bounds__(256) void prop_k(const float* __restrict__ D,
        const unsigned short* __restrict__ A, const float* __restrict__ cen,
        const float* __restrict__ sig, const float* __restrict__ kap,
        const float* __restrict__ xbuf, float* __restrict__ Dn, int Hs, int Ws) {
    int gid = blockIdx.x * 256 + threadIdx.x;
    int HW = Hs * Ws;
    if (gid >= BN * HW) return;
    int b = gid / HW;
    int p = gid - b * HW;
    int y = p / Ws;
    int x = p - y * Ws;
    const float* Db = D + (size_t)b * HW;
    float Dc = Db[p];
    const int dy_[8] = {-1, -1, -1, 0, 0, 1, 1, 1};
    const int dx_[8] = {-1, 0, 1, -1, 1, -1, 0, 1};
    float mix = 0.f;
#pragma unroll
    for (int k = 0; k < 3; k++) {
        int d = 1 << k;
        float s = cen[(size_t)(b * 3 + k) * HW + p] * Dc;
#pragma unroll
        for (int j = 0; j < 8; j++) {
            int yy = y + dy_[j] * d;
            int xx = x + dx_[j] * d;
            float nb = ((unsigned)yy < (unsigned)Hs && (unsigned)xx < (unsigned)Ws)
                           ? Db[(size_t)yy * Ws + xx] : 0.f;
            s = fmaf(bf2f(A[(size_t)(b * 24 + k * 8 + j) * HW + p]), nb, s);
        }
        float kp = kap[(size_t)(b * 3 + k) * HW + p];
        mix += sig[(size_t)(b * 3 + k) * HW + p] * (Dc + kp * (s - Dc));
    }
    float dl = xbuf[(size_t)(b * 6 + 3) * HW + p];
    float ml = xbuf[(size_t)(b * 6 + 4) * HW + p];
    Dn[(size_t)b * HW + p] = ml * (0.9f * dl + 0.1f * mix) + (1.f - ml) * mix;
}

extern "C" void kernel_launch(void* const* d_in, const int* in_sizes, int n_in,
                              void* d_out, int out_size, void* d_ws, size_t ws_size,
                              hipStream_t stream) {
    const float* I  = (const float*)d_in[0];
    const float* DL = (const float*)d_in[1];
    const float* ML = (const float*)d_in[2];
    const float* E  = (const float*)d_in[3];
    const float* w0 = (const float*)d_in[4];  const float* b0 = (const float*)d_in[5];
    const float* w1 = (const float*)d_in[6];  const float* b1 = (const float*)d_in[7];
    const float* w2 = (const float*)d_in[8];  const float* b2 = (const float*)d_in[9];
    const float* wa = (const float*)d_in[10]; const float* ba = (const float*)d_in[11];
    const float* wg = (const float*)d_in[12]; const float* bg = (const float*)d_in[13];
    const float* wc = (const float*)d_in[14]; const float* bc = (const float*)d_in[15];

    size_t off = 0;
    auto carve = [&](size_t bytes) -> void* {
        void* pp = (char*)d_ws + off;
        off = (off + bytes + 255) & ~(size_t)255;
        return pp;
    };
    float* xbuf  = (float*)carve((size_t)BN * 6 * HW1 * 4);
    bf16*  Abuf  = (bf16*)carve((size_t)BN * 24 * HW1 * 2);
    float* cen   = (float*)carve((size_t)BN * 3 * HW1 * 4);
    float* sig   = (float*)carve((size_t)BN * 3 * HW1 * 4);
    float* kap   = (float*)carve((size_t)BN * 3 * HW1 * 4);
    float* D0    = (float*)carve((size_t)BN * HW1 * 4);
    float* D1    = (float*)carve((size_t)BN * HW1 * 4);
    float* Dprev = (float*)carve((size_t)BN * HW1 * 4);
    size_t padElems = (size_t)BN * (H0 + 6) * (W0 + 2) * 64;
    short* padA = (short*)carve(padElems * 2 + 65536);
    short* padB = (short*)carve(padElems * 2 + 65536);
    short* xpad = (short*)carve((size_t)BN * (H0 + 6) * (W0 + 2) * 8 * 2 + 65536);
    short* WB1  = (short*)carve((size_t)18 * 2 * 4 * 512 * 2);
    short* WB2  = (short*)carve((size_t)18 * 2 * 4 * 512 * 2);
    short* WBh  = (short*)carve((size_t)18 * 2 * 2 * 512 * 2);
    short* WB0  = (short*)carve((size_t)3 * 2 * 4 * 512 * 2);
    float* hb   = (float*)carve(32 * 4);
    if (off > ws_size) return;

    wtr2_k<<<(18 * 2 * 4 * 512 + 255) / 256, 256, 0, stream>>>(w1, WB1);
    wtr2_k<<<(18 * 2 * 4 * 512 + 255) / 256, 256, 0, stream>>>(w2, WB2);
    whb_k<<<(18 * 2 * 2 * 512 + 255) / 256, 256, 0, stream>>>(wa, wg, wc, WBh);
    wtr0_k<<<(3 * 2 * 4 * 512 + 255) / 256, 256, 0, stream>>>(w0, WB0);
    hbias_k<<<1, 32, 0, stream>>>(ba, bg, bc, hb);

    const int scales[3] = {4, 2, 1};
    for (int si = 0; si < 3; si++) {
        int s = scales[si];
        int Hs = H0 / s, Ws = W0 / s, HW = Hs * Ws;
        int pw = Ws + 2;
        int nb3 = (BN * 3 * HW + 255) / 256;
        int nb1 = (BN * 1 * HW + 255) / 256;
        int nbp = (BN * HW + 255) / 256;

        resize_aa_k<<<nb3, 256, 0, stream>>>(I, H0, W0, xbuf, Hs, Ws, s, 3, 0, 0);
        resize_aa_k<<<nb1, 256, 0, stream>>>(E, H0, W0, xbuf, Hs, Ws, s, 1, 5, 1);
        downsp_k<<<nbp, 256, 0, stream>>>(DL, ML, xbuf, Hs, Ws, s);
        if (si == 0)
            dinit_first_k<<<nbp, 256, 0, stream>>>(xbuf, D0, Hs, Ws);
        else
            dinit_blend_k<<<nbp, 256, 0, stream>>>(Dprev, xbuf, D0, Hs, Ws);

        int npack = (BN * (Hs + 2) * pw + 255) / 256;
        xpack_k<<<npack, 256, 0, stream>>>(xbuf, xpad, Hs, Ws);
        int nhalo = (4 * (2 * pw + 2 * Hs) + 255) / 256;
        halo0_k<<<nhalo, 256, 0, stream>>>(padA, padB, Hs, Ws);

        int tX = (Ws + 63) / 64;
        int tY = Hs / 8;
        dim3 gmm(tX * tY, BN);
        conv0mm_k<<<gmm, 256, 0, stream>>>(xpad, WB0, b0, padA, Hs, Ws, tX);
        convmm_k<4, 0><<<gmm, 256, 0, stream>>>(padA, WB1, b1, padB,
            nullptr, nullptr, nullptr, nullptr, nullptr, nullptr, Hs, Ws, tX);
        convmm_k<4, 0><<<gmm, 256, 0, stream>>>(padB, WB2, b2, padA,
            nullptr, nullptr, nullptr, nullptr, nullptr, nullptr, Hs, Ws, tX);
        convmm_k<2, 1><<<gmm, 256, 0, stream>>>(padA, WBh, hb, nullptr,
            Abuf, cen, sig, kap, D0, wc, Hs, Ws, tX);

        float* Dc = D0;
        float* Dn = D1;
        for (int t = 0; t < 6; t++) {
            prop_k<<<nbp, 256, 0, stream>>>(Dc, (const unsigned short*)Abuf, cen, sig, kap,
                                            xbuf, Dn, Hs, Ws);
            float* tmp = Dc; Dc = Dn; Dn = tmp;
        }
        if (si < 2)
            hipMemcpyAsync(Dprev, Dc, (size_t)BN * HW * 4, hipMemcpyDeviceToDevice, stream);
        else
            hipMemcpyAsync(d_out, Dc, (size_t)BN * HW * 4, hipMemcpyDeviceToDevice, stream);
    }
}

// Round 4
// 1044.050 us; speedup vs baseline: 5.2904x; 1.0287x over previous
//
#include <hip/hip_runtime.h>
#include <hip/hip_bf16.h>

typedef __hip_bfloat16 bf16;
typedef __attribute__((ext_vector_type(8))) short short8v;
typedef __attribute__((ext_vector_type(4))) float f32x4;

static constexpr int BN = 2;
static constexpr int H0 = 480, W0 = 640;
static constexpr int HW1 = H0 * W0;

__device__ __forceinline__ unsigned short f2bf(float f) {
    bf16 h = __float2bfloat16(f);
    return reinterpret_cast<unsigned short&>(h);
}
__device__ __forceinline__ float bf2f(unsigned short u) {
    bf16 h; reinterpret_cast<unsigned short&>(h) = u;
    return __bfloat162float(h);
}

// ---------------- MFMA weight transform (64->64), hi/lo split ----------------
// WB flat: (((tap*2+ks)*2+hl)*4+n)*512 + lane*8 + i    (NF=4)
__global__ void wtr2_k(const float* __restrict__ w, short* __restrict__ WB) {
    int gid = blockIdx.x * 256 + threadIdx.x;
    if (gid >= 18 * 2 * 4 * 512) return;
    int ie = gid & 7;
    int l  = (gid >> 3) & 63;
    int n  = (gid >> 9) & 3;
    int hl = (gid >> 11) & 1;
    int t2 = gid >> 12;            // 0..17
    int tap = t2 >> 1, ks = t2 & 1;
    int o = 16 * n + (l & 15);
    int c = 32 * ks + (l >> 4) * 8 + ie;
    float wv = w[(size_t)(o * 64 + c) * 9 + tap];
    bf16 hi = __float2bfloat16(wv);
    float hif = __bfloat162float(hi);
    bf16 lo = __float2bfloat16(wv - hif);
    WB[gid] = hl ? reinterpret_cast<short&>(lo) : reinterpret_cast<short&>(hi);
}

// ---------------- conv0 MFMA weight transform (6ch+9tap -> K-slots), hi/lo ----------------
__global__ void wtr0_k(const float* __restrict__ w, short* __restrict__ WB) {
    int gid = blockIdx.x * 256 + threadIdx.x;
    if (gid >= 3 * 2 * 4 * 512) return;
    int ie = gid & 7;
    int l  = (gid >> 3) & 63;
    int n  = (gid >> 9) & 3;
    int hl = (gid >> 11) & 1;
    int j  = gid >> 12;            // 0..2
    int o = 16 * n + (l & 15);
    int g = l >> 4;
    int tap = 4 * j + g;
    float wv = (tap < 9 && ie < 6) ? w[(size_t)(o * 6 + ie) * 9 + tap] : 0.f;
    bf16 hi = __float2bfloat16(wv);
    float hif = __bfloat162float(hi);
    bf16 lo = __float2bfloat16(wv - hif);
    WB[gid] = hl ? reinterpret_cast<short&>(lo) : reinterpret_cast<short&>(hi);
}

// ---------------- head weight transform (aff24+gate3+curv3 -> 32ch), hi/lo ----------------
__global__ void whb_k(const float* __restrict__ wa, const float* __restrict__ wg,
                      const float* __restrict__ wc, short* __restrict__ WB) {
    int gid = blockIdx.x * 256 + threadIdx.x;
    if (gid >= 18 * 2 * 2 * 512) return;
    int ie = gid & 7;
    int l  = (gid >> 3) & 63;
    int n  = (gid >> 9) & 1;
    int hl = (gid >> 10) & 1;
    int t2 = gid >> 11;
    int tap = t2 >> 1, ks = t2 & 1;
    int o = 16 * n + (l & 15);     // 0..31
    int c = 32 * ks + (l >> 4) * 8 + ie;
    float wv = 0.f;
    if (o < 24)                 wv = wa[(size_t)(o * 64 + c) * 9 + tap];
    else if (o >= 24 && o < 27) wv = wg[(size_t)((o - 24) * 64 + c) * 9 + tap];
    else if (o >= 28 && o < 31) wv = wc[(size_t)((o - 28) * 65 + c) * 9 + tap];
    bf16 hi = __float2bfloat16(wv);
    float hif = __bfloat162float(hi);
    bf16 lo = __float2bfloat16(wv - hif);
    WB[gid] = hl ? reinterpret_cast<short&>(lo) : reinterpret_cast<short&>(hi);
}

__global__ void hbias_k(const float* __restrict__ ba, const float* __restrict__ bg,
                        const float* __restrict__ bc, float* __restrict__ hb) {
    int o = threadIdx.x;
    if (o >= 32) return;
    float v = 0.f;
    if (o < 24) v = ba[o];
    else if (o < 27) v = bg[o - 24];
    else if (o >= 28 && o < 31) v = bc[o - 28];
    hb[o] = v;
}

// ---------------- antialiased "linear" resize (JAX semantics), factor f in {1,2,4} ----------------
__global__ void resize_aa_k(const float* __restrict__ in, int Hin, int Win,
                            float* __restrict__ xout, int Hs, int Ws, int f,
                            int C, int c0, int clip01) {
    int gid = blockIdx.x * 256 + threadIdx.x;
    int HWs = Hs * Ws;
    int total = BN * C * HWs;
    if (gid >= total) return;
    int ox = gid % Ws;
    int t1 = gid / Ws;
    int oy = t1 % Hs;
    int t2 = t1 / Hs;
    int c = t2 % C;
    int b = t2 / C;
    const float* ip = in + (size_t)(b * C + c) * Hin * Win;

    float wy[8], wx[8];
    int nt = 2 * f;
    float sy = (oy + 0.5f) * f - 0.5f;
    int jly = f * oy - (f + 1) / 2;
    float wys = 0.f;
    for (int t = 0; t < nt; t++) {
        int j = jly + t;
        float w = 1.f - fabsf(sy - (float)j) / (float)f;
        w = fmaxf(w, 0.f);
        if (j < 0 || j >= Hin) w = 0.f;
        wy[t] = w; wys += w;
    }
    float sx = (ox + 0.5f) * f - 0.5f;
    int jlx = f * ox - (f + 1) / 2;
    float wxs = 0.f;
    for (int t = 0; t < nt; t++) {
        int j = jlx + t;
        float w = 1.f - fabsf(sx - (float)j) / (float)f;
        w = fmaxf(w, 0.f);
        if (j < 0 || j >= Win) w = 0.f;
        wx[t] = w; wxs += w;
    }
    float acc = 0.f;
    for (int ty = 0; ty < nt; ty++) {
        if (wy[ty] == 0.f) continue;
        const float* row = ip + (size_t)(jly + ty) * Win;
        float r = 0.f;
        for (int tx = 0; tx < nt; tx++) {
            if (wx[tx] == 0.f) continue;
            r += wx[tx] * row[jlx + tx];
        }
        acc += wy[ty] * r;
    }
    acc /= (wys * wxs);
    if (clip01) acc = fminf(fmaxf(acc, 0.f), 1.f);
    xout[(size_t)(b * 6 + c0 + c) * HWs + (size_t)oy * Ws + ox] = acc;
}

// ---------------- sparse-depth valid-mean pooling -> xbuf planes 3,4 + DLM plane ----------------
__global__ void downsp_k(const float* __restrict__ DL, const float* __restrict__ ML,
                         float* __restrict__ xout, float* __restrict__ dlm,
                         int Hs, int Ws, int k) {
    int gid = blockIdx.x * 256 + threadIdx.x;
    int HWs = Hs * Ws;
    if (gid >= BN * HWs) return;
    int ox = gid % Ws;
    int oy = (gid / Ws) % Hs;
    int b = gid / HWs;
    float s = 0.f, c = 0.f;
    for (int dy = 0; dy < k; dy++) {
        for (int dx = 0; dx < k; dx++) {
            size_t idx = ((size_t)b * H0 + (oy * k + dy)) * W0 + (ox * k + dx);
            float m = ML[idx] > 0.f ? 1.f : 0.f;
            s += DL[idx] * m;
            c += m;
        }
    }
    int p = oy * Ws + ox;
    float mls = c > 0.f ? 1.f : 0.f;
    float dls = c > 0.f ? s / (c + 1e-6f) : 0.f;
    xout[(size_t)(b * 6 + 3) * HWs + p] = dls;
    xout[(size_t)(b * 6 + 4) * HWs + p] = mls;
    dlm[(size_t)b * HWs + p] = c > 0.f ? dls : -1.f;
}

// ---------------- pack xbuf (6 fp32 planes) -> channel-last padded bf16 [b][yp][xp][8] ----------------
__global__ void xpack_k(const float* __restrict__ xbuf, short* __restrict__ Xp,
                        int Hs, int Ws) {
    int pw = Ws + 2;
    int gid = blockIdx.x * 256 + threadIdx.x;
    int total = BN * (Hs + 2) * pw;
    if (gid >= total) return;
    int xp = gid % pw;
    int yp = (gid / pw) % (Hs + 2);
    int b = gid / (pw * (Hs + 2));
    short8v v = {0, 0, 0, 0, 0, 0, 0, 0};
    if (yp >= 1 && yp <= Hs && xp >= 1 && xp <= Ws) {
        int HW = Hs * Ws;
        int p = (yp - 1) * Ws + (xp - 1);
#pragma unroll
        for (int c = 0; c < 6; c++)
            v[c] = (short)f2bf(xbuf[(size_t)(b * 6 + c) * HW + p]);
    }
    *(short8v*)(Xp + (((size_t)b * (Hs + 6) + 2 + yp) * pw + xp) * 8) = v;
}

// ---------------- D init, first scale ----------------
__global__ void dinit_first_k(const float* __restrict__ xbuf, float* __restrict__ D0,
                              int Hs, int Ws) {
    int gid = blockIdx.x * 256 + threadIdx.x;
    int HW = Hs * Ws;
    if (gid >= BN * HW) return;
    int b = gid / HW;
    int p = gid - b * HW;
    float e = xbuf[(size_t)(b * 6 + 5) * HW + p];
    D0[gid] = fminf(fmaxf(e * 10.f, 0.f), 10.f);
}

// ---------------- D init, later scales ----------------
__global__ void dinit_blend_k(const float* __restrict__ Dp, const float* __restrict__ xbuf,
                              float* __restrict__ D0, int Hs, int Ws) {
    int gid = blockIdx.x * 256 + threadIdx.x;
    int HW = Hs * Ws;
    if (gid >= BN * HW) return;
    int ox = gid % Ws;
    int oy = (gid / Ws) % Hs;
    int b = gid / HW;
    int hp = Hs / 2, wp = Ws / 2;
    const float* P = Dp + (size_t)b * hp * wp;

    float ty = 0.5f * oy - 0.25f;
    int jy = (int)floorf(ty);
    float fy = ty - jy;
    float wy0 = 1.f - fy, wy1 = fy;
    bool v0 = (jy >= 0) && (jy < hp);
    bool v1 = (jy + 1 >= 0) && (jy + 1 < hp);
    if (!v0) wy0 = 0.f;
    if (!v1) wy1 = 0.f;
    float wys = wy0 + wy1;

    float tx = 0.5f * ox - 0.25f;
    int jx = (int)floorf(tx);
    float fx = tx - jx;
    float wx0 = 1.f - fx, wx1 = fx;
    bool u0 = (jx >= 0) && (jx < wp);
    bool u1 = (jx + 1 >= 0) && (jx + 1 < wp);
    if (!u0) wx0 = 0.f;
    if (!u1) wx1 = 0.f;
    float wxs = wx0 + wx1;

    int jy0c = v0 ? jy : 0, jy1c = v1 ? (jy + 1) : 0;
    int jx0c = u0 ? jx : 0, jx1c = u1 ? (jx + 1) : 0;
    float up = wy0 * (wx0 * P[(size_t)jy0c * wp + jx0c] + wx1 * P[(size_t)jy0c * wp + jx1c])
             + wy1 * (wx0 * P[(size_t)jy1c * wp + jx0c] + wx1 * P[(size_t)jy1c * wp + jx1c]);
    up /= (wys * wxs);

    const float* E = xbuf + (size_t)(b * 6 + 5) * HW;
    float e = E[(size_t)oy * Ws + ox];
    float gx = (ox > 0) ? fabsf(e - E[(size_t)oy * Ws + ox - 1]) : 0.f;
    float gy = (oy > 0) ? fabsf(e - E[(size_t)(oy - 1) * Ws + ox]) : 0.f;
    float g = fminf(fmaxf(0.5f * (gx + gy), 0.f), 1.f);
    float w = 0.7f * fminf(fmaxf(1.f - g * 10.f, 0.f), 1.f);
    float Pv = fminf(fmaxf(e * 10.f, 0.f), 10.f);
    D0[gid] = w * up + (1.f - w) * Pv;
}

// ---------------- zero halos of both padded feature buffers ----------------
__global__ void halo0_k(short* __restrict__ A, short* __restrict__ B2, int Hs, int Ws) {
    int pw = Ws + 2;
    int ne = 2 * pw + 2 * Hs;
    int total = 4 * ne;
    int gid = blockIdx.x * 256 + threadIdx.x;
    if (gid >= total) return;
    int e = gid % ne;
    int t = gid / ne;
    int b = t & 1;
    int buf = t >> 1;
    int yp, xp;
    if (e < pw)            { yp = 0;      xp = e; }
    else if (e < 2 * pw)   { yp = Hs + 1; xp = e - pw; }
    else { int e2 = e - 2 * pw; yp = 1 + (e2 >> 1); xp = (e2 & 1) ? (Ws + 1) : 0; }
    short* p = (buf ? B2 : A) + (((size_t)b * (Hs + 6) + 2 + yp) * pw + xp) * 64;
    short8v z = {0, 0, 0, 0, 0, 0, 0, 0};
#pragma unroll
    for (int j = 0; j < 8; j++) *(short8v*)(p + j * 8) = z;
}

// bijective XCD-chunked swizzle (m204)
__device__ __forceinline__ int xcd_swz(int orig, int nwg) {
    int q = nwg >> 3, r = nwg & 7;
    int xcd = orig & 7, idx = orig >> 3;
    return (xcd < r ? xcd * (q + 1) : r * (q + 1) + (xcd - r) * q) + idx;
}

// ---------------- conv0: 6->64 MFMA implicit GEMM (K padded to 96 = 3 x K32) ----------------
// wave = 1 output row x 64 px
__global__ __launch_bounds__(256, 3) void conv0mm_k(
        const short* __restrict__ Xp, const short* __restrict__ WB,
        const float* __restrict__ bias, short* __restrict__ Y,
        int Hs, int Ws, int tX) {
    const int pw = Ws + 2;
    const int lane = threadIdx.x & 63;
    const int wv = threadIdx.x >> 6;
    const int b = blockIdx.y;
    const int l15 = lane & 15;
    const int g = lane >> 4;
    int wg = xcd_swz(blockIdx.x, gridDim.x);
    int ty = wg / tX, txi = wg - ty * tX;
    const int y = ty * 4 + wv;
    const int x0 = txi * 64;

    const size_t bbase8 = ((size_t)b * (Hs + 6) + 2) * pw * 8;
    const short* Xb = Xp + bbase8;

    f32x4 acc[4][4];
#pragma unroll
    for (int n = 0; n < 4; n++) {
        f32x4 bv;
#pragma unroll
        for (int j = 0; j < 4; j++) bv[j] = bias[16 * n + g * 4 + j];
#pragma unroll
        for (int cg = 0; cg < 4; cg++) acc[n][cg] = bv;
    }

    int vb[4];
#pragma unroll
    for (int cg = 0; cg < 4; cg++)
        vb[cg] = ((y + 1) * pw + (x0 + cg * 16 + l15 + 1)) * 8;

#pragma unroll
    for (int j = 0; j < 3; j++) {
        int tap = 4 * j + g;
        if (tap > 8) tap = 8;
        int toff = ((tap / 3 - 1) * pw + (tap % 3 - 1)) * 8;
        short8v bx[4];
#pragma unroll
        for (int cg = 0; cg < 4; cg++)
            bx[cg] = *(const short8v*)(Xb + vb[cg] + toff);
        const short* wp = WB + (size_t)j * (2 * 4 * 512) + lane * 8;
#pragma unroll
        for (int hl = 0; hl < 2; hl++) {
#pragma unroll
            for (int n = 0; n < 4; n++) {
                short8v av = *(const short8v*)(wp + (hl * 4 + n) * 512);
#pragma unroll
                for (int cg = 0; cg < 4; cg++)
                    acc[n][cg] = __builtin_amdgcn_mfma_f32_16x16x32_bf16(
                        av, bx[cg], acc[n][cg], 0, 0, 0);
            }
        }
    }

    const size_t bbase = ((size_t)b * (Hs + 6) + 2) * pw * 64;
#pragma unroll
    for (int cg = 0; cg < 4; cg++) {
        int x = x0 + cg * 16 + l15;
        if (x >= Ws) continue;
        short* out = Y + bbase + ((size_t)(y + 1) * pw + (x + 1)) * 64 + g * 4;
#pragma unroll
        for (int n = 0; n < 4; n++) {
            ushort4 v;
            v.x = f2bf(fmaxf(acc[n][cg][0], 0.f));
            v.y = f2bf(fmaxf(acc[n][cg][1], 0.f));
            v.z = f2bf(fmaxf(acc[n][cg][2], 0.f));
            v.w = f2bf(fmaxf(acc[n][cg][3], 0.f));
            *(ushort4*)(out + 16 * n) = v;
        }
    }
}

// ---------------- MFMA implicit-GEMM 3x3 conv ----------------
// block = 4 waves; wave = 1 output row x 64 px; B-fragment double-buffer prefetch.
// EPI 0: relu -> bf16 channel-last padded Y.  EPI 1: head epilogue (NF=2) -> A,cen,sk.
template <int NF, int EPI>
__global__ __launch_bounds__(256, 3) void convmm_k(
        const short* __restrict__ X, const short* __restrict__ WB,
        const float* __restrict__ bias, short* __restrict__ Y,
        bf16* __restrict__ Aout, float* __restrict__ cen,
        float* __restrict__ sk,
        const float* __restrict__ Dcur, const float* __restrict__ wc,
        int Hs, int Ws, int tX) {
    const int pw = Ws + 2;
    const int lane = threadIdx.x & 63;
    const int wv = threadIdx.x >> 6;
    const int b = blockIdx.y;
    const int l15 = lane & 15;
    const int g = lane >> 4;
    int wg = xcd_swz(blockIdx.x, gridDim.x);
    int ty = wg / tX, txi = wg - ty * tX;
    const int y = ty * 4 + wv;
    const int x0 = txi * 64;

    const size_t bbase = ((size_t)b * (Hs + 6) + 2) * pw * 64;
    const short* Xb = X + bbase;

    f32x4 acc[NF][4];
#pragma unroll
    for (int n = 0; n < NF; n++) {
        f32x4 bv;
#pragma unroll
        for (int j = 0; j < 4; j++) bv[j] = bias[16 * n + g * 4 + j];
#pragma unroll
        for (int cg = 0; cg < 4; cg++) acc[n][cg] = bv;
    }

    int vb[4];
#pragma unroll
    for (int cg = 0; cg < 4; cg++)
        vb[cg] = ((y + 1) * pw + (x0 + cg * 16 + l15 + 1)) * 64 + g * 8;

    short8v bxA[4], bxB[4];
    auto LD = [&](short8v* bx, int st) {
        int tap = st >> 1, ks = st & 1;
        int toff = ((tap / 3 - 1) * pw + (tap % 3 - 1)) * 64 + ks * 32;
#pragma unroll
        for (int cg = 0; cg < 4; cg++)
            bx[cg] = *(const short8v*)(Xb + vb[cg] + toff);
    };
    LD(bxA, 0);

#pragma unroll
    for (int st = 0; st < 18; st++) {
        short8v* cur = (st & 1) ? bxB : bxA;
        short8v* nxt = (st & 1) ? bxA : bxB;
        if (st < 17) LD(nxt, st + 1);
        const short* wp = WB + (size_t)(st * 2) * (NF * 512) + lane * 8;
#pragma unroll
        for (int hl = 0; hl < 2; hl++) {
#pragma unroll
            for (int n = 0; n < NF; n++) {
                short8v av = *(const short8v*)(wp + (hl * NF + n) * 512);
#pragma unroll
                for (int cg = 0; cg < 4; cg++)
                    acc[n][cg] = __builtin_amdgcn_mfma_f32_16x16x32_bf16(
                        av, cur[cg], acc[n][cg], 0, 0, 0);
            }
        }
    }

    const int HW = Hs * Ws;
#pragma unroll
    for (int cg = 0; cg < 4; cg++) {
        int x = x0 + cg * 16 + l15;
        bool ok = (x < Ws);
        if (EPI == 0) {
            if (!ok) continue;
            short* out = Y + bbase + ((size_t)(y + 1) * pw + (x + 1)) * 64 + g * 4;
#pragma unroll
            for (int n = 0; n < NF; n++) {
                ushort4 v;
                v.x = f2bf(fmaxf(acc[n][cg][0], 0.f));
                v.y = f2bf(fmaxf(acc[n][cg][1], 0.f));
                v.z = f2bf(fmaxf(acc[n][cg][2], 0.f));
                v.w = f2bf(fmaxf(acc[n][cg][3], 0.f));
                *(ushort4*)(out + 16 * n) = v;
            }
        } else {
            // --- head epilogue ---
            float t0 = fabsf(acc[0][cg][0]) + fabsf(acc[0][cg][1]) +
                       fabsf(acc[0][cg][2]) + fabsf(acc[0][cg][3]);
            float s0 = t0 + __shfl_xor(t0, 16, 64);
            float t1 = fabsf(acc[1][cg][0]) + fabsf(acc[1][cg][1]) +
                       fabsf(acc[1][cg][2]) + fabsf(acc[1][cg][3]);
            float s1 = t1 + __shfl_xor(t1, 16, 64);
            float inv0 = 1.f / (s0 + 1e-6f);
            float inv1 = 1.f / (s1 + 1e-6f);
            float a0[4], a1[4];
#pragma unroll
            for (int j = 0; j < 4; j++) { a0[j] = acc[0][cg][j] * inv0; a1[j] = acc[1][cg][j] * inv1; }
            float p0 = a0[0] + a0[1] + a0[2] + a0[3];
            float c0 = p0 + __shfl_xor(p0, 16, 64);
            float p1 = a1[0] + a1[1] + a1[2] + a1[3];
            float c1 = p1 + __shfl_xor(p1, 16, 64);

            // gate softmax (valid on g==2 lanes), share to g==3 via xor16
            float e0 = acc[1][cg][0], e1 = acc[1][cg][1], e2 = acc[1][cg][2];
            float m = fmaxf(e0, fmaxf(e1, e2));
            float q0 = expf(e0 - m), q1 = expf(e1 - m), q2 = expf(e2 - m);
            float qs = 1.f / (q0 + q1 + q2);
            float sg0 = q0 * qs, sg1 = q1 * qs, sg2 = q2 * qs;
            float r0 = __shfl_xor(sg0, 16, 64);
            float r1 = __shfl_xor(sg1, 16, 64);
            float r2 = __shfl_xor(sg2, 16, 64);

            int pix = y * Ws + x;
            if (ok) {
#pragma unroll
                for (int j = 0; j < 4; j++) {
                    int ch = g * 4 + j;
                    reinterpret_cast<unsigned short*>(Aout)[((size_t)(b * 24 + ch)) * HW + pix] = f2bf(a0[j]);
                }
                if (g < 2) {
#pragma unroll
                    for (int j = 0; j < 4; j++) {
                        int ch = 16 + g * 4 + j;
                        reinterpret_cast<unsigned short*>(Aout)[((size_t)(b * 24 + ch)) * HW + pix] = f2bf(a1[j]);
                    }
                }
                if (g == 0) {
                    cen[((size_t)(b * 3 + 0)) * HW + pix] = 1.f - c0;
                    cen[((size_t)(b * 3 + 2)) * HW + pix] = 1.f - c1;
                }
                if (g == 2) {
                    cen[((size_t)(b * 3 + 1)) * HW + pix] = 1.f - c0;
                }
                if (g == 3) {
                    // kappa (ch 28..30) incl. D-channel taps; store sk = sigma*kappa
                    float dsum[3] = {0.f, 0.f, 0.f};
#pragma unroll
                    for (int t = 0; t < 9; t++) {
                        int yy = y + t / 3 - 1;
                        int xx = x + t % 3 - 1;
                        if ((unsigned)yy < (unsigned)Hs && (unsigned)xx < (unsigned)Ws) {
                            float dv = Dcur[(size_t)b * HW + (size_t)yy * Ws + xx] * 0.1f;
#pragma unroll
                            for (int j = 0; j < 3; j++)
                                dsum[j] = fmaf(wc[(size_t)(j * 65 + 64) * 9 + t], dv, dsum[j]);
                        }
                    }
                    float rr[3] = {r0, r1, r2};
#pragma unroll
                    for (int j = 0; j < 3; j++) {
                        float z = acc[1][cg][j] + dsum[j];
                        float kp = 0.1f + 0.9f / (1.f + expf(-z));
                        sk[((size_t)(b * 3 + j)) * HW + pix] = rr[j] * kp;
                    }
                }
            }
        }
    }
}

// ---------------- one CSPN propagation step ----------------
// mix = D + sum_k sk_k * (agg_k - D), with agg_k = cen_k*D + sum_j A_kj*nb_j
__global__ __launch_bounds__(256) void prop_k(const float* __restrict__ D,
        const unsigned short* __restrict__ A, const float* __restrict__ cen,
        const float* __restrict__ sk, const float* __restrict__ dlm,
        float* __restrict__ Dn, int Hs, int Ws) {
    int gid = blockIdx.x * 256 + threadIdx.x;
    int HW = Hs * Ws;
    if (gid >= BN * HW) return;
    int b = gid / HW;
    int p = gid - b * HW;
    int y = p / Ws;
    int x = p - y * Ws;
    const float* Db = D + (size_t)b * HW;
    float Dc = Db[p];
    const int dy_[8] = {-1, -1, -1, 0, 0, 1, 1, 1};
    const int dx_[8] = {-1, 0, 1, -1, 1, -1, 0, 1};
    float mix = Dc;
#pragma unroll
    for (int k = 0; k < 3; k++) {
        int d = 1 << k;
        float s = cen[(size_t)(b * 3 + k) * HW + p] * Dc;
#pragma unroll
        for (int j = 0; j < 8; j++) {
            int yy = y + dy_[j] * d;
            int xx = x + dx_[j] * d;
            float nb = ((unsigned)yy < (unsigned)Hs && (unsigned)xx < (unsigned)Ws)
                           ? Db[(size_t)yy * Ws + xx] : 0.f;
            s = fmaf(bf2f(A[(size_t)(b * 24 + k * 8 + j) * HW + p]), nb, s);
        }
        mix += sk[(size_t)(b * 3 + k) * HW + p] * (s - Dc);
    }
    float v = dlm[(size_t)b * HW + p];
    float ml = v >= 0.f ? 1.f : 0.f;
    float dl = v >= 0.f ? v : 0.f;
    Dn[(size_t)b * HW + p] = ml * (0.9f * dl + 0.1f * mix) + (1.f - ml) * mix;
}

extern "C" void kernel_launch(void* const* d_in, const int* in_sizes, int n_in,
                              void* d_out, int out_size, void* d_ws, size_t ws_size,
                              hipStream_t stream) {
    const float* I  = (const float*)d_in[0];
    const float* DL = (const float*)d_in[1];
    const float* ML = (const float*)d_in[2];
    const float* E  = (const float*)d_in[3];
    const float* w0 = (const float*)d_in[4];  const float* b0 = (const float*)d_in[5];
    const float* w1 = (const float*)d_in[6];  const float* b1 = (const float*)d_in[7];
    const float* w2 = (const float*)d_in[8];  const float* b2 = (const float*)d_in[9];
    const float* wa = (const float*)d_in[10]; const float* ba = (const float*)d_in[11];
    const float* wg = (const float*)d_in[12]; const float* bg = (const float*)d_in[13];
    const float* wc = (const float*)d_in[14]; const float* bc = (const float*)d_in[15];

    size_t off = 0;
    auto carve = [&](size_t bytes) -> void* {
        void* pp = (char*)d_ws + off;
        off = (off + bytes + 255) & ~(size_t)255;
        return pp;
    };
    float* xbuf  = (float*)carve((size_t)BN * 6 * HW1 * 4);
    bf16*  Abuf  = (bf16*)carve((size_t)BN * 24 * HW1 * 2);
    float* cen   = (float*)carve((size_t)BN * 3 * HW1 * 4);
    float* sk    = (float*)carve((size_t)BN * 3 * HW1 * 4);
    float* dlm   = (float*)carve((size_t)BN * HW1 * 4);
    float* D0    = (float*)carve((size_t)BN * HW1 * 4);
    float* D1    = (float*)carve((size_t)BN * HW1 * 4);
    float* Dprev = (float*)carve((size_t)BN * HW1 * 4);
    size_t padElems = (size_t)BN * (H0 + 6) * (W0 + 2) * 64;
    short* padA = (short*)carve(padElems * 2 + 65536);
    short* padB = (short*)carve(padElems * 2 + 65536);
    short* xpad = (short*)carve((size_t)BN * (H0 + 6) * (W0 + 2) * 8 * 2 + 65536);
    short* WB1  = (short*)carve((size_t)18 * 2 * 4 * 512 * 2);
    short* WB2  = (short*)carve((size_t)18 * 2 * 4 * 512 * 2);
    short* WBh  = (short*)carve((size_t)18 * 2 * 2 * 512 * 2);
    short* WB0  = (short*)carve((size_t)3 * 2 * 4 * 512 * 2);
    float* hb   = (float*)carve(32 * 4);
    if (off > ws_size) return;

    wtr2_k<<<(18 * 2 * 4 * 512 + 255) / 256, 256, 0, stream>>>(w1, WB1);
    wtr2_k<<<(18 * 2 * 4 * 512 + 255) / 256, 256, 0, stream>>>(w2, WB2);
    whb_k<<<(18 * 2 * 2 * 512 + 255) / 256, 256, 0, stream>>>(wa, wg, wc, WBh);
    wtr0_k<<<(3 * 2 * 4 * 512 + 255) / 256, 256, 0, stream>>>(w0, WB0);
    hbias_k<<<1, 32, 0, stream>>>(ba, bg, bc, hb);

    const int scales[3] = {4, 2, 1};
    for (int si = 0; si < 3; si++) {
        int s = scales[si];
        int Hs = H0 / s, Ws = W0 / s, HW = Hs * Ws;
        int pw = Ws + 2;
        int nb3 = (BN * 3 * HW + 255) / 256;
        int nb1 = (BN * 1 * HW + 255) / 256;
        int nbp = (BN * HW + 255) / 256;

        resize_aa_k<<<nb3, 256, 0, stream>>>(I, H0, W0, xbuf, Hs, Ws, s, 3, 0, 0);
        resize_aa_k<<<nb1, 256, 0, stream>>>(E, H0, W0, xbuf, Hs, Ws, s, 1, 5, 1);
        downsp_k<<<nbp, 256, 0, stream>>>(DL, ML, xbuf, dlm, Hs, Ws, s);
        if (si == 0)
            dinit_first_k<<<nbp, 256, 0, stream>>>(xbuf, D0, Hs, Ws);
        else
            dinit_blend_k<<<nbp, 256, 0, stream>>>(Dprev, xbuf, D0, Hs, Ws);

        int npack = (BN * (Hs + 2) * pw + 255) / 256;
        xpack_k<<<npack, 256, 0, stream>>>(xbuf, xpad, Hs, Ws);
        int nhalo = (4 * (2 * pw + 2 * Hs) + 255) / 256;
        halo0_k<<<nhalo, 256, 0, stream>>>(padA, padB, Hs, Ws);

        int tX = (Ws + 63) / 64;
        int tY = Hs / 4;
        dim3 gmm(tX * tY, BN);
        conv0mm_k<<<gmm, 256, 0, stream>>>(xpad, WB0, b0, padA, Hs, Ws, tX);
        convmm_k<4, 0><<<gmm, 256, 0, stream>>>(padA, WB1, b1, padB,
            nullptr, nullptr, nullptr, nullptr, nullptr, Hs, Ws, tX);
        convmm_k<4, 0><<<gmm, 256, 0, stream>>>(padB, WB2, b2, padA,
            nullptr, nullptr, nullptr, nullptr, nullptr, Hs, Ws, tX);
        convmm_k<2, 1><<<gmm, 256, 0, stream>>>(padA, WBh, hb, nullptr,
            Abuf, cen, sk, D0, wc, Hs, Ws, tX);

        float* Dc = D0;
        float* Dn = D1;
        float* fin = (si < 2) ? Dprev : (float*)d_out;
        for (int t = 0; t < 6; t++) {
            float* tgt = (t == 5) ? fin : Dn;
            prop_k<<<nbp, 256, 0, stream>>>(Dc, (const unsigned short*)Abuf, cen, sk,
                                            dlm, tgt, Hs, Ws);
            if (t < 5) { float* tmp = Dc; Dc = Dn; Dn = tmp; }
        }
    }
}

// Round 5
// 977.466 us; speedup vs baseline: 5.6508x; 1.0681x over previous
//
#include <hip/hip_runtime.h>
#include <hip/hip_bf16.h>

typedef __hip_bfloat16 bf16;
typedef __attribute__((ext_vector_type(8))) short short8v;
typedef __attribute__((ext_vector_type(4))) float f32x4;

static constexpr int BN = 2;
static constexpr int H0 = 480, W0 = 640;
static constexpr int HW1 = H0 * W0;

__device__ __forceinline__ unsigned short f2bf(float f) {
    bf16 h = __float2bfloat16(f);
    return reinterpret_cast<unsigned short&>(h);
}
__device__ __forceinline__ float bf2f(unsigned short u) {
    bf16 h; reinterpret_cast<unsigned short&>(h) = u;
    return __bfloat162float(h);
}

// ---------------- MFMA weight transform (64->64), hi/lo split ----------------
// WB flat: (((tap*2+ks)*2+hl)*4+n)*512 + lane*8 + i    (NF=4)
__global__ void wtr2_k(const float* __restrict__ w, short* __restrict__ WB) {
    int gid = blockIdx.x * 256 + threadIdx.x;
    if (gid >= 18 * 2 * 4 * 512) return;
    int ie = gid & 7;
    int l  = (gid >> 3) & 63;
    int n  = (gid >> 9) & 3;
    int hl = (gid >> 11) & 1;
    int t2 = gid >> 12;            // 0..17
    int tap = t2 >> 1, ks = t2 & 1;
    int o = 16 * n + (l & 15);
    int c = 32 * ks + (l >> 4) * 8 + ie;
    float wv = w[(size_t)(o * 64 + c) * 9 + tap];
    bf16 hi = __float2bfloat16(wv);
    float hif = __bfloat162float(hi);
    bf16 lo = __float2bfloat16(wv - hif);
    WB[gid] = hl ? reinterpret_cast<short&>(lo) : reinterpret_cast<short&>(hi);
}

// ---------------- conv0 MFMA weight transform (6ch+9tap -> K-slots), hi/lo ----------------
__global__ void wtr0_k(const float* __restrict__ w, short* __restrict__ WB) {
    int gid = blockIdx.x * 256 + threadIdx.x;
    if (gid >= 3 * 2 * 4 * 512) return;
    int ie = gid & 7;
    int l  = (gid >> 3) & 63;
    int n  = (gid >> 9) & 3;
    int hl = (gid >> 11) & 1;
    int j  = gid >> 12;            // 0..2
    int o = 16 * n + (l & 15);
    int g = l >> 4;
    int tap = 4 * j + g;
    float wv = (tap < 9 && ie < 6) ? w[(size_t)(o * 6 + ie) * 9 + tap] : 0.f;
    bf16 hi = __float2bfloat16(wv);
    float hif = __bfloat162float(hi);
    bf16 lo = __float2bfloat16(wv - hif);
    WB[gid] = hl ? reinterpret_cast<short&>(lo) : reinterpret_cast<short&>(hi);
}

// ---------------- head weight transform (aff24+gate3+curv3 -> 32ch), hi/lo ----------------
__global__ void whb_k(const float* __restrict__ wa, const float* __restrict__ wg,
                      const float* __restrict__ wc, short* __restrict__ WB) {
    int gid = blockIdx.x * 256 + threadIdx.x;
    if (gid >= 18 * 2 * 2 * 512) return;
    int ie = gid & 7;
    int l  = (gid >> 3) & 63;
    int n  = (gid >> 9) & 1;
    int hl = (gid >> 10) & 1;
    int t2 = gid >> 11;
    int tap = t2 >> 1, ks = t2 & 1;
    int o = 16 * n + (l & 15);     // 0..31
    int c = 32 * ks + (l >> 4) * 8 + ie;
    float wv = 0.f;
    if (o < 24)                 wv = wa[(size_t)(o * 64 + c) * 9 + tap];
    else if (o >= 24 && o < 27) wv = wg[(size_t)((o - 24) * 64 + c) * 9 + tap];
    else if (o >= 28 && o < 31) wv = wc[(size_t)((o - 28) * 65 + c) * 9 + tap];
    bf16 hi = __float2bfloat16(wv);
    float hif = __bfloat162float(hi);
    bf16 lo = __float2bfloat16(wv - hif);
    WB[gid] = hl ? reinterpret_cast<short&>(lo) : reinterpret_cast<short&>(hi);
}

__global__ void hbias_k(const float* __restrict__ ba, const float* __restrict__ bg,
                        const float* __restrict__ bc, float* __restrict__ hb) {
    int o = threadIdx.x;
    if (o >= 32) return;
    float v = 0.f;
    if (o < 24) v = ba[o];
    else if (o < 27) v = bg[o - 24];
    else if (o >= 28 && o < 31) v = bc[o - 28];
    hb[o] = v;
}

// ---------------- fused per-scale prep: resize I(3) + resize E + down_sparse ----------------
// writes channel-last padded bf16 xpad[b][yp][xp][8] = {I0,I1,I2,DLs,MLs,Es,0,0},
// plus fp32 E plane and fused DL/ML plane (dlm = DLs if ML else -1).
template <int F>
__global__ void prep_k(const float* __restrict__ I, const float* __restrict__ DL,
                       const float* __restrict__ ML, const float* __restrict__ E,
                       short* __restrict__ Xp, float* __restrict__ Ebuf,
                       float* __restrict__ dlm, int Hs, int Ws) {
    const int pw = Ws + 2;
    int gid = blockIdx.x * 256 + threadIdx.x;
    int total = BN * (Hs + 2) * pw;
    if (gid >= total) return;
    int xp = gid % pw;
    int yp = (gid / pw) % (Hs + 2);
    int b = gid / (pw * (Hs + 2));
    short8v v = {0, 0, 0, 0, 0, 0, 0, 0};
    if (yp >= 1 && yp <= Hs && xp >= 1 && xp <= Ws) {
        int oy = yp - 1, ox = xp - 1;
        constexpr int NT = 2 * F;
        float wy[NT], wx[NT];
        float sy = (oy + 0.5f) * F - 0.5f;
        int jly = F * oy - (F + 1) / 2;
        float wys = 0.f;
#pragma unroll
        for (int t = 0; t < NT; t++) {
            int j = jly + t;
            float w = fmaxf(1.f - fabsf(sy - (float)j) / (float)F, 0.f);
            if (j < 0 || j >= H0) w = 0.f;
            wy[t] = w; wys += w;
        }
        float sx = (ox + 0.5f) * F - 0.5f;
        int jlx = F * ox - (F + 1) / 2;
        float wxs = 0.f;
#pragma unroll
        for (int t = 0; t < NT; t++) {
            int j = jlx + t;
            float w = fmaxf(1.f - fabsf(sx - (float)j) / (float)F, 0.f);
            if (j < 0 || j >= W0) w = 0.f;
            wx[t] = w; wxs += w;
        }
        float inv = 1.f / (wys * wxs);
        // 3 image channels
#pragma unroll
        for (int c = 0; c < 3; c++) {
            const float* ip = I + (size_t)(b * 3 + c) * HW1;
            float acc = 0.f;
#pragma unroll
            for (int ty = 0; ty < NT; ty++) {
                if (wy[ty] == 0.f) continue;
                const float* row = ip + (size_t)(jly + ty) * W0;
                float r = 0.f;
#pragma unroll
                for (int tx = 0; tx < NT; tx++)
                    if (wx[tx] != 0.f) r += wx[tx] * row[jlx + tx];
                acc += wy[ty] * r;
            }
            v[c] = (short)f2bf(acc * inv);
        }
        // E channel (clipped)
        {
            const float* ip = E + (size_t)b * HW1;
            float acc = 0.f;
#pragma unroll
            for (int ty = 0; ty < NT; ty++) {
                if (wy[ty] == 0.f) continue;
                const float* row = ip + (size_t)(jly + ty) * W0;
                float r = 0.f;
#pragma unroll
                for (int tx = 0; tx < NT; tx++)
                    if (wx[tx] != 0.f) r += wx[tx] * row[jlx + tx];
                acc += wy[ty] * r;
            }
            acc = fminf(fmaxf(acc * inv, 0.f), 1.f);
            v[5] = (short)f2bf(acc);
            Ebuf[(size_t)b * Hs * Ws + oy * Ws + ox] = acc;
        }
        // sparse pooling
        {
            float s = 0.f, c = 0.f;
#pragma unroll
            for (int dy = 0; dy < F; dy++)
#pragma unroll
                for (int dx = 0; dx < F; dx++) {
                    size_t idx = ((size_t)b * H0 + (oy * F + dy)) * W0 + (ox * F + dx);
                    float m = ML[idx] > 0.f ? 1.f : 0.f;
                    s += DL[idx] * m;
                    c += m;
                }
            float dls = c > 0.f ? s / (c + 1e-6f) : 0.f;
            v[3] = (short)f2bf(dls);
            v[4] = (short)f2bf(c > 0.f ? 1.f : 0.f);
            dlm[(size_t)b * Hs * Ws + oy * Ws + ox] = c > 0.f ? dls : -1.f;
        }
    }
    *(short8v*)(Xp + (((size_t)b * (Hs + 6) + 2 + yp) * pw + xp) * 8) = v;
}

// ---------------- D init, first scale ----------------
__global__ void dinit_first_k(const float* __restrict__ Ebuf, float* __restrict__ D0,
                              int Hs, int Ws) {
    int gid = blockIdx.x * 256 + threadIdx.x;
    int HW = Hs * Ws;
    if (gid >= BN * HW) return;
    float e = Ebuf[gid];
    D0[gid] = fminf(fmaxf(e * 10.f, 0.f), 10.f);
}

// ---------------- D init, later scales ----------------
__global__ void dinit_blend_k(const float* __restrict__ Dp, const float* __restrict__ Ebuf,
                              float* __restrict__ D0, int Hs, int Ws) {
    int gid = blockIdx.x * 256 + threadIdx.x;
    int HW = Hs * Ws;
    if (gid >= BN * HW) return;
    int ox = gid % Ws;
    int oy = (gid / Ws) % Hs;
    int b = gid / HW;
    int hp = Hs / 2, wp = Ws / 2;
    const float* P = Dp + (size_t)b * hp * wp;

    float ty = 0.5f * oy - 0.25f;
    int jy = (int)floorf(ty);
    float fy = ty - jy;
    float wy0 = 1.f - fy, wy1 = fy;
    bool v0 = (jy >= 0) && (jy < hp);
    bool v1 = (jy + 1 >= 0) && (jy + 1 < hp);
    if (!v0) wy0 = 0.f;
    if (!v1) wy1 = 0.f;
    float wys = wy0 + wy1;

    float tx = 0.5f * ox - 0.25f;
    int jx = (int)floorf(tx);
    float fx = tx - jx;
    float wx0 = 1.f - fx, wx1 = fx;
    bool u0 = (jx >= 0) && (jx < wp);
    bool u1 = (jx + 1 >= 0) && (jx + 1 < wp);
    if (!u0) wx0 = 0.f;
    if (!u1) wx1 = 0.f;
    float wxs = wx0 + wx1;

    int jy0c = v0 ? jy : 0, jy1c = v1 ? (jy + 1) : 0;
    int jx0c = u0 ? jx : 0, jx1c = u1 ? (jx + 1) : 0;
    float up = wy0 * (wx0 * P[(size_t)jy0c * wp + jx0c] + wx1 * P[(size_t)jy0c * wp + jx1c])
             + wy1 * (wx0 * P[(size_t)jy1c * wp + jx0c] + wx1 * P[(size_t)jy1c * wp + jx1c]);
    up /= (wys * wxs);

    const float* Eb = Ebuf + (size_t)b * HW;
    float e = Eb[(size_t)oy * Ws + ox];
    float gx = (ox > 0) ? fabsf(e - Eb[(size_t)oy * Ws + ox - 1]) : 0.f;
    float gy = (oy > 0) ? fabsf(e - Eb[(size_t)(oy - 1) * Ws + ox]) : 0.f;
    float g = fminf(fmaxf(0.5f * (gx + gy), 0.f), 1.f);
    float w = 0.7f * fminf(fmaxf(1.f - g * 10.f, 0.f), 1.f);
    float Pv = fminf(fmaxf(e * 10.f, 0.f), 10.f);
    D0[gid] = w * up + (1.f - w) * Pv;
}

// ---------------- zero halos of both padded feature buffers ----------------
__global__ void halo0_k(short* __restrict__ A, short* __restrict__ B2, int Hs, int Ws) {
    int pw = Ws + 2;
    int ne = 2 * pw + 2 * Hs;
    int total = 4 * ne;
    int gid = blockIdx.x * 256 + threadIdx.x;
    if (gid >= total) return;
    int e = gid % ne;
    int t = gid / ne;
    int b = t & 1;
    int buf = t >> 1;
    int yp, xp;
    if (e < pw)            { yp = 0;      xp = e; }
    else if (e < 2 * pw)   { yp = Hs + 1; xp = e - pw; }
    else { int e2 = e - 2 * pw; yp = 1 + (e2 >> 1); xp = (e2 & 1) ? (Ws + 1) : 0; }
    short* p = (buf ? B2 : A) + (((size_t)b * (Hs + 6) + 2 + yp) * pw + xp) * 64;
    short8v z = {0, 0, 0, 0, 0, 0, 0, 0};
#pragma unroll
    for (int j = 0; j < 8; j++) *(short8v*)(p + j * 8) = z;
}

// bijective XCD-chunked swizzle (m204)
__device__ __forceinline__ int xcd_swz(int orig, int nwg) {
    int q = nwg >> 3, r = nwg & 7;
    int xcd = orig & 7, idx = orig >> 3;
    return (xcd < r ? xcd * (q + 1) : r * (q + 1) + (xcd - r) * q) + idx;
}

// ---------------- conv0: 6->64 MFMA implicit GEMM (K padded to 96 = 3 x K32) ----------------
__global__ __launch_bounds__(256, 3) void conv0mm_k(
        const short* __restrict__ Xp, const short* __restrict__ WB,
        const float* __restrict__ bias, short* __restrict__ Y,
        int Hs, int Ws, int tX) {
    const int pw = Ws + 2;
    const int lane = threadIdx.x & 63;
    const int wv = threadIdx.x >> 6;
    const int b = blockIdx.y;
    const int l15 = lane & 15;
    const int g = lane >> 4;
    int wg = xcd_swz(blockIdx.x, gridDim.x);
    int ty = wg / tX, txi = wg - ty * tX;
    const int y = ty * 4 + wv;
    const int x0 = txi * 64;

    const size_t bbase8 = ((size_t)b * (Hs + 6) + 2) * pw * 8;
    const short* Xb = Xp + bbase8;

    f32x4 acc[4][4];
#pragma unroll
    for (int n = 0; n < 4; n++) {
        f32x4 bv;
#pragma unroll
        for (int j = 0; j < 4; j++) bv[j] = bias[16 * n + g * 4 + j];
#pragma unroll
        for (int cg = 0; cg < 4; cg++) acc[n][cg] = bv;
    }

    int vb[4];
#pragma unroll
    for (int cg = 0; cg < 4; cg++)
        vb[cg] = ((y + 1) * pw + (x0 + cg * 16 + l15 + 1)) * 8;

#pragma unroll
    for (int j = 0; j < 3; j++) {
        int tap = 4 * j + g;
        if (tap > 8) tap = 8;
        int toff = ((tap / 3 - 1) * pw + (tap % 3 - 1)) * 8;
        short8v bx[4];
#pragma unroll
        for (int cg = 0; cg < 4; cg++)
            bx[cg] = *(const short8v*)(Xb + vb[cg] + toff);
        const short* wp = WB + (size_t)j * (2 * 4 * 512) + lane * 8;
#pragma unroll
        for (int hl = 0; hl < 2; hl++) {
#pragma unroll
            for (int n = 0; n < 4; n++) {
                short8v av = *(const short8v*)(wp + (hl * 4 + n) * 512);
#pragma unroll
                for (int cg = 0; cg < 4; cg++)
                    acc[n][cg] = __builtin_amdgcn_mfma_f32_16x16x32_bf16(
                        av, bx[cg], acc[n][cg], 0, 0, 0);
            }
        }
    }

    const size_t bbase = ((size_t)b * (Hs + 6) + 2) * pw * 64;
#pragma unroll
    for (int cg = 0; cg < 4; cg++) {
        int x = x0 + cg * 16 + l15;
        if (x >= Ws) continue;
        short* out = Y + bbase + ((size_t)(y + 1) * pw + (x + 1)) * 64 + g * 4;
#pragma unroll
        for (int n = 0; n < 4; n++) {
            ushort4 v;
            v.x = f2bf(fmaxf(acc[n][cg][0], 0.f));
            v.y = f2bf(fmaxf(acc[n][cg][1], 0.f));
            v.z = f2bf(fmaxf(acc[n][cg][2], 0.f));
            v.w = f2bf(fmaxf(acc[n][cg][3], 0.f));
            *(ushort4*)(out + 16 * n) = v;
        }
    }
}

// ---------------- MFMA implicit-GEMM 3x3 conv ----------------
// block = 4 waves; wave = 1 output row x 64 px; A AND B register double-buffer prefetch.
// EPI 0: relu -> bf16 channel-last padded Y.  EPI 1: head epilogue (NF=2) -> A,cen,sk.
template <int NF, int EPI>
__global__ __launch_bounds__(256, 2) void convmm_k(
        const short* __restrict__ X, const short* __restrict__ WB,
        const float* __restrict__ bias, short* __restrict__ Y,
        bf16* __restrict__ Aout, float* __restrict__ cen,
        float* __restrict__ sk,
        const float* __restrict__ Dcur, const float* __restrict__ wc,
        int Hs, int Ws, int tX) {
    const int pw = Ws + 2;
    const int lane = threadIdx.x & 63;
    const int wv = threadIdx.x >> 6;
    const int b = blockIdx.y;
    const int l15 = lane & 15;
    const int g = lane >> 4;
    int wg = xcd_swz(blockIdx.x, gridDim.x);
    int ty = wg / tX, txi = wg - ty * tX;
    const int y = ty * 4 + wv;
    const int x0 = txi * 64;

    const size_t bbase = ((size_t)b * (Hs + 6) + 2) * pw * 64;
    const short* Xb = X + bbase;

    f32x4 acc[NF][4];
#pragma unroll
    for (int n = 0; n < NF; n++) {
        f32x4 bv;
#pragma unroll
        for (int j = 0; j < 4; j++) bv[j] = bias[16 * n + g * 4 + j];
#pragma unroll
        for (int cg = 0; cg < 4; cg++) acc[n][cg] = bv;
    }

    int vb[4];
#pragma unroll
    for (int cg = 0; cg < 4; cg++)
        vb[cg] = ((y + 1) * pw + (x0 + cg * 16 + l15 + 1)) * 64 + g * 8;

    short8v bxA[4], bxB[4];
    short8v wfA[2 * NF], wfB[2 * NF];
    auto LDB = [&](short8v* bx, int st) {
        int tap = st >> 1, ks = st & 1;
        int toff = ((tap / 3 - 1) * pw + (tap % 3 - 1)) * 64 + ks * 32;
#pragma unroll
        for (int cg = 0; cg < 4; cg++)
            bx[cg] = *(const short8v*)(Xb + vb[cg] + toff);
    };
    auto LDW = [&](short8v* w, int st) {
        const short* wp = WB + (size_t)(st * 2) * (NF * 512) + lane * 8;
#pragma unroll
        for (int q = 0; q < 2 * NF; q++)
            w[q] = *(const short8v*)(wp + q * 512);
    };
    LDB(bxA, 0);
    LDW(wfA, 0);

#pragma unroll
    for (int st = 0; st < 18; st++) {
        short8v* bcur = (st & 1) ? bxB : bxA;
        short8v* bnxt = (st & 1) ? bxA : bxB;
        short8v* wcur = (st & 1) ? wfB : wfA;
        short8v* wnxt = (st & 1) ? wfA : wfB;
        if (st < 17) { LDB(bnxt, st + 1); LDW(wnxt, st + 1); }
#pragma unroll
        for (int hl = 0; hl < 2; hl++) {
#pragma unroll
            for (int n = 0; n < NF; n++) {
#pragma unroll
                for (int cg = 0; cg < 4; cg++)
                    acc[n][cg] = __builtin_amdgcn_mfma_f32_16x16x32_bf16(
                        wcur[hl * NF + n], bcur[cg], acc[n][cg], 0, 0, 0);
            }
        }
    }

    const int HW = Hs * Ws;
#pragma unroll
    for (int cg = 0; cg < 4; cg++) {
        int x = x0 + cg * 16 + l15;
        bool ok = (x < Ws);
        if (EPI == 0) {
            if (!ok) continue;
            short* out = Y + bbase + ((size_t)(y + 1) * pw + (x + 1)) * 64 + g * 4;
#pragma unroll
            for (int n = 0; n < NF; n++) {
                ushort4 v;
                v.x = f2bf(fmaxf(acc[n][cg][0], 0.f));
                v.y = f2bf(fmaxf(acc[n][cg][1], 0.f));
                v.z = f2bf(fmaxf(acc[n][cg][2], 0.f));
                v.w = f2bf(fmaxf(acc[n][cg][3], 0.f));
                *(ushort4*)(out + 16 * n) = v;
            }
        } else {
            // --- head epilogue ---
            float t0 = fabsf(acc[0][cg][0]) + fabsf(acc[0][cg][1]) +
                       fabsf(acc[0][cg][2]) + fabsf(acc[0][cg][3]);
            float s0 = t0 + __shfl_xor(t0, 16, 64);
            float t1 = fabsf(acc[1][cg][0]) + fabsf(acc[1][cg][1]) +
                       fabsf(acc[1][cg][2]) + fabsf(acc[1][cg][3]);
            float s1 = t1 + __shfl_xor(t1, 16, 64);
            float inv0 = 1.f / (s0 + 1e-6f);
            float inv1 = 1.f / (s1 + 1e-6f);
            float a0[4], a1[4];
#pragma unroll
            for (int j = 0; j < 4; j++) { a0[j] = acc[0][cg][j] * inv0; a1[j] = acc[1][cg][j] * inv1; }
            float p0 = a0[0] + a0[1] + a0[2] + a0[3];
            float c0 = p0 + __shfl_xor(p0, 16, 64);
            float p1 = a1[0] + a1[1] + a1[2] + a1[3];
            float c1 = p1 + __shfl_xor(p1, 16, 64);

            // gate softmax (valid on g==2 lanes), share to g==3 via xor16
            float e0 = acc[1][cg][0], e1 = acc[1][cg][1], e2 = acc[1][cg][2];
            float m = fmaxf(e0, fmaxf(e1, e2));
            float q0 = expf(e0 - m), q1 = expf(e1 - m), q2 = expf(e2 - m);
            float qs = 1.f / (q0 + q1 + q2);
            float sg0 = q0 * qs, sg1 = q1 * qs, sg2 = q2 * qs;
            float r0 = __shfl_xor(sg0, 16, 64);
            float r1 = __shfl_xor(sg1, 16, 64);
            float r2 = __shfl_xor(sg2, 16, 64);

            int pix = y * Ws + x;
            if (ok) {
#pragma unroll
                for (int j = 0; j < 4; j++) {
                    int ch = g * 4 + j;
                    reinterpret_cast<unsigned short*>(Aout)[((size_t)(b * 24 + ch)) * HW + pix] = f2bf(a0[j]);
                }
                if (g < 2) {
#pragma unroll
                    for (int j = 0; j < 4; j++) {
                        int ch = 16 + g * 4 + j;
                        reinterpret_cast<unsigned short*>(Aout)[((size_t)(b * 24 + ch)) * HW + pix] = f2bf(a1[j]);
                    }
                }
                if (g == 0) {
                    cen[((size_t)(b * 3 + 0)) * HW + pix] = 1.f - c0;
                    cen[((size_t)(b * 3 + 2)) * HW + pix] = 1.f - c1;
                }
                if (g == 2) {
                    cen[((size_t)(b * 3 + 1)) * HW + pix] = 1.f - c0;
                }
                if (g == 3) {
                    // kappa (ch 28..30) incl. D-channel taps; store sk = sigma*kappa
                    float dsum[3] = {0.f, 0.f, 0.f};
#pragma unroll
                    for (int t = 0; t < 9; t++) {
                        int yy = y + t / 3 - 1;
                        int xx = x + t % 3 - 1;
                        if ((unsigned)yy < (unsigned)Hs && (unsigned)xx < (unsigned)Ws) {
                            float dv = Dcur[(size_t)b * HW + (size_t)yy * Ws + xx] * 0.1f;
#pragma unroll
                            for (int j = 0; j < 3; j++)
                                dsum[j] = fmaf(wc[(size_t)(j * 65 + 64) * 9 + t], dv, dsum[j]);
                        }
                    }
                    float rr[3] = {r0, r1, r2};
#pragma unroll
                    for (int j = 0; j < 3; j++) {
                        float z = acc[1][cg][j] + dsum[j];
                        float kp = 0.1f + 0.9f / (1.f + expf(-z));
                        sk[((size_t)(b * 3 + j)) * HW + pix] = rr[j] * kp;
                    }
                }
            }
        }
    }
}

// ---------------- one CSPN propagation step ----------------
__global__ __launch_bounds__(256) void prop_k(const float* __restrict__ D,
        const unsigned short* __restrict__ A, const float* __restrict__ cen,
        const float* __restrict__ sk, const float* __restrict__ dlm,
        float* __restrict__ Dn, int Hs, int Ws) {
    int gid = blockIdx.x * 256 + threadIdx.x;
    int HW = Hs * Ws;
    if (gid >= BN * HW) return;
    int b = gid / HW;
    int p = gid - b * HW;
    int y = p / Ws;
    int x = p - y * Ws;
    const float* Db = D + (size_t)b * HW;
    float Dc = Db[p];
    const int dy_[8] = {-1, -1, -1, 0, 0, 1, 1, 1};
    const int dx_[8] = {-1, 0, 1, -1, 1, -1, 0, 1};
    float mix = Dc;
#pragma unroll
    for (int k = 0; k < 3; k++) {
        int d = 1 << k;
        float s = cen[(size_t)(b * 3 + k) * HW + p] * Dc;
#pragma unroll
        for (int j = 0; j < 8; j++) {
            int yy = y + dy_[j] * d;
            int xx = x + dx_[j] * d;
            float nb = ((unsigned)yy < (unsigned)Hs && (unsigned)xx < (unsigned)Ws)
                           ? Db[(size_t)yy * Ws + xx] : 0.f;
            s = fmaf(bf2f(A[(size_t)(b * 24 + k * 8 + j) * HW + p]), nb, s);
        }
        mix += sk[(size_t)(b * 3 + k) * HW + p] * (s - Dc);
    }
    float v = dlm[(size_t)b * HW + p];
    float ml = v >= 0.f ? 1.f : 0.f;
    float dl = v >= 0.f ? v : 0.f;
    Dn[(size_t)b * HW + p] = ml * (0.9f * dl + 0.1f * mix) + (1.f - ml) * mix;
}

extern "C" void kernel_launch(void* const* d_in, const int* in_sizes, int n_in,
                              void* d_out, int out_size, void* d_ws, size_t ws_size,
                              hipStream_t stream) {
    const float* I  = (const float*)d_in[0];
    const float* DL = (const float*)d_in[1];
    const float* ML = (const float*)d_in[2];
    const float* E  = (const float*)d_in[3];
    const float* w0 = (const float*)d_in[4];  const float* b0 = (const float*)d_in[5];
    const float* w1 = (const float*)d_in[6];  const float* b1 = (const float*)d_in[7];
    const float* w2 = (const float*)d_in[8];  const float* b2 = (const float*)d_in[9];
    const float* wa = (const float*)d_in[10]; const float* ba = (const float*)d_in[11];
    const float* wg = (const float*)d_in[12]; const float* bg = (const float*)d_in[13];
    const float* wc = (const float*)d_in[14]; const float* bc = (const float*)d_in[15];

    size_t off = 0;
    auto carve = [&](size_t bytes) -> void* {
        void* pp = (char*)d_ws + off;
        off = (off + bytes + 255) & ~(size_t)255;
        return pp;
    };
    bf16*  Abuf  = (bf16*)carve((size_t)BN * 24 * HW1 * 2);
    float* cen   = (float*)carve((size_t)BN * 3 * HW1 * 4);
    float* sk    = (float*)carve((size_t)BN * 3 * HW1 * 4);
    float* dlm   = (float*)carve((size_t)BN * HW1 * 4);
    float* Ebuf  = (float*)carve((size_t)BN * HW1 * 4);
    float* D0    = (float*)carve((size_t)BN * HW1 * 4);
    float* D1    = (float*)carve((size_t)BN * HW1 * 4);
    float* Dprev = (float*)carve((size_t)BN * HW1 * 4);
    size_t padElems = (size_t)BN * (H0 + 6) * (W0 + 2) * 64;
    short* padA = (short*)carve(padElems * 2 + 65536);
    short* padB = (short*)carve(padElems * 2 + 65536);
    short* xpad = (short*)carve((size_t)BN * (H0 + 6) * (W0 + 2) * 8 * 2 + 65536);
    short* WB1  = (short*)carve((size_t)18 * 2 * 4 * 512 * 2);
    short* WB2  = (short*)carve((size_t)18 * 2 * 4 * 512 * 2);
    short* WBh  = (short*)carve((size_t)18 * 2 * 2 * 512 * 2);
    short* WB0  = (short*)carve((size_t)3 * 2 * 4 * 512 * 2);
    float* hb   = (float*)carve(32 * 4);
    if (off > ws_size) return;

    wtr2_k<<<(18 * 2 * 4 * 512 + 255) / 256, 256, 0, stream>>>(w1, WB1);
    wtr2_k<<<(18 * 2 * 4 * 512 + 255) / 256, 256, 0, stream>>>(w2, WB2);
    whb_k<<<(18 * 2 * 2 * 512 + 255) / 256, 256, 0, stream>>>(wa, wg, wc, WBh);
    wtr0_k<<<(3 * 2 * 4 * 512 + 255) / 256, 256, 0, stream>>>(w0, WB0);
    hbias_k<<<1, 32, 0, stream>>>(ba, bg, bc, hb);

    const int scales[3] = {4, 2, 1};
    for (int si = 0; si < 3; si++) {
        int s = scales[si];
        int Hs = H0 / s, Ws = W0 / s, HW = Hs * Ws;
        int pw = Ws + 2;
        int nbp = (BN * HW + 255) / 256;
        int nprep = (BN * (Hs + 2) * pw + 255) / 256;

        if (s == 4)      prep_k<4><<<nprep, 256, 0, stream>>>(I, DL, ML, E, xpad, Ebuf, dlm, Hs, Ws);
        else if (s == 2) prep_k<2><<<nprep, 256, 0, stream>>>(I, DL, ML, E, xpad, Ebuf, dlm, Hs, Ws);
        else             prep_k<1><<<nprep, 256, 0, stream>>>(I, DL, ML, E, xpad, Ebuf, dlm, Hs, Ws);

        if (si == 0)
            dinit_first_k<<<nbp, 256, 0, stream>>>(Ebuf, D0, Hs, Ws);
        else
            dinit_blend_k<<<nbp, 256, 0, stream>>>(Dprev, Ebuf, D0, Hs, Ws);

        int nhalo = (4 * (2 * pw + 2 * Hs) + 255) / 256;
        halo0_k<<<nhalo, 256, 0, stream>>>(padA, padB, Hs, Ws);

        int tX = (Ws + 63) / 64;
        int tY = Hs / 4;
        dim3 gmm(tX * tY, BN);
        conv0mm_k<<<gmm, 256, 0, stream>>>(xpad, WB0, b0, padA, Hs, Ws, tX);
        convmm_k<4, 0><<<gmm, 256, 0, stream>>>(padA, WB1, b1, padB,
            nullptr, nullptr, nullptr, nullptr, nullptr, Hs, Ws, tX);
        convmm_k<4, 0><<<gmm, 256, 0, stream>>>(padB, WB2, b2, padA,
            nullptr, nullptr, nullptr, nullptr, nullptr, Hs, Ws, tX);
        convmm_k<2, 1><<<gmm, 256, 0, stream>>>(padA, WBh, hb, nullptr,
            Abuf, cen, sk, D0, wc, Hs, Ws, tX);

        float* Dc = D0;
        float* Dn = D1;
        float* fin = (si < 2) ? Dprev : (float*)d_out;
        for (int t = 0; t < 6; t++) {
            float* tgt = (t == 5) ? fin : Dn;
            prop_k<<<nbp, 256, 0, stream>>>(Dc, (const unsigned short*)Abuf, cen, sk,
                                            dlm, tgt, Hs, Ws);
            if (t < 5) { float* tmp = Dc; Dc = Dn; Dn = tmp; }
        }
    }
}

// Round 6
// 770.278 us; speedup vs baseline: 7.1707x; 1.2690x over previous
//
#include <hip/hip_runtime.h>
#include <hip/hip_bf16.h>

typedef __hip_bfloat16 bf16;
typedef __attribute__((ext_vector_type(8))) short short8v;
typedef __attribute__((ext_vector_type(4))) float f32x4;

static constexpr int BN = 2;
static constexpr int H0 = 480, W0 = 640;
static constexpr int HW1 = H0 * W0;

__device__ __forceinline__ unsigned short f2bf(float f) {
    bf16 h = __float2bfloat16(f);
    return reinterpret_cast<unsigned short&>(h);
}
__device__ __forceinline__ float bf2f(unsigned short u) {
    bf16 h; reinterpret_cast<unsigned short&>(h) = u;
    return __bfloat162float(h);
}

// ---------------- MFMA weight transform (64->64), hi/lo split ----------------
// WB flat: (((tap*2+ks)*2+hl)*4+n)*512 + lane*8 + i    (NF=4)
__global__ void wtr2_k(const float* __restrict__ w, short* __restrict__ WB) {
    int gid = blockIdx.x * 256 + threadIdx.x;
    if (gid >= 18 * 2 * 4 * 512) return;
    int ie = gid & 7;
    int l  = (gid >> 3) & 63;
    int n  = (gid >> 9) & 3;
    int hl = (gid >> 11) & 1;
    int t2 = gid >> 12;            // 0..17
    int tap = t2 >> 1, ks = t2 & 1;
    int o = 16 * n + (l & 15);
    int c = 32 * ks + (l >> 4) * 8 + ie;
    float wv = w[(size_t)(o * 64 + c) * 9 + tap];
    bf16 hi = __float2bfloat16(wv);
    float hif = __bfloat162float(hi);
    bf16 lo = __float2bfloat16(wv - hif);
    WB[gid] = hl ? reinterpret_cast<short&>(lo) : reinterpret_cast<short&>(hi);
}

// ---------------- conv0 MFMA weight transform (6ch+9tap -> K-slots), hi/lo ----------------
__global__ void wtr0_k(const float* __restrict__ w, short* __restrict__ WB) {
    int gid = blockIdx.x * 256 + threadIdx.x;
    if (gid >= 3 * 2 * 4 * 512) return;
    int ie = gid & 7;
    int l  = (gid >> 3) & 63;
    int n  = (gid >> 9) & 3;
    int hl = (gid >> 11) & 1;
    int j  = gid >> 12;            // 0..2
    int o = 16 * n + (l & 15);
    int g = l >> 4;
    int tap = 4 * j + g;
    float wv = (tap < 9 && ie < 6) ? w[(size_t)(o * 6 + ie) * 9 + tap] : 0.f;
    bf16 hi = __float2bfloat16(wv);
    float hif = __bfloat162float(hi);
    bf16 lo = __float2bfloat16(wv - hif);
    WB[gid] = hl ? reinterpret_cast<short&>(lo) : reinterpret_cast<short&>(hi);
}

// ---------------- head weight transform (aff24+gate3+curv3 -> 32ch), hi/lo ----------------
__global__ void whb_k(const float* __restrict__ wa, const float* __restrict__ wg,
                      const float* __restrict__ wc, short* __restrict__ WB) {
    int gid = blockIdx.x * 256 + threadIdx.x;
    if (gid >= 18 * 2 * 2 * 512) return;
    int ie = gid & 7;
    int l  = (gid >> 3) & 63;
    int n  = (gid >> 9) & 1;
    int hl = (gid >> 10) & 1;
    int t2 = gid >> 11;
    int tap = t2 >> 1, ks = t2 & 1;
    int o = 16 * n + (l & 15);     // 0..31
    int c = 32 * ks + (l >> 4) * 8 + ie;
    float wv = 0.f;
    if (o < 24)                 wv = wa[(size_t)(o * 64 + c) * 9 + tap];
    else if (o >= 24 && o < 27) wv = wg[(size_t)((o - 24) * 64 + c) * 9 + tap];
    else if (o >= 28 && o < 31) wv = wc[(size_t)((o - 28) * 65 + c) * 9 + tap];
    bf16 hi = __float2bfloat16(wv);
    float hif = __bfloat162float(hi);
    bf16 lo = __float2bfloat16(wv - hif);
    WB[gid] = hl ? reinterpret_cast<short&>(lo) : reinterpret_cast<short&>(hi);
}

__global__ void hbias_k(const float* __restrict__ ba, const float* __restrict__ bg,
                        const float* __restrict__ bc, float* __restrict__ hb) {
    int o = threadIdx.x;
    if (o >= 32) return;
    float v = 0.f;
    if (o < 24) v = ba[o];
    else if (o < 27) v = bg[o - 24];
    else if (o >= 28 && o < 31) v = bc[o - 28];
    hb[o] = v;
}

// ---------------- fused per-scale prep: resize I(3) + resize E + down_sparse ----------------
template <int F>
__global__ void prep_k(const float* __restrict__ I, const float* __restrict__ DL,
                       const float* __restrict__ ML, const float* __restrict__ E,
                       short* __restrict__ Xp, float* __restrict__ Ebuf,
                       float* __restrict__ dlm, int Hs, int Ws) {
    const int pw = Ws + 2;
    int gid = blockIdx.x * 256 + threadIdx.x;
    int total = BN * (Hs + 2) * pw;
    if (gid >= total) return;
    int xp = gid % pw;
    int yp = (gid / pw) % (Hs + 2);
    int b = gid / (pw * (Hs + 2));
    short8v v = {0, 0, 0, 0, 0, 0, 0, 0};
    if (yp >= 1 && yp <= Hs && xp >= 1 && xp <= Ws) {
        int oy = yp - 1, ox = xp - 1;
        constexpr int NT = 2 * F;
        float wy[NT], wx[NT];
        float sy = (oy + 0.5f) * F - 0.5f;
        int jly = F * oy - (F + 1) / 2;
        float wys = 0.f;
#pragma unroll
        for (int t = 0; t < NT; t++) {
            int j = jly + t;
            float w = fmaxf(1.f - fabsf(sy - (float)j) / (float)F, 0.f);
            if (j < 0 || j >= H0) w = 0.f;
            wy[t] = w; wys += w;
        }
        float sx = (ox + 0.5f) * F - 0.5f;
        int jlx = F * ox - (F + 1) / 2;
        float wxs = 0.f;
#pragma unroll
        for (int t = 0; t < NT; t++) {
            int j = jlx + t;
            float w = fmaxf(1.f - fabsf(sx - (float)j) / (float)F, 0.f);
            if (j < 0 || j >= W0) w = 0.f;
            wx[t] = w; wxs += w;
        }
        float inv = 1.f / (wys * wxs);
#pragma unroll
        for (int c = 0; c < 3; c++) {
            const float* ip = I + (size_t)(b * 3 + c) * HW1;
            float acc = 0.f;
#pragma unroll
            for (int ty = 0; ty < NT; ty++) {
                if (wy[ty] == 0.f) continue;
                const float* row = ip + (size_t)(jly + ty) * W0;
                float r = 0.f;
#pragma unroll
                for (int tx = 0; tx < NT; tx++)
                    if (wx[tx] != 0.f) r += wx[tx] * row[jlx + tx];
                acc += wy[ty] * r;
            }
            v[c] = (short)f2bf(acc * inv);
        }
        {
            const float* ip = E + (size_t)b * HW1;
            float acc = 0.f;
#pragma unroll
            for (int ty = 0; ty < NT; ty++) {
                if (wy[ty] == 0.f) continue;
                const float* row = ip + (size_t)(jly + ty) * W0;
                float r = 0.f;
#pragma unroll
                for (int tx = 0; tx < NT; tx++)
                    if (wx[tx] != 0.f) r += wx[tx] * row[jlx + tx];
                acc += wy[ty] * r;
            }
            acc = fminf(fmaxf(acc * inv, 0.f), 1.f);
            v[5] = (short)f2bf(acc);
            Ebuf[(size_t)b * Hs * Ws + oy * Ws + ox] = acc;
        }
        {
            float s = 0.f, c = 0.f;
#pragma unroll
            for (int dy = 0; dy < F; dy++)
#pragma unroll
                for (int dx = 0; dx < F; dx++) {
                    size_t idx = ((size_t)b * H0 + (oy * F + dy)) * W0 + (ox * F + dx);
                    float m = ML[idx] > 0.f ? 1.f : 0.f;
                    s += DL[idx] * m;
                    c += m;
                }
            float dls = c > 0.f ? s / (c + 1e-6f) : 0.f;
            v[3] = (short)f2bf(dls);
            v[4] = (short)f2bf(c > 0.f ? 1.f : 0.f);
            dlm[(size_t)b * Hs * Ws + oy * Ws + ox] = c > 0.f ? dls : -1.f;
        }
    }
    *(short8v*)(Xp + (((size_t)b * (Hs + 6) + 2 + yp) * pw + xp) * 8) = v;
}

// ---------------- D init, first scale ----------------
__global__ void dinit_first_k(const float* __restrict__ Ebuf, float* __restrict__ D0,
                              int Hs, int Ws) {
    int gid = blockIdx.x * 256 + threadIdx.x;
    int HW = Hs * Ws;
    if (gid >= BN * HW) return;
    float e = Ebuf[gid];
    D0[gid] = fminf(fmaxf(e * 10.f, 0.f), 10.f);
}

// ---------------- D init, later scales ----------------
__global__ void dinit_blend_k(const float* __restrict__ Dp, const float* __restrict__ Ebuf,
                              float* __restrict__ D0, int Hs, int Ws) {
    int gid = blockIdx.x * 256 + threadIdx.x;
    int HW = Hs * Ws;
    if (gid >= BN * HW) return;
    int ox = gid % Ws;
    int oy = (gid / Ws) % Hs;
    int b = gid / HW;
    int hp = Hs / 2, wp = Ws / 2;
    const float* P = Dp + (size_t)b * hp * wp;

    float ty = 0.5f * oy - 0.25f;
    int jy = (int)floorf(ty);
    float fy = ty - jy;
    float wy0 = 1.f - fy, wy1 = fy;
    bool v0 = (jy >= 0) && (jy < hp);
    bool v1 = (jy + 1 >= 0) && (jy + 1 < hp);
    if (!v0) wy0 = 0.f;
    if (!v1) wy1 = 0.f;
    float wys = wy0 + wy1;

    float tx = 0.5f * ox - 0.25f;
    int jx = (int)floorf(tx);
    float fx = tx - jx;
    float wx0 = 1.f - fx, wx1 = fx;
    bool u0 = (jx >= 0) && (jx < wp);
    bool u1 = (jx + 1 >= 0) && (jx + 1 < wp);
    if (!u0) wx0 = 0.f;
    if (!u1) wx1 = 0.f;
    float wxs = wx0 + wx1;

    int jy0c = v0 ? jy : 0, jy1c = v1 ? (jy + 1) : 0;
    int jx0c = u0 ? jx : 0, jx1c = u1 ? (jx + 1) : 0;
    float up = wy0 * (wx0 * P[(size_t)jy0c * wp + jx0c] + wx1 * P[(size_t)jy0c * wp + jx1c])
             + wy1 * (wx0 * P[(size_t)jy1c * wp + jx0c] + wx1 * P[(size_t)jy1c * wp + jx1c]);
    up /= (wys * wxs);

    const float* Eb = Ebuf + (size_t)b * HW;
    float e = Eb[(size_t)oy * Ws + ox];
    float gx = (ox > 0) ? fabsf(e - Eb[(size_t)oy * Ws + ox - 1]) : 0.f;
    float gy = (oy > 0) ? fabsf(e - Eb[(size_t)(oy - 1) * Ws + ox]) : 0.f;
    float g = fminf(fmaxf(0.5f * (gx + gy), 0.f), 1.f);
    float w = 0.7f * fminf(fmaxf(1.f - g * 10.f, 0.f), 1.f);
    float Pv = fminf(fmaxf(e * 10.f, 0.f), 10.f);
    D0[gid] = w * up + (1.f - w) * Pv;
}

// ---------------- zero halos of both padded feature buffers ----------------
__global__ void halo0_k(short* __restrict__ A, short* __restrict__ B2, int Hs, int Ws) {
    int pw = Ws + 2;
    int ne = 2 * pw + 2 * Hs;
    int total = 4 * ne;
    int gid = blockIdx.x * 256 + threadIdx.x;
    if (gid >= total) return;
    int e = gid % ne;
    int t = gid / ne;
    int b = t & 1;
    int buf = t >> 1;
    int yp, xp;
    if (e < pw)            { yp = 0;      xp = e; }
    else if (e < 2 * pw)   { yp = Hs + 1; xp = e - pw; }
    else { int e2 = e - 2 * pw; yp = 1 + (e2 >> 1); xp = (e2 & 1) ? (Ws + 1) : 0; }
    short* p = (buf ? B2 : A) + (((size_t)b * (Hs + 6) + 2 + yp) * pw + xp) * 64;
    short8v z = {0, 0, 0, 0, 0, 0, 0, 0};
#pragma unroll
    for (int j = 0; j < 8; j++) *(short8v*)(p + j * 8) = z;
}

// bijective XCD-chunked swizzle (m204)
__device__ __forceinline__ int xcd_swz(int orig, int nwg) {
    int q = nwg >> 3, r = nwg & 7;
    int xcd = orig & 7, idx = orig >> 3;
    return (xcd < r ? xcd * (q + 1) : r * (q + 1) + (xcd - r) * q) + idx;
}

// ---------------- conv0: 6->64 MFMA implicit GEMM (K padded to 96 = 3 x K32) ----------------
__global__ __launch_bounds__(256, 3) void conv0mm_k(
        const short* __restrict__ Xp, const short* __restrict__ WB,
        const float* __restrict__ bias, short* __restrict__ Y,
        int Hs, int Ws, int tX) {
    const int pw = Ws + 2;
    const int lane = threadIdx.x & 63;
    const int wv = threadIdx.x >> 6;
    const int b = blockIdx.y;
    const int l15 = lane & 15;
    const int g = lane >> 4;
    int wg = xcd_swz(blockIdx.x, gridDim.x);
    int ty = wg / tX, txi = wg - ty * tX;
    const int y = ty * 4 + wv;
    const int x0 = txi * 64;

    const size_t bbase8 = ((size_t)b * (Hs + 6) + 2) * pw * 8;
    const short* Xb = Xp + bbase8;

    f32x4 acc[4][4];
#pragma unroll
    for (int n = 0; n < 4; n++) {
        f32x4 bv;
#pragma unroll
        for (int j = 0; j < 4; j++) bv[j] = bias[16 * n + g * 4 + j];
#pragma unroll
        for (int cg = 0; cg < 4; cg++) acc[n][cg] = bv;
    }

    int vb[4];
#pragma unroll
    for (int cg = 0; cg < 4; cg++)
        vb[cg] = ((y + 1) * pw + (x0 + cg * 16 + l15 + 1)) * 8;

#pragma unroll
    for (int j = 0; j < 3; j++) {
        int tap = 4 * j + g;
        if (tap > 8) tap = 8;
        int toff = ((tap / 3 - 1) * pw + (tap % 3 - 1)) * 8;
        short8v bx[4];
#pragma unroll
        for (int cg = 0; cg < 4; cg++)
            bx[cg] = *(const short8v*)(Xb + vb[cg] + toff);
        const short* wp = WB + (size_t)j * (2 * 4 * 512) + lane * 8;
#pragma unroll
        for (int hl = 0; hl < 2; hl++) {
#pragma unroll
            for (int n = 0; n < 4; n++) {
                short8v av = *(const short8v*)(wp + (hl * 4 + n) * 512);
#pragma unroll
                for (int cg = 0; cg < 4; cg++)
                    acc[n][cg] = __builtin_amdgcn_mfma_f32_16x16x32_bf16(
                        av, bx[cg], acc[n][cg], 0, 0, 0);
            }
        }
    }

    const size_t bbase = ((size_t)b * (Hs + 6) + 2) * pw * 64;
#pragma unroll
    for (int cg = 0; cg < 4; cg++) {
        int x = x0 + cg * 16 + l15;
        if (x >= Ws) continue;
        short* out = Y + bbase + ((size_t)(y + 1) * pw + (x + 1)) * 64 + g * 4;
#pragma unroll
        for (int n = 0; n < 4; n++) {
            ushort4 v;
            v.x = f2bf(fmaxf(acc[n][cg][0], 0.f));
            v.y = f2bf(fmaxf(acc[n][cg][1], 0.f));
            v.z = f2bf(fmaxf(acc[n][cg][2], 0.f));
            v.w = f2bf(fmaxf(acc[n][cg][3], 0.f));
            *(ushort4*)(out + 16 * n) = v;
        }
    }
}

// ---------------- MFMA implicit-GEMM 3x3 conv, weights staged in LDS ----------------
// block = 4 waves; wave = 1 output row x 64 px.
// Per tap (2 K-steps): weights double-buffered in LDS (issue-early/write-late),
// B fragments loaded at tap top, 1 barrier per tap.
template <int NF, int EPI>
__global__ __launch_bounds__(256, 2) void convmm_k(
        const short* __restrict__ X, const short* __restrict__ WB,
        const float* __restrict__ bias, short* __restrict__ Y,
        bf16* __restrict__ Aout, float* __restrict__ cen,
        float* __restrict__ sk,
        const float* __restrict__ Dcur, const float* __restrict__ wc,
        int Hs, int Ws, int tX) {
    const int pw = Ws + 2;
    const int lane = threadIdx.x & 63;
    const int wv = threadIdx.x >> 6;
    const int b = blockIdx.y;
    const int l15 = lane & 15;
    const int g = lane >> 4;
    int wg = xcd_swz(blockIdx.x, gridDim.x);
    int ty = wg / tX, txi = wg - ty * tX;
    const int y = ty * 4 + wv;
    const int x0 = txi * 64;

    const size_t bbase = ((size_t)b * (Hs + 6) + 2) * pw * 64;
    const short* Xb = X + bbase;

    constexpr int TAPSZ = 4 * NF * 512;        // shorts per tap (2ks x 2hl x NF x 512)
    __shared__ __attribute__((aligned(16))) short WL[2][TAPSZ];

    f32x4 acc[NF][4];
#pragma unroll
    for (int n = 0; n < NF; n++) {
        f32x4 bv;
#pragma unroll
        for (int j = 0; j < 4; j++) bv[j] = bias[16 * n + g * 4 + j];
#pragma unroll
        for (int cg = 0; cg < 4; cg++) acc[n][cg] = bv;
    }

    int vb[4];
#pragma unroll
    for (int cg = 0; cg < 4; cg++)
        vb[cg] = ((y + 1) * pw + (x0 + cg * 16 + l15 + 1)) * 64 + g * 8;

    // prologue: stage tap 0 weights into WL[0]
    {
        const short* src = WB + (size_t)(wv * NF) * 512 + lane * 8;
        short* dst = &WL[0][(wv * NF) * 512 + lane * 8];
#pragma unroll
        for (int r = 0; r < NF; r++)
            *(short8v*)(dst + r * 512) = *(const short8v*)(src + r * 512);
    }
    __syncthreads();

#pragma unroll
    for (int tap = 0; tap < 9; tap++) {
        const int cur = tap & 1;
        // B fragments for this tap (8 global loads)
        const int toff = ((tap / 3 - 1) * pw + (tap % 3 - 1)) * 64;
        short8v bx[8];
#pragma unroll
        for (int ks = 0; ks < 2; ks++)
#pragma unroll
            for (int cg = 0; cg < 4; cg++)
                bx[ks * 4 + cg] = *(const short8v*)(Xb + vb[cg] + toff + ks * 32);
        // issue staging loads for next tap's weights (write to LDS after MFMAs)
        short8v stg[NF];
        if (tap < 8) {
            const short* src = WB + (size_t)(tap + 1) * TAPSZ + (wv * NF) * 512 + lane * 8;
#pragma unroll
            for (int r = 0; r < NF; r++)
                stg[r] = *(const short8v*)(src + r * 512);
        }
        // compute: weights from LDS
#pragma unroll
        for (int ks = 0; ks < 2; ks++) {
            short8v wf[2 * NF];
#pragma unroll
            for (int q = 0; q < 2 * NF; q++)
                wf[q] = *(const short8v*)(&WL[cur][(ks * 2 * NF + q) * 512 + lane * 8]);
#pragma unroll
            for (int hl = 0; hl < 2; hl++)
#pragma unroll
                for (int n = 0; n < NF; n++)
#pragma unroll
                    for (int cg = 0; cg < 4; cg++)
                        acc[n][cg] = __builtin_amdgcn_mfma_f32_16x16x32_bf16(
                            wf[hl * NF + n], bx[ks * 4 + cg], acc[n][cg], 0, 0, 0);
        }
        // write-late staging + single barrier per tap
        if (tap < 8) {
            short* dst = &WL[cur ^ 1][(wv * NF) * 512 + lane * 8];
#pragma unroll
            for (int r = 0; r < NF; r++)
                *(short8v*)(dst + r * 512) = stg[r];
        }
        __syncthreads();
    }

    const int HW = Hs * Ws;
#pragma unroll
    for (int cg = 0; cg < 4; cg++) {
        int x = x0 + cg * 16 + l15;
        bool ok = (x < Ws);
        if (EPI == 0) {
            if (!ok) continue;
            short* out = Y + bbase + ((size_t)(y + 1) * pw + (x + 1)) * 64 + g * 4;
#pragma unroll
            for (int n = 0; n < NF; n++) {
                ushort4 v;
                v.x = f2bf(fmaxf(acc[n][cg][0], 0.f));
                v.y = f2bf(fmaxf(acc[n][cg][1], 0.f));
                v.z = f2bf(fmaxf(acc[n][cg][2], 0.f));
                v.w = f2bf(fmaxf(acc[n][cg][3], 0.f));
                *(ushort4*)(out + 16 * n) = v;
            }
        } else {
            // --- head epilogue ---
            float t0 = fabsf(acc[0][cg][0]) + fabsf(acc[0][cg][1]) +
                       fabsf(acc[0][cg][2]) + fabsf(acc[0][cg][3]);
            float s0 = t0 + __shfl_xor(t0, 16, 64);
            float t1 = fabsf(acc[1][cg][0]) + fabsf(acc[1][cg][1]) +
                       fabsf(acc[1][cg][2]) + fabsf(acc[1][cg][3]);
            float s1 = t1 + __shfl_xor(t1, 16, 64);
            float inv0 = 1.f / (s0 + 1e-6f);
            float inv1 = 1.f / (s1 + 1e-6f);
            float a0[4], a1[4];
#pragma unroll
            for (int j = 0; j < 4; j++) { a0[j] = acc[0][cg][j] * inv0; a1[j] = acc[1][cg][j] * inv1; }
            float p0 = a0[0] + a0[1] + a0[2] + a0[3];
            float c0 = p0 + __shfl_xor(p0, 16, 64);
            float p1 = a1[0] + a1[1] + a1[2] + a1[3];
            float c1 = p1 + __shfl_xor(p1, 16, 64);

            float e0 = acc[1][cg][0], e1 = acc[1][cg][1], e2 = acc[1][cg][2];
            float m = fmaxf(e0, fmaxf(e1, e2));
            float q0 = expf(e0 - m), q1 = expf(e1 - m), q2 = expf(e2 - m);
            float qs = 1.f / (q0 + q1 + q2);
            float sg0 = q0 * qs, sg1 = q1 * qs, sg2 = q2 * qs;
            float r0 = __shfl_xor(sg0, 16, 64);
            float r1 = __shfl_xor(sg1, 16, 64);
            float r2 = __shfl_xor(sg2, 16, 64);

            int pix = y * Ws + x;
            if (ok) {
#pragma unroll
                for (int j = 0; j < 4; j++) {
                    int ch = g * 4 + j;
                    reinterpret_cast<unsigned short*>(Aout)[((size_t)(b * 24 + ch)) * HW + pix] = f2bf(a0[j]);
                }
                if (g < 2) {
#pragma unroll
                    for (int j = 0; j < 4; j++) {
                        int ch = 16 + g * 4 + j;
                        reinterpret_cast<unsigned short*>(Aout)[((size_t)(b * 24 + ch)) * HW + pix] = f2bf(a1[j]);
                    }
                }
                if (g == 0) {
                    cen[((size_t)(b * 3 + 0)) * HW + pix] = 1.f - c0;
                    cen[((size_t)(b * 3 + 2)) * HW + pix] = 1.f - c1;
                }
                if (g == 2) {
                    cen[((size_t)(b * 3 + 1)) * HW + pix] = 1.f - c0;
                }
                if (g == 3) {
                    float dsum[3] = {0.f, 0.f, 0.f};
#pragma unroll
                    for (int t = 0; t < 9; t++) {
                        int yy = y + t / 3 - 1;
                        int xx = x + t % 3 - 1;
                        if ((unsigned)yy < (unsigned)Hs && (unsigned)xx < (unsigned)Ws) {
                            float dv = Dcur[(size_t)b * HW + (size_t)yy * Ws + xx] * 0.1f;
#pragma unroll
                            for (int j = 0; j < 3; j++)
                                dsum[j] = fmaf(wc[(size_t)(j * 65 + 64) * 9 + t], dv, dsum[j]);
                        }
                    }
                    float rr[3] = {r0, r1, r2};
#pragma unroll
                    for (int j = 0; j < 3; j++) {
                        float z = acc[1][cg][j] + dsum[j];
                        float kp = 0.1f + 0.9f / (1.f + expf(-z));
                        sk[((size_t)(b * 3 + j)) * HW + pix] = rr[j] * kp;
                    }
                }
            }
        }
    }
}

// ---------------- one CSPN propagation step ----------------
__global__ __launch_bounds__(256) void prop_k(const float* __restrict__ D,
        const unsigned short* __restrict__ A, const float* __restrict__ cen,
        const float* __restrict__ sk, const float* __restrict__ dlm,
        float* __restrict__ Dn, int Hs, int Ws) {
    int gid = blockIdx.x * 256 + threadIdx.x;
    int HW = Hs * Ws;
    if (gid >= BN * HW) return;
    int b = gid / HW;
    int p = gid - b * HW;
    int y = p / Ws;
    int x = p - y * Ws;
    const float* Db = D + (size_t)b * HW;
    float Dc = Db[p];
    const int dy_[8] = {-1, -1, -1, 0, 0, 1, 1, 1};
    const int dx_[8] = {-1, 0, 1, -1, 1, -1, 0, 1};
    float mix = Dc;
#pragma unroll
    for (int k = 0; k < 3; k++) {
        int d = 1 << k;
        float s = cen[(size_t)(b * 3 + k) * HW + p] * Dc;
#pragma unroll
        for (int j = 0; j < 8; j++) {
            int yy = y + dy_[j] * d;
            int xx = x + dx_[j] * d;
            float nb = ((unsigned)yy < (unsigned)Hs && (unsigned)xx < (unsigned)Ws)
                           ? Db[(size_t)yy * Ws + xx] : 0.f;
            s = fmaf(bf2f(A[(size_t)(b * 24 + k * 8 + j) * HW + p]), nb, s);
        }
        mix += sk[(size_t)(b * 3 + k) * HW + p] * (s - Dc);
    }
    float v = dlm[(size_t)b * HW + p];
    float ml = v >= 0.f ? 1.f : 0.f;
    float dl = v >= 0.f ? v : 0.f;
    Dn[(size_t)b * HW + p] = ml * (0.9f * dl + 0.1f * mix) + (1.f - ml) * mix;
}

extern "C" void kernel_launch(void* const* d_in, const int* in_sizes, int n_in,
                              void* d_out, int out_size, void* d_ws, size_t ws_size,
                              hipStream_t stream) {
    const float* I  = (const float*)d_in[0];
    const float* DL = (const float*)d_in[1];
    const float* ML = (const float*)d_in[2];
    const float* E  = (const float*)d_in[3];
    const float* w0 = (const float*)d_in[4];  const float* b0 = (const float*)d_in[5];
    const float* w1 = (const float*)d_in[6];  const float* b1 = (const float*)d_in[7];
    const float* w2 = (const float*)d_in[8];  const float* b2 = (const float*)d_in[9];
    const float* wa = (const float*)d_in[10]; const float* ba = (const float*)d_in[11];
    const float* wg = (const float*)d_in[12]; const float* bg = (const float*)d_in[13];
    const float* wc = (const float*)d_in[14]; const float* bc = (const float*)d_in[15];

    size_t off = 0;
    auto carve = [&](size_t bytes) -> void* {
        void* pp = (char*)d_ws + off;
        off = (off + bytes + 255) & ~(size_t)255;
        return pp;
    };
    bf16*  Abuf  = (bf16*)carve((size_t)BN * 24 * HW1 * 2);
    float* cen   = (float*)carve((size_t)BN * 3 * HW1 * 4);
    float* sk    = (float*)carve((size_t)BN * 3 * HW1 * 4);
    float* dlm   = (float*)carve((size_t)BN * HW1 * 4);
    float* Ebuf  = (float*)carve((size_t)BN * HW1 * 4);
    float* D0    = (float*)carve((size_t)BN * HW1 * 4);
    float* D1    = (float*)carve((size_t)BN * HW1 * 4);
    float* Dprev = (float*)carve((size_t)BN * HW1 * 4);
    size_t padElems = (size_t)BN * (H0 + 6) * (W0 + 2) * 64;
    short* padA = (short*)carve(padElems * 2 + 65536);
    short* padB = (short*)carve(padElems * 2 + 65536);
    short* xpad = (short*)carve((size_t)BN * (H0 + 6) * (W0 + 2) * 8 * 2 + 65536);
    short* WB1  = (short*)carve((size_t)18 * 2 * 4 * 512 * 2);
    short* WB2  = (short*)carve((size_t)18 * 2 * 4 * 512 * 2);
    short* WBh  = (short*)carve((size_t)18 * 2 * 2 * 512 * 2);
    short* WB0  = (short*)carve((size_t)3 * 2 * 4 * 512 * 2);
    float* hb   = (float*)carve(32 * 4);
    if (off > ws_size) return;

    wtr2_k<<<(18 * 2 * 4 * 512 + 255) / 256, 256, 0, stream>>>(w1, WB1);
    wtr2_k<<<(18 * 2 * 4 * 512 + 255) / 256, 256, 0, stream>>>(w2, WB2);
    whb_k<<<(18 * 2 * 2 * 512 + 255) / 256, 256, 0, stream>>>(wa, wg, wc, WBh);
    wtr0_k<<<(3 * 2 * 4 * 512 + 255) / 256, 256, 0, stream>>>(w0, WB0);
    hbias_k<<<1, 32, 0, stream>>>(ba, bg, bc, hb);

    const int scales[3] = {4, 2, 1};
    for (int si = 0; si < 3; si++) {
        int s = scales[si];
        int Hs = H0 / s, Ws = W0 / s, HW = Hs * Ws;
        int pw = Ws + 2;
        int nbp = (BN * HW + 255) / 256;
        int nprep = (BN * (Hs + 2) * pw + 255) / 256;

        if (s == 4)      prep_k<4><<<nprep, 256, 0, stream>>>(I, DL, ML, E, xpad, Ebuf, dlm, Hs, Ws);
        else if (s == 2) prep_k<2><<<nprep, 256, 0, stream>>>(I, DL, ML, E, xpad, Ebuf, dlm, Hs, Ws);
        else             prep_k<1><<<nprep, 256, 0, stream>>>(I, DL, ML, E, xpad, Ebuf, dlm, Hs, Ws);

        if (si == 0)
            dinit_first_k<<<nbp, 256, 0, stream>>>(Ebuf, D0, Hs, Ws);
        else
            dinit_blend_k<<<nbp, 256, 0, stream>>>(Dprev, Ebuf, D0, Hs, Ws);

        int nhalo = (4 * (2 * pw + 2 * Hs) + 255) / 256;
        halo0_k<<<nhalo, 256, 0, stream>>>(padA, padB, Hs, Ws);

        int tX = (Ws + 63) / 64;
        int tY = Hs / 4;
        dim3 gmm(tX * tY, BN);
        conv0mm_k<<<gmm, 256, 0, stream>>>(xpad, WB0, b0, padA, Hs, Ws, tX);
        convmm_k<4, 0><<<gmm, 256, 0, stream>>>(padA, WB1, b1, padB,
            nullptr, nullptr, nullptr, nullptr, nullptr, Hs, Ws, tX);
        convmm_k<4, 0><<<gmm, 256, 0, stream>>>(padB, WB2, b2, padA,
            nullptr, nullptr, nullptr, nullptr, nullptr, Hs, Ws, tX);
        convmm_k<2, 1><<<gmm, 256, 0, stream>>>(padA, WBh, hb, nullptr,
            Abuf, cen, sk, D0, wc, Hs, Ws, tX);

        float* Dc = D0;
        float* Dn = D1;
        float* fin = (si < 2) ? Dprev : (float*)d_out;
        for (int t = 0; t < 6; t++) {
            float* tgt = (t == 5) ? fin : Dn;
            prop_k<<<nbp, 256, 0, stream>>>(Dc, (const unsigned short*)Abuf, cen, sk,
                                            dlm, tgt, Hs, Ws);
            if (t < 5) { float* tmp = Dc; Dc = Dn; Dn = tmp; }
        }
    }
}

// Round 7
// 752.014 us; speedup vs baseline: 7.3448x; 1.0243x over previous
//
#include <hip/hip_runtime.h>
#include <hip/hip_bf16.h>

typedef __hip_bfloat16 bf16;
typedef __attribute__((ext_vector_type(8))) short short8v;
typedef __attribute__((ext_vector_type(4))) float f32x4;

static constexpr int BN = 2;
static constexpr int H0 = 480, W0 = 640;
static constexpr int HW1 = H0 * W0;

__device__ __forceinline__ unsigned short f2bf(float f) {
    bf16 h = __float2bfloat16(f);
    return reinterpret_cast<unsigned short&>(h);
}
__device__ __forceinline__ float bf2f(unsigned short u) {
    bf16 h; reinterpret_cast<unsigned short&>(h) = u;
    return __bfloat162float(h);
}

// ---------------- MFMA weight transform (64->64), hi/lo split ----------------
// WB flat: (((tap*2+ks)*2+hl)*4+n)*512 + lane*8 + i    (NF=4)
__global__ void wtr2_k(const float* __restrict__ w, short* __restrict__ WB) {
    int gid = blockIdx.x * 256 + threadIdx.x;
    if (gid >= 18 * 2 * 4 * 512) return;
    int ie = gid & 7;
    int l  = (gid >> 3) & 63;
    int n  = (gid >> 9) & 3;
    int hl = (gid >> 11) & 1;
    int t2 = gid >> 12;            // 0..17
    int tap = t2 >> 1, ks = t2 & 1;
    int o = 16 * n + (l & 15);
    int c = 32 * ks + (l >> 4) * 8 + ie;
    float wv = w[(size_t)(o * 64 + c) * 9 + tap];
    bf16 hi = __float2bfloat16(wv);
    float hif = __bfloat162float(hi);
    bf16 lo = __float2bfloat16(wv - hif);
    WB[gid] = hl ? reinterpret_cast<short&>(lo) : reinterpret_cast<short&>(hi);
}

// ---------------- conv0 MFMA weight transform (6ch+9tap -> K-slots), hi/lo ----------------
__global__ void wtr0_k(const float* __restrict__ w, short* __restrict__ WB) {
    int gid = blockIdx.x * 256 + threadIdx.x;
    if (gid >= 3 * 2 * 4 * 512) return;
    int ie = gid & 7;
    int l  = (gid >> 3) & 63;
    int n  = (gid >> 9) & 3;
    int hl = (gid >> 11) & 1;
    int j  = gid >> 12;            // 0..2
    int o = 16 * n + (l & 15);
    int g = l >> 4;
    int tap = 4 * j + g;
    float wv = (tap < 9 && ie < 6) ? w[(size_t)(o * 6 + ie) * 9 + tap] : 0.f;
    bf16 hi = __float2bfloat16(wv);
    float hif = __bfloat162float(hi);
    bf16 lo = __float2bfloat16(wv - hif);
    WB[gid] = hl ? reinterpret_cast<short&>(lo) : reinterpret_cast<short&>(hi);
}

// ---------------- head weight transform (aff24+gate3+curv3 -> 32ch), hi/lo ----------------
__global__ void whb_k(const float* __restrict__ wa, const float* __restrict__ wg,
                      const float* __restrict__ wc, short* __restrict__ WB) {
    int gid = blockIdx.x * 256 + threadIdx.x;
    if (gid >= 18 * 2 * 2 * 512) return;
    int ie = gid & 7;
    int l  = (gid >> 3) & 63;
    int n  = (gid >> 9) & 1;
    int hl = (gid >> 10) & 1;
    int t2 = gid >> 11;
    int tap = t2 >> 1, ks = t2 & 1;
    int o = 16 * n + (l & 15);     // 0..31
    int c = 32 * ks + (l >> 4) * 8 + ie;
    float wv = 0.f;
    if (o < 24)                 wv = wa[(size_t)(o * 64 + c) * 9 + tap];
    else if (o >= 24 && o < 27) wv = wg[(size_t)((o - 24) * 64 + c) * 9 + tap];
    else if (o >= 28 && o < 31) wv = wc[(size_t)((o - 28) * 65 + c) * 9 + tap];
    bf16 hi = __float2bfloat16(wv);
    float hif = __bfloat162float(hi);
    bf16 lo = __float2bfloat16(wv - hif);
    WB[gid] = hl ? reinterpret_cast<short&>(lo) : reinterpret_cast<short&>(hi);
}

__global__ void hbias_k(const float* __restrict__ ba, const float* __restrict__ bg,
                        const float* __restrict__ bc, float* __restrict__ hb) {
    int o = threadIdx.x;
    if (o >= 32) return;
    float v = 0.f;
    if (o < 24) v = ba[o];
    else if (o < 27) v = bg[o - 24];
    else if (o >= 28 && o < 31) v = bc[o - 28];
    hb[o] = v;
}

// ---------------- fused per-scale prep: resize I(3) + resize E + down_sparse ----------------
template <int F>
__global__ void prep_k(const float* __restrict__ I, const float* __restrict__ DL,
                       const float* __restrict__ ML, const float* __restrict__ E,
                       short* __restrict__ Xp, float* __restrict__ Ebuf,
                       float* __restrict__ dlm, int Hs, int Ws) {
    const int pw = Ws + 2;
    int gid = blockIdx.x * 256 + threadIdx.x;
    int total = BN * (Hs + 2) * pw;
    if (gid >= total) return;
    int xp = gid % pw;
    int yp = (gid / pw) % (Hs + 2);
    int b = gid / (pw * (Hs + 2));
    short8v v = {0, 0, 0, 0, 0, 0, 0, 0};
    if (yp >= 1 && yp <= Hs && xp >= 1 && xp <= Ws) {
        int oy = yp - 1, ox = xp - 1;
        constexpr int NT = 2 * F;
        float wy[NT], wx[NT];
        float sy = (oy + 0.5f) * F - 0.5f;
        int jly = F * oy - (F + 1) / 2;
        float wys = 0.f;
#pragma unroll
        for (int t = 0; t < NT; t++) {
            int j = jly + t;
            float w = fmaxf(1.f - fabsf(sy - (float)j) / (float)F, 0.f);
            if (j < 0 || j >= H0) w = 0.f;
            wy[t] = w; wys += w;
        }
        float sx = (ox + 0.5f) * F - 0.5f;
        int jlx = F * ox - (F + 1) / 2;
        float wxs = 0.f;
#pragma unroll
        for (int t = 0; t < NT; t++) {
            int j = jlx + t;
            float w = fmaxf(1.f - fabsf(sx - (float)j) / (float)F, 0.f);
            if (j < 0 || j >= W0) w = 0.f;
            wx[t] = w; wxs += w;
        }
        float inv = 1.f / (wys * wxs);
#pragma unroll
        for (int c = 0; c < 3; c++) {
            const float* ip = I + (size_t)(b * 3 + c) * HW1;
            float acc = 0.f;
#pragma unroll
            for (int ty = 0; ty < NT; ty++) {
                if (wy[ty] == 0.f) continue;
                const float* row = ip + (size_t)(jly + ty) * W0;
                float r = 0.f;
#pragma unroll
                for (int tx = 0; tx < NT; tx++)
                    if (wx[tx] != 0.f) r += wx[tx] * row[jlx + tx];
                acc += wy[ty] * r;
            }
            v[c] = (short)f2bf(acc * inv);
        }
        {
            const float* ip = E + (size_t)b * HW1;
            float acc = 0.f;
#pragma unroll
            for (int ty = 0; ty < NT; ty++) {
                if (wy[ty] == 0.f) continue;
                const float* row = ip + (size_t)(jly + ty) * W0;
                float r = 0.f;
#pragma unroll
                for (int tx = 0; tx < NT; tx++)
                    if (wx[tx] != 0.f) r += wx[tx] * row[jlx + tx];
                acc += wy[ty] * r;
            }
            acc = fminf(fmaxf(acc * inv, 0.f), 1.f);
            v[5] = (short)f2bf(acc);
            Ebuf[(size_t)b * Hs * Ws + oy * Ws + ox] = acc;
        }
        {
            float s = 0.f, c = 0.f;
#pragma unroll
            for (int dy = 0; dy < F; dy++)
#pragma unroll
                for (int dx = 0; dx < F; dx++) {
                    size_t idx = ((size_t)b * H0 + (oy * F + dy)) * W0 + (ox * F + dx);
                    float m = ML[idx] > 0.f ? 1.f : 0.f;
                    s += DL[idx] * m;
                    c += m;
                }
            float dls = c > 0.f ? s / (c + 1e-6f) : 0.f;
            v[3] = (short)f2bf(dls);
            v[4] = (short)f2bf(c > 0.f ? 1.f : 0.f);
            dlm[(size_t)b * Hs * Ws + oy * Ws + ox] = c > 0.f ? dls : -1.f;
        }
    }
    *(short8v*)(Xp + (((size_t)b * (Hs + 6) + 2 + yp) * pw + xp) * 8) = v;
}

// ---------------- D init, first scale ----------------
__global__ void dinit_first_k(const float* __restrict__ Ebuf, float* __restrict__ D0,
                              int Hs, int Ws) {
    int gid = blockIdx.x * 256 + threadIdx.x;
    int HW = Hs * Ws;
    if (gid >= BN * HW) return;
    float e = Ebuf[gid];
    D0[gid] = fminf(fmaxf(e * 10.f, 0.f), 10.f);
}

// ---------------- D init, later scales ----------------
__global__ void dinit_blend_k(const float* __restrict__ Dp, const float* __restrict__ Ebuf,
                              float* __restrict__ D0, int Hs, int Ws) {
    int gid = blockIdx.x * 256 + threadIdx.x;
    int HW = Hs * Ws;
    if (gid >= BN * HW) return;
    int ox = gid % Ws;
    int oy = (gid / Ws) % Hs;
    int b = gid / HW;
    int hp = Hs / 2, wp = Ws / 2;
    const float* P = Dp + (size_t)b * hp * wp;

    float ty = 0.5f * oy - 0.25f;
    int jy = (int)floorf(ty);
    float fy = ty - jy;
    float wy0 = 1.f - fy, wy1 = fy;
    bool v0 = (jy >= 0) && (jy < hp);
    bool v1 = (jy + 1 >= 0) && (jy + 1 < hp);
    if (!v0) wy0 = 0.f;
    if (!v1) wy1 = 0.f;
    float wys = wy0 + wy1;

    float tx = 0.5f * ox - 0.25f;
    int jx = (int)floorf(tx);
    float fx = tx - jx;
    float wx0 = 1.f - fx, wx1 = fx;
    bool u0 = (jx >= 0) && (jx < wp);
    bool u1 = (jx + 1 >= 0) && (jx + 1 < wp);
    if (!u0) wx0 = 0.f;
    if (!u1) wx1 = 0.f;
    float wxs = wx0 + wx1;

    int jy0c = v0 ? jy : 0, jy1c = v1 ? (jy + 1) : 0;
    int jx0c = u0 ? jx : 0, jx1c = u1 ? (jx + 1) : 0;
    float up = wy0 * (wx0 * P[(size_t)jy0c * wp + jx0c] + wx1 * P[(size_t)jy0c * wp + jx1c])
             + wy1 * (wx0 * P[(size_t)jy1c * wp + jx0c] + wx1 * P[(size_t)jy1c * wp + jx1c]);
    up /= (wys * wxs);

    const float* Eb = Ebuf + (size_t)b * HW;
    float e = Eb[(size_t)oy * Ws + ox];
    float gx = (ox > 0) ? fabsf(e - Eb[(size_t)oy * Ws + ox - 1]) : 0.f;
    float gy = (oy > 0) ? fabsf(e - Eb[(size_t)(oy - 1) * Ws + ox]) : 0.f;
    float g = fminf(fmaxf(0.5f * (gx + gy), 0.f), 1.f);
    float w = 0.7f * fminf(fmaxf(1.f - g * 10.f, 0.f), 1.f);
    float Pv = fminf(fmaxf(e * 10.f, 0.f), 10.f);
    D0[gid] = w * up + (1.f - w) * Pv;
}

// ---------------- zero halos of both padded feature buffers ----------------
__global__ void halo0_k(short* __restrict__ A, short* __restrict__ B2, int Hs, int Ws) {
    int pw = Ws + 2;
    int ne = 2 * pw + 2 * Hs;
    int total = 4 * ne;
    int gid = blockIdx.x * 256 + threadIdx.x;
    if (gid >= total) return;
    int e = gid % ne;
    int t = gid / ne;
    int b = t & 1;
    int buf = t >> 1;
    int yp, xp;
    if (e < pw)            { yp = 0;      xp = e; }
    else if (e < 2 * pw)   { yp = Hs + 1; xp = e - pw; }
    else { int e2 = e - 2 * pw; yp = 1 + (e2 >> 1); xp = (e2 & 1) ? (Ws + 1) : 0; }
    short* p = (buf ? B2 : A) + (((size_t)b * (Hs + 6) + 2 + yp) * pw + xp) * 64;
    short8v z = {0, 0, 0, 0, 0, 0, 0, 0};
#pragma unroll
    for (int j = 0; j < 8; j++) *(short8v*)(p + j * 8) = z;
}

// bijective XCD-chunked swizzle (m204)
__device__ __forceinline__ int xcd_swz(int orig, int nwg) {
    int q = nwg >> 3, r = nwg & 7;
    int xcd = orig & 7, idx = orig >> 3;
    return (xcd < r ? xcd * (q + 1) : r * (q + 1) + (xcd - r) * q) + idx;
}

// ---------------- conv0: 6->64 MFMA implicit GEMM (K padded to 96 = 3 x K32) ----------------
__global__ __launch_bounds__(256, 3) void conv0mm_k(
        const short* __restrict__ Xp, const short* __restrict__ WB,
        const float* __restrict__ bias, short* __restrict__ Y,
        int Hs, int Ws, int tX) {
    const int pw = Ws + 2;
    const int lane = threadIdx.x & 63;
    const int wv = threadIdx.x >> 6;
    const int b = blockIdx.y;
    const int l15 = lane & 15;
    const int g = lane >> 4;
    int wg = xcd_swz(blockIdx.x, gridDim.x);
    int ty = wg / tX, txi = wg - ty * tX;
    const int y = ty * 4 + wv;
    const int x0 = txi * 64;

    const size_t bbase8 = ((size_t)b * (Hs + 6) + 2) * pw * 8;
    const short* Xb = Xp + bbase8;

    f32x4 acc[4][4];
#pragma unroll
    for (int n = 0; n < 4; n++) {
        f32x4 bv;
#pragma unroll
        for (int j = 0; j < 4; j++) bv[j] = bias[16 * n + g * 4 + j];
#pragma unroll
        for (int cg = 0; cg < 4; cg++) acc[n][cg] = bv;
    }

    int vb[4];
#pragma unroll
    for (int cg = 0; cg < 4; cg++)
        vb[cg] = ((y + 1) * pw + (x0 + cg * 16 + l15 + 1)) * 8;

#pragma unroll
    for (int j = 0; j < 3; j++) {
        int tap = 4 * j + g;
        if (tap > 8) tap = 8;
        int toff = ((tap / 3 - 1) * pw + (tap % 3 - 1)) * 8;
        short8v bx[4];
#pragma unroll
        for (int cg = 0; cg < 4; cg++)
            bx[cg] = *(const short8v*)(Xb + vb[cg] + toff);
        const short* wp = WB + (size_t)j * (2 * 4 * 512) + lane * 8;
#pragma unroll
        for (int hl = 0; hl < 2; hl++) {
#pragma unroll
            for (int n = 0; n < 4; n++) {
                short8v av = *(const short8v*)(wp + (hl * 4 + n) * 512);
#pragma unroll
                for (int cg = 0; cg < 4; cg++)
                    acc[n][cg] = __builtin_amdgcn_mfma_f32_16x16x32_bf16(
                        av, bx[cg], acc[n][cg], 0, 0, 0);
            }
        }
    }

    const size_t bbase = ((size_t)b * (Hs + 6) + 2) * pw * 64;
#pragma unroll
    for (int cg = 0; cg < 4; cg++) {
        int x = x0 + cg * 16 + l15;
        if (x >= Ws) continue;
        short* out = Y + bbase + ((size_t)(y + 1) * pw + (x + 1)) * 64 + g * 4;
#pragma unroll
        for (int n = 0; n < 4; n++) {
            ushort4 v;
            v.x = f2bf(fmaxf(acc[n][cg][0], 0.f));
            v.y = f2bf(fmaxf(acc[n][cg][1], 0.f));
            v.z = f2bf(fmaxf(acc[n][cg][2], 0.f));
            v.w = f2bf(fmaxf(acc[n][cg][3], 0.f));
            *(ushort4*)(out + 16 * n) = v;
        }
    }
}

// ---------------- MFMA implicit-GEMM 3x3 conv, LDS weights + full-tap B prefetch ----------------
// block = 4 waves; wave = 1 output row x 64 px.
// Weights double-buffered in LDS (issue-early/write-late, 1 barrier/tap).
// B fragments register double-buffered with a FULL TAP of lead time.
template <int NF, int EPI>
__global__ __launch_bounds__(256, 2) void convmm_k(
        const short* __restrict__ X, const short* __restrict__ WB,
        const float* __restrict__ bias, short* __restrict__ Y,
        bf16* __restrict__ Aout, float* __restrict__ cen,
        float* __restrict__ sk,
        const float* __restrict__ Dcur, const float* __restrict__ wc,
        int Hs, int Ws, int tX) {
    const int pw = Ws + 2;
    const int lane = threadIdx.x & 63;
    const int wv = threadIdx.x >> 6;
    const int b = blockIdx.y;
    const int l15 = lane & 15;
    const int g = lane >> 4;
    int wg = xcd_swz(blockIdx.x, gridDim.x);
    int ty = wg / tX, txi = wg - ty * tX;
    const int y = ty * 4 + wv;
    const int x0 = txi * 64;

    const size_t bbase = ((size_t)b * (Hs + 6) + 2) * pw * 64;
    const short* Xb = X + bbase;

    constexpr int TAPSZ = 4 * NF * 512;        // shorts per tap (2ks x 2hl x NF x 512)
    __shared__ __attribute__((aligned(16))) short WL[2][TAPSZ];

    f32x4 acc[NF][4];
#pragma unroll
    for (int n = 0; n < NF; n++) {
        f32x4 bv;
#pragma unroll
        for (int j = 0; j < 4; j++) bv[j] = bias[16 * n + g * 4 + j];
#pragma unroll
        for (int cg = 0; cg < 4; cg++) acc[n][cg] = bv;
    }

    int vb[4];
#pragma unroll
    for (int cg = 0; cg < 4; cg++)
        vb[cg] = ((y + 1) * pw + (x0 + cg * 16 + l15 + 1)) * 64 + g * 8;

    short8v bxA[8], bxB[8];
    auto LDB = [&](short8v* bx, int tap) {
        const int toff = ((tap / 3 - 1) * pw + (tap % 3 - 1)) * 64;
#pragma unroll
        for (int ks = 0; ks < 2; ks++)
#pragma unroll
            for (int cg = 0; cg < 4; cg++)
                bx[ks * 4 + cg] = *(const short8v*)(Xb + vb[cg] + toff + ks * 32);
    };

    // prologue: B for tap 0 + weights tap 0 into WL[0]
    LDB(bxA, 0);
    {
        const short* src = WB + (size_t)(wv * NF) * 512 + lane * 8;
        short* dst = &WL[0][(wv * NF) * 512 + lane * 8];
#pragma unroll
        for (int r = 0; r < NF; r++)
            *(short8v*)(dst + r * 512) = *(const short8v*)(src + r * 512);
    }
    __syncthreads();

#pragma unroll
    for (int tap = 0; tap < 9; tap++) {
        const int cur = tap & 1;
        short8v* bcur = cur ? bxB : bxA;
        short8v* bnxt = cur ? bxA : bxB;
        // prefetch next tap's B fragments (full tap of lead)
        if (tap < 8) LDB(bnxt, tap + 1);
        // issue staging loads for next tap's weights (write to LDS after MFMAs)
        short8v stg[NF];
        if (tap < 8) {
            const short* src = WB + (size_t)(tap + 1) * TAPSZ + (wv * NF) * 512 + lane * 8;
#pragma unroll
            for (int r = 0; r < NF; r++)
                stg[r] = *(const short8v*)(src + r * 512);
        }
        // compute: weights from LDS, 4 frags per hl
#pragma unroll
        for (int ks = 0; ks < 2; ks++) {
#pragma unroll
            for (int hl = 0; hl < 2; hl++) {
                short8v wf[NF];
#pragma unroll
                for (int n = 0; n < NF; n++)
                    wf[n] = *(const short8v*)(&WL[cur][((ks * 2 + hl) * NF + n) * 512 + lane * 8]);
#pragma unroll
                for (int n = 0; n < NF; n++)
#pragma unroll
                    for (int cg = 0; cg < 4; cg++)
                        acc[n][cg] = __builtin_amdgcn_mfma_f32_16x16x32_bf16(
                            wf[n], bcur[ks * 4 + cg], acc[n][cg], 0, 0, 0);
            }
        }
        // write-late staging + single barrier per tap
        if (tap < 8) {
            short* dst = &WL[cur ^ 1][(wv * NF) * 512 + lane * 8];
#pragma unroll
            for (int r = 0; r < NF; r++)
                *(short8v*)(dst + r * 512) = stg[r];
        }
        __syncthreads();
    }

    const int HW = Hs * Ws;
#pragma unroll
    for (int cg = 0; cg < 4; cg++) {
        int x = x0 + cg * 16 + l15;
        bool ok = (x < Ws);
        if (EPI == 0) {
            if (!ok) continue;
            short* out = Y + bbase + ((size_t)(y + 1) * pw + (x + 1)) * 64 + g * 4;
#pragma unroll
            for (int n = 0; n < NF; n++) {
                ushort4 v;
                v.x = f2bf(fmaxf(acc[n][cg][0], 0.f));
                v.y = f2bf(fmaxf(acc[n][cg][1], 0.f));
                v.z = f2bf(fmaxf(acc[n][cg][2], 0.f));
                v.w = f2bf(fmaxf(acc[n][cg][3], 0.f));
                *(ushort4*)(out + 16 * n) = v;
            }
        } else {
            // --- head epilogue ---
            float t0 = fabsf(acc[0][cg][0]) + fabsf(acc[0][cg][1]) +
                       fabsf(acc[0][cg][2]) + fabsf(acc[0][cg][3]);
            float s0 = t0 + __shfl_xor(t0, 16, 64);
            float t1 = fabsf(acc[1][cg][0]) + fabsf(acc[1][cg][1]) +
                       fabsf(acc[1][cg][2]) + fabsf(acc[1][cg][3]);
            float s1 = t1 + __shfl_xor(t1, 16, 64);
            float inv0 = 1.f / (s0 + 1e-6f);
            float inv1 = 1.f / (s1 + 1e-6f);
            float a0[4], a1[4];
#pragma unroll
            for (int j = 0; j < 4; j++) { a0[j] = acc[0][cg][j] * inv0; a1[j] = acc[1][cg][j] * inv1; }
            float p0 = a0[0] + a0[1] + a0[2] + a0[3];
            float c0 = p0 + __shfl_xor(p0, 16, 64);
            float p1 = a1[0] + a1[1] + a1[2] + a1[3];
            float c1 = p1 + __shfl_xor(p1, 16, 64);

            float e0 = acc[1][cg][0], e1 = acc[1][cg][1], e2 = acc[1][cg][2];
            float m = fmaxf(e0, fmaxf(e1, e2));
            float q0 = expf(e0 - m), q1 = expf(e1 - m), q2 = expf(e2 - m);
            float qs = 1.f / (q0 + q1 + q2);
            float sg0 = q0 * qs, sg1 = q1 * qs, sg2 = q2 * qs;
            float r0 = __shfl_xor(sg0, 16, 64);
            float r1 = __shfl_xor(sg1, 16, 64);
            float r2 = __shfl_xor(sg2, 16, 64);

            int pix = y * Ws + x;
            if (ok) {
#pragma unroll
                for (int j = 0; j < 4; j++) {
                    int ch = g * 4 + j;
                    reinterpret_cast<unsigned short*>(Aout)[((size_t)(b * 24 + ch)) * HW + pix] = f2bf(a0[j]);
                }
                if (g < 2) {
#pragma unroll
                    for (int j = 0; j < 4; j++) {
                        int ch = 16 + g * 4 + j;
                        reinterpret_cast<unsigned short*>(Aout)[((size_t)(b * 24 + ch)) * HW + pix] = f2bf(a1[j]);
                    }
                }
                if (g == 0) {
                    cen[((size_t)(b * 3 + 0)) * HW + pix] = 1.f - c0;
                    cen[((size_t)(b * 3 + 2)) * HW + pix] = 1.f - c1;
                }
                if (g == 2) {
                    cen[((size_t)(b * 3 + 1)) * HW + pix] = 1.f - c0;
                }
                if (g == 3) {
                    float dsum[3] = {0.f, 0.f, 0.f};
#pragma unroll
                    for (int t = 0; t < 9; t++) {
                        int yy = y + t / 3 - 1;
                        int xx = x + t % 3 - 1;
                        if ((unsigned)yy < (unsigned)Hs && (unsigned)xx < (unsigned)Ws) {
                            float dv = Dcur[(size_t)b * HW + (size_t)yy * Ws + xx] * 0.1f;
#pragma unroll
                            for (int j = 0; j < 3; j++)
                                dsum[j] = fmaf(wc[(size_t)(j * 65 + 64) * 9 + t], dv, dsum[j]);
                        }
                    }
                    float rr[3] = {r0, r1, r2};
#pragma unroll
                    for (int j = 0; j < 3; j++) {
                        float z = acc[1][cg][j] + dsum[j];
                        float kp = 0.1f + 0.9f / (1.f + expf(-z));
                        sk[((size_t)(b * 3 + j)) * HW + pix] = rr[j] * kp;
                    }
                }
            }
        }
    }
}

// ---------------- one CSPN propagation step ----------------
__global__ __launch_bounds__(256) void prop_k(const float* __restrict__ D,
        const unsigned short* __restrict__ A, const float* __restrict__ cen,
        const float* __restrict__ sk, const float* __restrict__ dlm,
        float* __restrict__ Dn, int Hs, int Ws) {
    int gid = blockIdx.x * 256 + threadIdx.x;
    int HW = Hs * Ws;
    if (gid >= BN * HW) return;
    int b = gid / HW;
    int p = gid - b * HW;
    int y = p / Ws;
    int x = p - y * Ws;
    const float* Db = D + (size_t)b * HW;
    float Dc = Db[p];
    const int dy_[8] = {-1, -1, -1, 0, 0, 1, 1, 1};
    const int dx_[8] = {-1, 0, 1, -1, 1, -1, 0, 1};
    float mix = Dc;
#pragma unroll
    for (int k = 0; k < 3; k++) {
        int d = 1 << k;
        float s = cen[(size_t)(b * 3 + k) * HW + p] * Dc;
#pragma unroll
        for (int j = 0; j < 8; j++) {
            int yy = y + dy_[j] * d;
            int xx = x + dx_[j] * d;
            float nb = ((unsigned)yy < (unsigned)Hs && (unsigned)xx < (unsigned)Ws)
                           ? Db[(size_t)yy * Ws + xx] : 0.f;
            s = fmaf(bf2f(A[(size_t)(b * 24 + k * 8 + j) * HW + p]), nb, s);
        }
        mix += sk[(size_t)(b * 3 + k) * HW + p] * (s - Dc);
    }
    float v = dlm[(size_t)b * HW + p];
    float ml = v >= 0.f ? 1.f : 0.f;
    float dl = v >= 0.f ? v : 0.f;
    Dn[(size_t)b * HW + p] = ml * (0.9f * dl + 0.1f * mix) + (1.f - ml) * mix;
}

extern "C" void kernel_launch(void* const* d_in, const int* in_sizes, int n_in,
                              void* d_out, int out_size, void* d_ws, size_t ws_size,
                              hipStream_t stream) {
    const float* I  = (const float*)d_in[0];
    const float* DL = (const float*)d_in[1];
    const float* ML = (const float*)d_in[2];
    const float* E  = (const float*)d_in[3];
    const float* w0 = (const float*)d_in[4];  const float* b0 = (const float*)d_in[5];
    const float* w1 = (const float*)d_in[6];  const float* b1 = (const float*)d_in[7];
    const float* w2 = (const float*)d_in[8];  const float* b2 = (const float*)d_in[9];
    const float* wa = (const float*)d_in[10]; const float* ba = (const float*)d_in[11];
    const float* wg = (const float*)d_in[12]; const float* bg = (const float*)d_in[13];
    const float* wc = (const float*)d_in[14]; const float* bc = (const float*)d_in[15];

    size_t off = 0;
    auto carve = [&](size_t bytes) -> void* {
        void* pp = (char*)d_ws + off;
        off = (off + bytes + 255) & ~(size_t)255;
        return pp;
    };
    bf16*  Abuf  = (bf16*)carve((size_t)BN * 24 * HW1 * 2);
    float* cen   = (float*)carve((size_t)BN * 3 * HW1 * 4);
    float* sk    = (float*)carve((size_t)BN * 3 * HW1 * 4);
    float* dlm   = (float*)carve((size_t)BN * HW1 * 4);
    float* Ebuf  = (float*)carve((size_t)BN * HW1 * 4);
    float* D0    = (float*)carve((size_t)BN * HW1 * 4);
    float* D1    = (float*)carve((size_t)BN * HW1 * 4);
    float* Dprev = (float*)carve((size_t)BN * HW1 * 4);
    size_t padElems = (size_t)BN * (H0 + 6) * (W0 + 2) * 64;
    short* padA = (short*)carve(padElems * 2 + 65536);
    short* padB = (short*)carve(padElems * 2 + 65536);
    short* xpad = (short*)carve((size_t)BN * (H0 + 6) * (W0 + 2) * 8 * 2 + 65536);
    short* WB1  = (short*)carve((size_t)18 * 2 * 4 * 512 * 2);
    short* WB2  = (short*)carve((size_t)18 * 2 * 4 * 512 * 2);
    short* WBh  = (short*)carve((size_t)18 * 2 * 2 * 512 * 2);
    short* WB0  = (short*)carve((size_t)3 * 2 * 4 * 512 * 2);
    float* hb   = (float*)carve(32 * 4);
    if (off > ws_size) return;

    wtr2_k<<<(18 * 2 * 4 * 512 + 255) / 256, 256, 0, stream>>>(w1, WB1);
    wtr2_k<<<(18 * 2 * 4 * 512 + 255) / 256, 256, 0, stream>>>(w2, WB2);
    whb_k<<<(18 * 2 * 2 * 512 + 255) / 256, 256, 0, stream>>>(wa, wg, wc, WBh);
    wtr0_k<<<(3 * 2 * 4 * 512 + 255) / 256, 256, 0, stream>>>(w0, WB0);
    hbias_k<<<1, 32, 0, stream>>>(ba, bg, bc, hb);

    const int scales[3] = {4, 2, 1};
    for (int si = 0; si < 3; si++) {
        int s = scales[si];
        int Hs = H0 / s, Ws = W0 / s, HW = Hs * Ws;
        int pw = Ws + 2;
        int nbp = (BN * HW + 255) / 256;
        int nprep = (BN * (Hs + 2) * pw + 255) / 256;

        if (s == 4)      prep_k<4><<<nprep, 256, 0, stream>>>(I, DL, ML, E, xpad, Ebuf, dlm, Hs, Ws);
        else if (s == 2) prep_k<2><<<nprep, 256, 0, stream>>>(I, DL, ML, E, xpad, Ebuf, dlm, Hs, Ws);
        else             prep_k<1><<<nprep, 256, 0, stream>>>(I, DL, ML, E, xpad, Ebuf, dlm, Hs, Ws);

        if (si == 0)
            dinit_first_k<<<nbp, 256, 0, stream>>>(Ebuf, D0, Hs, Ws);
        else
            dinit_blend_k<<<nbp, 256, 0, stream>>>(Dprev, Ebuf, D0, Hs, Ws);

        int nhalo = (4 * (2 * pw + 2 * Hs) + 255) / 256;
        halo0_k<<<nhalo, 256, 0, stream>>>(padA, padB, Hs, Ws);

        int tX = (Ws + 63) / 64;
        int tY = Hs / 4;
        dim3 gmm(tX * tY, BN);
        conv0mm_k<<<gmm, 256, 0, stream>>>(xpad, WB0, b0, padA, Hs, Ws, tX);
        convmm_k<4, 0><<<gmm, 256, 0, stream>>>(padA, WB1, b1, padB,
            nullptr, nullptr, nullptr, nullptr, nullptr, Hs, Ws, tX);
        convmm_k<4, 0><<<gmm, 256, 0, stream>>>(padB, WB2, b2, padA,
            nullptr, nullptr, nullptr, nullptr, nullptr, Hs, Ws, tX);
        convmm_k<2, 1><<<gmm, 256, 0, stream>>>(padA, WBh, hb, nullptr,
            Abuf, cen, sk, D0, wc, Hs, Ws, tX);

        float* Dc = D0;
        float* Dn = D1;
        float* fin = (si < 2) ? Dprev : (float*)d_out;
        for (int t = 0; t < 6; t++) {
            float* tgt = (t == 5) ? fin : Dn;
            prop_k<<<nbp, 256, 0, stream>>>(Dc, (const unsigned short*)Abuf, cen, sk,
                                            dlm, tgt, Hs, Ws);
            if (t < 5) { float* tmp = Dc; Dc = Dn; Dn = tmp; }
        }
    }
}

// Round 8
// 708.376 us; speedup vs baseline: 7.7973x; 1.0616x over previous
//
#include <hip/hip_runtime.h>
#include <hip/hip_bf16.h>

typedef __attribute__((ext_vector_type(8))) short short8v;
typedef __attribute__((ext_vector_type(8))) _Float16 half8v;
typedef __attribute__((ext_vector_type(4))) float f32x4;

static constexpr int BN = 2;
static constexpr int H0 = 480, W0 = 640;
static constexpr int HW1 = H0 * W0;

__device__ __forceinline__ short f2h(float f) {
    _Float16 h = (_Float16)f;
    short s; __builtin_memcpy(&s, &h, 2); return s;
}
__device__ __forceinline__ float h2f(short s) {
    _Float16 h; __builtin_memcpy(&h, &s, 2); return (float)h;
}

// ---------------- MFMA weight transform (64->64) fp16 ----------------
// WB flat: ((tap*2+ks)*4+n)*512 + lane*8 + i    (NF=4)
__global__ void wtr2_k(const float* __restrict__ w, short* __restrict__ WB) {
    int gid = blockIdx.x * 256 + threadIdx.x;
    if (gid >= 18 * 4 * 512) return;
    int ie = gid & 7;
    int l  = (gid >> 3) & 63;
    int n  = (gid >> 9) & 3;
    int t2 = gid >> 11;            // 0..17
    int tap = t2 >> 1, ks = t2 & 1;
    int o = 16 * n + (l & 15);
    int c = 32 * ks + (l >> 4) * 8 + ie;
    WB[gid] = f2h(w[(size_t)(o * 64 + c) * 9 + tap]);
}

// ---------------- conv0 MFMA weight transform (6ch+9tap -> K-slots) fp16 ----------------
__global__ void wtr0_k(const float* __restrict__ w, short* __restrict__ WB) {
    int gid = blockIdx.x * 256 + threadIdx.x;
    if (gid >= 3 * 4 * 512) return;
    int ie = gid & 7;
    int l  = (gid >> 3) & 63;
    int n  = (gid >> 9) & 3;
    int j  = gid >> 11;            // 0..2
    int o = 16 * n + (l & 15);
    int g = l >> 4;
    int tap = 4 * j + g;
    float wv = (tap < 9 && ie < 6) ? w[(size_t)(o * 6 + ie) * 9 + tap] : 0.f;
    WB[gid] = f2h(wv);
}

// ---------------- head weight transform (aff24+gate3+curv3 -> 32ch) fp16 ----------------
__global__ void whb_k(const float* __restrict__ wa, const float* __restrict__ wg,
                      const float* __restrict__ wc, short* __restrict__ WB) {
    int gid = blockIdx.x * 256 + threadIdx.x;
    if (gid >= 18 * 2 * 512) return;
    int ie = gid & 7;
    int l  = (gid >> 3) & 63;
    int n  = (gid >> 9) & 1;
    int t2 = gid >> 10;            // 0..17
    int tap = t2 >> 1, ks = t2 & 1;
    int o = 16 * n + (l & 15);     // 0..31
    int c = 32 * ks + (l >> 4) * 8 + ie;
    float wv = 0.f;
    if (o < 24)                 wv = wa[(size_t)(o * 64 + c) * 9 + tap];
    else if (o >= 24 && o < 27) wv = wg[(size_t)((o - 24) * 64 + c) * 9 + tap];
    else if (o >= 28 && o < 31) wv = wc[(size_t)((o - 28) * 65 + c) * 9 + tap];
    WB[gid] = f2h(wv);
}

__global__ void hbias_k(const float* __restrict__ ba, const float* __restrict__ bg,
                        const float* __restrict__ bc, float* __restrict__ hb) {
    int o = threadIdx.x;
    if (o >= 32) return;
    float v = 0.f;
    if (o < 24) v = ba[o];
    else if (o < 27) v = bg[o - 24];
    else if (o >= 28 && o < 31) v = bc[o - 28];
    hb[o] = v;
}

// ---------------- fused per-scale prep: resize I(3) + resize E + down_sparse ----------------
template <int F>
__global__ void prep_k(const float* __restrict__ I, const float* __restrict__ DL,
                       const float* __restrict__ ML, const float* __restrict__ E,
                       short* __restrict__ Xp, float* __restrict__ Ebuf,
                       float* __restrict__ dlm, int Hs, int Ws) {
    const int pw = Ws + 2;
    int gid = blockIdx.x * 256 + threadIdx.x;
    int total = BN * (Hs + 2) * pw;
    if (gid >= total) return;
    int xp = gid % pw;
    int yp = (gid / pw) % (Hs + 2);
    int b = gid / (pw * (Hs + 2));
    short8v v = {0, 0, 0, 0, 0, 0, 0, 0};
    if (yp >= 1 && yp <= Hs && xp >= 1 && xp <= Ws) {
        int oy = yp - 1, ox = xp - 1;
        constexpr int NT = 2 * F;
        float wy[NT], wx[NT];
        float sy = (oy + 0.5f) * F - 0.5f;
        int jly = F * oy - (F + 1) / 2;
        float wys = 0.f;
#pragma unroll
        for (int t = 0; t < NT; t++) {
            int j = jly + t;
            float w = fmaxf(1.f - fabsf(sy - (float)j) / (float)F, 0.f);
            if (j < 0 || j >= H0) w = 0.f;
            wy[t] = w; wys += w;
        }
        float sx = (ox + 0.5f) * F - 0.5f;
        int jlx = F * ox - (F + 1) / 2;
        float wxs = 0.f;
#pragma unroll
        for (int t = 0; t < NT; t++) {
            int j = jlx + t;
            float w = fmaxf(1.f - fabsf(sx - (float)j) / (float)F, 0.f);
            if (j < 0 || j >= W0) w = 0.f;
            wx[t] = w; wxs += w;
        }
        float inv = 1.f / (wys * wxs);
#pragma unroll
        for (int c = 0; c < 3; c++) {
            const float* ip = I + (size_t)(b * 3 + c) * HW1;
            float acc = 0.f;
#pragma unroll
            for (int ty = 0; ty < NT; ty++) {
                if (wy[ty] == 0.f) continue;
                const float* row = ip + (size_t)(jly + ty) * W0;
                float r = 0.f;
#pragma unroll
                for (int tx = 0; tx < NT; tx++)
                    if (wx[tx] != 0.f) r += wx[tx] * row[jlx + tx];
                acc += wy[ty] * r;
            }
            v[c] = f2h(acc * inv);
        }
        {
            const float* ip = E + (size_t)b * HW1;
            float acc = 0.f;
#pragma unroll
            for (int ty = 0; ty < NT; ty++) {
                if (wy[ty] == 0.f) continue;
                const float* row = ip + (size_t)(jly + ty) * W0;
                float r = 0.f;
#pragma unroll
                for (int tx = 0; tx < NT; tx++)
                    if (wx[tx] != 0.f) r += wx[tx] * row[jlx + tx];
                acc += wy[ty] * r;
            }
            acc = fminf(fmaxf(acc * inv, 0.f), 1.f);
            v[5] = f2h(acc);
            Ebuf[(size_t)b * Hs * Ws + oy * Ws + ox] = acc;
        }
        {
            float s = 0.f, c = 0.f;
#pragma unroll
            for (int dy = 0; dy < F; dy++)
#pragma unroll
                for (int dx = 0; dx < F; dx++) {
                    size_t idx = ((size_t)b * H0 + (oy * F + dy)) * W0 + (ox * F + dx);
                    float m = ML[idx] > 0.f ? 1.f : 0.f;
                    s += DL[idx] * m;
                    c += m;
                }
            float dls = c > 0.f ? s / (c + 1e-6f) : 0.f;
            v[3] = f2h(dls);
            v[4] = f2h(c > 0.f ? 1.f : 0.f);
            dlm[(size_t)b * Hs * Ws + oy * Ws + ox] = c > 0.f ? dls : -1.f;
        }
    }
    *(short8v*)(Xp + (((size_t)b * (Hs + 6) + 2 + yp) * pw + xp) * 8) = v;
}

// ---------------- D init, first scale ----------------
__global__ void dinit_first_k(const float* __restrict__ Ebuf, float* __restrict__ D0,
                              int Hs, int Ws) {
    int gid = blockIdx.x * 256 + threadIdx.x;
    int HW = Hs * Ws;
    if (gid >= BN * HW) return;
    float e = Ebuf[gid];
    D0[gid] = fminf(fmaxf(e * 10.f, 0.f), 10.f);
}

// ---------------- D init, later scales ----------------
__global__ void dinit_blend_k(const float* __restrict__ Dp, const float* __restrict__ Ebuf,
                              float* __restrict__ D0, int Hs, int Ws) {
    int gid = blockIdx.x * 256 + threadIdx.x;
    int HW = Hs * Ws;
    if (gid >= BN * HW) return;
    int ox = gid % Ws;
    int oy = (gid / Ws) % Hs;
    int b = gid / HW;
    int hp = Hs / 2, wp = Ws / 2;
    const float* P = Dp + (size_t)b * hp * wp;

    float ty = 0.5f * oy - 0.25f;
    int jy = (int)floorf(ty);
    float fy = ty - jy;
    float wy0 = 1.f - fy, wy1 = fy;
    bool v0 = (jy >= 0) && (jy < hp);
    bool v1 = (jy + 1 >= 0) && (jy + 1 < hp);
    if (!v0) wy0 = 0.f;
    if (!v1) wy1 = 0.f;
    float wys = wy0 + wy1;

    float tx = 0.5f * ox - 0.25f;
    int jx = (int)floorf(tx);
    float fx = tx - jx;
    float wx0 = 1.f - fx, wx1 = fx;
    bool u0 = (jx >= 0) && (jx < wp);
    bool u1 = (jx + 1 >= 0) && (jx + 1 < wp);
    if (!u0) wx0 = 0.f;
    if (!u1) wx1 = 0.f;
    float wxs = wx0 + wx1;

    int jy0c = v0 ? jy : 0, jy1c = v1 ? (jy + 1) : 0;
    int jx0c = u0 ? jx : 0, jx1c = u1 ? (jx + 1) : 0;
    float up = wy0 * (wx0 * P[(size_t)jy0c * wp + jx0c] + wx1 * P[(size_t)jy0c * wp + jx1c])
             + wy1 * (wx0 * P[(size_t)jy1c * wp + jx0c] + wx1 * P[(size_t)jy1c * wp + jx1c]);
    up /= (wys * wxs);

    const float* Eb = Ebuf + (size_t)b * HW;
    float e = Eb[(size_t)oy * Ws + ox];
    float gx = (ox > 0) ? fabsf(e - Eb[(size_t)oy * Ws + ox - 1]) : 0.f;
    float gy = (oy > 0) ? fabsf(e - Eb[(size_t)(oy - 1) * Ws + ox]) : 0.f;
    float g = fminf(fmaxf(0.5f * (gx + gy), 0.f), 1.f);
    float w = 0.7f * fminf(fmaxf(1.f - g * 10.f, 0.f), 1.f);
    float Pv = fminf(fmaxf(e * 10.f, 0.f), 10.f);
    D0[gid] = w * up + (1.f - w) * Pv;
}

// ---------------- zero halos of both padded feature buffers ----------------
__global__ void halo0_k(short* __restrict__ A, short* __restrict__ B2, int Hs, int Ws) {
    int pw = Ws + 2;
    int ne = 2 * pw + 2 * Hs;
    int total = 4 * ne;
    int gid = blockIdx.x * 256 + threadIdx.x;
    if (gid >= total) return;
    int e = gid % ne;
    int t = gid / ne;
    int b = t & 1;
    int buf = t >> 1;
    int yp, xp;
    if (e < pw)            { yp = 0;      xp = e; }
    else if (e < 2 * pw)   { yp = Hs + 1; xp = e - pw; }
    else { int e2 = e - 2 * pw; yp = 1 + (e2 >> 1); xp = (e2 & 1) ? (Ws + 1) : 0; }
    short* p = (buf ? B2 : A) + (((size_t)b * (Hs + 6) + 2 + yp) * pw + xp) * 64;
    short8v z = {0, 0, 0, 0, 0, 0, 0, 0};
#pragma unroll
    for (int j = 0; j < 8; j++) *(short8v*)(p + j * 8) = z;
}

// bijective XCD-chunked swizzle (m204)
__device__ __forceinline__ int xcd_swz(int orig, int nwg) {
    int q = nwg >> 3, r = nwg & 7;
    int xcd = orig & 7, idx = orig >> 3;
    return (xcd < r ? xcd * (q + 1) : r * (q + 1) + (xcd - r) * q) + idx;
}

// ---------------- conv0: 6->64 MFMA implicit GEMM fp16 (K padded to 96) ----------------
__global__ __launch_bounds__(256, 3) void conv0mm_k(
        const short* __restrict__ Xp, const short* __restrict__ WB,
        const float* __restrict__ bias, short* __restrict__ Y,
        int Hs, int Ws, int tX) {
    const int pw = Ws + 2;
    const int lane = threadIdx.x & 63;
    const int wv = threadIdx.x >> 6;
    const int b = blockIdx.y;
    const int l15 = lane & 15;
    const int g = lane >> 4;
    int wg = xcd_swz(blockIdx.x, gridDim.x);
    int ty = wg / tX, txi = wg - ty * tX;
    const int y = ty * 4 + wv;
    const int x0 = txi * 64;

    const size_t bbase8 = ((size_t)b * (Hs + 6) + 2) * pw * 8;
    const short* Xb = Xp + bbase8;

    f32x4 acc[4][4];
#pragma unroll
    for (int n = 0; n < 4; n++) {
        f32x4 bv;
#pragma unroll
        for (int j = 0; j < 4; j++) bv[j] = bias[16 * n + g * 4 + j];
#pragma unroll
        for (int cg = 0; cg < 4; cg++) acc[n][cg] = bv;
    }

    int vb[4];
#pragma unroll
    for (int cg = 0; cg < 4; cg++)
        vb[cg] = ((y + 1) * pw + (x0 + cg * 16 + l15 + 1)) * 8;

#pragma unroll
    for (int j = 0; j < 3; j++) {
        int tap = 4 * j + g;
        if (tap > 8) tap = 8;
        int toff = ((tap / 3 - 1) * pw + (tap % 3 - 1)) * 8;
        half8v bx[4];
#pragma unroll
        for (int cg = 0; cg < 4; cg++)
            bx[cg] = *(const half8v*)(Xb + vb[cg] + toff);
        const short* wp = WB + (size_t)j * (4 * 512) + lane * 8;
#pragma unroll
        for (int n = 0; n < 4; n++) {
            half8v av = *(const half8v*)(wp + n * 512);
#pragma unroll
            for (int cg = 0; cg < 4; cg++)
                acc[n][cg] = __builtin_amdgcn_mfma_f32_16x16x32_f16(
                    av, bx[cg], acc[n][cg], 0, 0, 0);
        }
    }

    const size_t bbase = ((size_t)b * (Hs + 6) + 2) * pw * 64;
#pragma unroll
    for (int cg = 0; cg < 4; cg++) {
        int x = x0 + cg * 16 + l15;
        if (x >= Ws) continue;
        short* out = Y + bbase + ((size_t)(y + 1) * pw + (x + 1)) * 64 + g * 4;
#pragma unroll
        for (int n = 0; n < 4; n++) {
            ushort4 v;
            v.x = (unsigned short)f2h(fmaxf(acc[n][cg][0], 0.f));
            v.y = (unsigned short)f2h(fmaxf(acc[n][cg][1], 0.f));
            v.z = (unsigned short)f2h(fmaxf(acc[n][cg][2], 0.f));
            v.w = (unsigned short)f2h(fmaxf(acc[n][cg][3], 0.f));
            *(ushort4*)(out + 16 * n) = v;
        }
    }
}

// ---------------- MFMA implicit-GEMM 3x3 conv fp16, LDS weights + full-tap B prefetch ----------------
// block = 4 waves; wave = 1 output row x 64 px.
// Weights (fp16, single) double-buffered in LDS (issue-early/write-late, 1 barrier/tap).
// B fragments register double-buffered with a FULL TAP of lead time.
template <int NF, int EPI>
__global__ __launch_bounds__(256, 2) void convmm_k(
        const short* __restrict__ X, const short* __restrict__ WB,
        const float* __restrict__ bias, short* __restrict__ Y,
        short* __restrict__ Aout, short* __restrict__ cen,
        short* __restrict__ sk,
        const float* __restrict__ Dcur, const float* __restrict__ wc,
        int Hs, int Ws, int tX) {
    const int pw = Ws + 2;
    const int lane = threadIdx.x & 63;
    const int wv = threadIdx.x >> 6;
    const int b = blockIdx.y;
    const int l15 = lane & 15;
    const int g = lane >> 4;
    int wg = xcd_swz(blockIdx.x, gridDim.x);
    int ty = wg / tX, txi = wg - ty * tX;
    const int y = ty * 4 + wv;
    const int x0 = txi * 64;

    const size_t bbase = ((size_t)b * (Hs + 6) + 2) * pw * 64;
    const short* Xb = X + bbase;

    constexpr int TAPSZ = 2 * NF * 512;        // shorts per tap (2ks x NF x 512)
    constexpr int FPW = (2 * NF) / 4;          // fragments staged per wave per tap
    __shared__ __attribute__((aligned(16))) short WL[2][TAPSZ];

    f32x4 acc[NF][4];
#pragma unroll
    for (int n = 0; n < NF; n++) {
        f32x4 bv;
#pragma unroll
        for (int j = 0; j < 4; j++) bv[j] = bias[16 * n + g * 4 + j];
#pragma unroll
        for (int cg = 0; cg < 4; cg++) acc[n][cg] = bv;
    }

    int vb[4];
#pragma unroll
    for (int cg = 0; cg < 4; cg++)
        vb[cg] = ((y + 1) * pw + (x0 + cg * 16 + l15 + 1)) * 64 + g * 8;

    half8v bxA[8], bxB[8];
    auto LDB = [&](half8v* bx, int tap) {
        const int toff = ((tap / 3 - 1) * pw + (tap % 3 - 1)) * 64;
#pragma unroll
        for (int ks = 0; ks < 2; ks++)
#pragma unroll
            for (int cg = 0; cg < 4; cg++)
                bx[ks * 4 + cg] = *(const half8v*)(Xb + vb[cg] + toff + ks * 32);
    };

    // prologue: B for tap 0 + weights tap 0 into WL[0]
    LDB(bxA, 0);
    {
        const short* src = WB + (size_t)(wv * FPW) * 512 + lane * 8;
        short* dst = &WL[0][(wv * FPW) * 512 + lane * 8];
#pragma unroll
        for (int r = 0; r < FPW; r++)
            *(short8v*)(dst + r * 512) = *(const short8v*)(src + r * 512);
    }
    __syncthreads();

#pragma unroll
    for (int tap = 0; tap < 9; tap++) {
        const int cur = tap & 1;
        half8v* bcur = cur ? bxB : bxA;
        half8v* bnxt = cur ? bxA : bxB;
        // prefetch next tap's B fragments (full tap of lead)
        if (tap < 8) LDB(bnxt, tap + 1);
        // issue staging loads for next tap's weights (write to LDS after MFMAs)
        short8v stg[FPW];
        if (tap < 8) {
            const short* src = WB + (size_t)(tap + 1) * TAPSZ + (wv * FPW) * 512 + lane * 8;
#pragma unroll
            for (int r = 0; r < FPW; r++)
                stg[r] = *(const short8v*)(src + r * 512);
        }
        // compute: weights from LDS
#pragma unroll
        for (int ks = 0; ks < 2; ks++) {
            half8v wf[NF];
#pragma unroll
            for (int n = 0; n < NF; n++)
                wf[n] = *(const half8v*)(&WL[cur][(ks * NF + n) * 512 + lane * 8]);
#pragma unroll
            for (int n = 0; n < NF; n++)
#pragma unroll
                for (int cg = 0; cg < 4; cg++)
                    acc[n][cg] = __builtin_amdgcn_mfma_f32_16x16x32_f16(
                        wf[n], bcur[ks * 4 + cg], acc[n][cg], 0, 0, 0);
        }
        // write-late staging + single barrier per tap
        if (tap < 8) {
            short* dst = &WL[cur ^ 1][(wv * FPW) * 512 + lane * 8];
#pragma unroll
            for (int r = 0; r < FPW; r++)
                *(short8v*)(dst + r * 512) = stg[r];
        }
        __syncthreads();
    }

    const int HW = Hs * Ws;
#pragma unroll
    for (int cg = 0; cg < 4; cg++) {
        int x = x0 + cg * 16 + l15;
        bool ok = (x < Ws);
        if (EPI == 0) {
            if (!ok) continue;
            short* out = Y + bbase + ((size_t)(y + 1) * pw + (x + 1)) * 64 + g * 4;
#pragma unroll
            for (int n = 0; n < NF; n++) {
                ushort4 v;
                v.x = (unsigned short)f2h(fmaxf(acc[n][cg][0], 0.f));
                v.y = (unsigned short)f2h(fmaxf(acc[n][cg][1], 0.f));
                v.z = (unsigned short)f2h(fmaxf(acc[n][cg][2], 0.f));
                v.w = (unsigned short)f2h(fmaxf(acc[n][cg][3], 0.f));
                *(ushort4*)(out + 16 * n) = v;
            }
        } else {
            // --- head epilogue ---
            float t0 = fabsf(acc[0][cg][0]) + fabsf(acc[0][cg][1]) +
                       fabsf(acc[0][cg][2]) + fabsf(acc[0][cg][3]);
            float s0 = t0 + __shfl_xor(t0, 16, 64);
            float t1 = fabsf(acc[1][cg][0]) + fabsf(acc[1][cg][1]) +
                       fabsf(acc[1][cg][2]) + fabsf(acc[1][cg][3]);
            float s1 = t1 + __shfl_xor(t1, 16, 64);
            float inv0 = 1.f / (s0 + 1e-6f);
            float inv1 = 1.f / (s1 + 1e-6f);
            float a0[4], a1[4];
#pragma unroll
            for (int j = 0; j < 4; j++) { a0[j] = acc[0][cg][j] * inv0; a1[j] = acc[1][cg][j] * inv1; }
            float p0 = a0[0] + a0[1] + a0[2] + a0[3];
            float c0 = p0 + __shfl_xor(p0, 16, 64);
            float p1 = a1[0] + a1[1] + a1[2] + a1[3];
            float c1 = p1 + __shfl_xor(p1, 16, 64);

            float e0 = acc[1][cg][0], e1 = acc[1][cg][1], e2 = acc[1][cg][2];
            float m = fmaxf(e0, fmaxf(e1, e2));
            float q0 = expf(e0 - m), q1 = expf(e1 - m), q2 = expf(e2 - m);
            float qs = 1.f / (q0 + q1 + q2);
            float sg0 = q0 * qs, sg1 = q1 * qs, sg2 = q2 * qs;
            float r0 = __shfl_xor(sg0, 16, 64);
            float r1 = __shfl_xor(sg1, 16, 64);
            float r2 = __shfl_xor(sg2, 16, 64);

            int pix = y * Ws + x;
            if (ok) {
#pragma unroll
                for (int j = 0; j < 4; j++) {
                    int ch = g * 4 + j;
                    Aout[((size_t)(b * 24 + ch)) * HW + pix] = f2h(a0[j]);
                }
                if (g < 2) {
#pragma unroll
                    for (int j = 0; j < 4; j++) {
                        int ch = 16 + g * 4 + j;
                        Aout[((size_t)(b * 24 + ch)) * HW + pix] = f2h(a1[j]);
                    }
                }
                if (g == 0) {
                    cen[((size_t)(b * 3 + 0)) * HW + pix] = f2h(1.f - c0);
                    cen[((size_t)(b * 3 + 2)) * HW + pix] = f2h(1.f - c1);
                }
                if (g == 2) {
                    cen[((size_t)(b * 3 + 1)) * HW + pix] = f2h(1.f - c0);
                }
                if (g == 3) {
                    float dsum[3] = {0.f, 0.f, 0.f};
#pragma unroll
                    for (int t = 0; t < 9; t++) {
                        int yy = y + t / 3 - 1;
                        int xx = x + t % 3 - 1;
                        if ((unsigned)yy < (unsigned)Hs && (unsigned)xx < (unsigned)Ws) {
                            float dv = Dcur[(size_t)b * HW + (size_t)yy * Ws + xx] * 0.1f;
#pragma unroll
                            for (int j = 0; j < 3; j++)
                                dsum[j] = fmaf(wc[(size_t)(j * 65 + 64) * 9 + t], dv, dsum[j]);
                        }
                    }
                    float rr[3] = {r0, r1, r2};
#pragma unroll
                    for (int j = 0; j < 3; j++) {
                        float z = acc[1][cg][j] + dsum[j];
                        float kp = 0.1f + 0.9f / (1.f + expf(-z));
                        sk[((size_t)(b * 3 + j)) * HW + pix] = f2h(rr[j] * kp);
                    }
                }
            }
        }
    }
}

// ---------------- one CSPN propagation step (A/cen/sk in fp16) ----------------
__global__ __launch_bounds__(256) void prop_k(const float* __restrict__ D,
        const short* __restrict__ A, const short* __restrict__ cen,
        const short* __restrict__ sk, const float* __restrict__ dlm,
        float* __restrict__ Dn, int Hs, int Ws) {
    int gid = blockIdx.x * 256 + threadIdx.x;
    int HW = Hs * Ws;
    if (gid >= BN * HW) return;
    int b = gid / HW;
    int p = gid - b * HW;
    int y = p / Ws;
    int x = p - y * Ws;
    const float* Db = D + (size_t)b * HW;
    float Dc = Db[p];
    const int dy_[8] = {-1, -1, -1, 0, 0, 1, 1, 1};
    const int dx_[8] = {-1, 0, 1, -1, 1, -1, 0, 1};
    float mix = Dc;
#pragma unroll
    for (int k = 0; k < 3; k++) {
        int d = 1 << k;
        float s = h2f(cen[(size_t)(b * 3 + k) * HW + p]) * Dc;
#pragma unroll
        for (int j = 0; j < 8; j++) {
            int yy = y + dy_[j] * d;
            int xx = x + dx_[j] * d;
            float nb = ((unsigned)yy < (unsigned)Hs && (unsigned)xx < (unsigned)Ws)
                           ? Db[(size_t)yy * Ws + xx] : 0.f;
            s = fmaf(h2f(A[(size_t)(b * 24 + k * 8 + j) * HW + p]), nb, s);
        }
        mix += h2f(sk[(size_t)(b * 3 + k) * HW + p]) * (s - Dc);
    }
    float v = dlm[(size_t)b * HW + p];
    float ml = v >= 0.f ? 1.f : 0.f;
    float dl = v >= 0.f ? v : 0.f;
    Dn[(size_t)b * HW + p] = ml * (0.9f * dl + 0.1f * mix) + (1.f - ml) * mix;
}

extern "C" void kernel_launch(void* const* d_in, const int* in_sizes, int n_in,
                              void* d_out, int out_size, void* d_ws, size_t ws_size,
                              hipStream_t stream) {
    const float* I  = (const float*)d_in[0];
    const float* DL = (const float*)d_in[1];
    const float* ML = (const float*)d_in[2];
    const float* E  = (const float*)d_in[3];
    const float* w0 = (const float*)d_in[4];  const float* b0 = (const float*)d_in[5];
    const float* w1 = (const float*)d_in[6];  const float* b1 = (const float*)d_in[7];
    const float* w2 = (const float*)d_in[8];  const float* b2 = (const float*)d_in[9];
    const float* wa = (const float*)d_in[10]; const float* ba = (const float*)d_in[11];
    const float* wg = (const float*)d_in[12]; const float* bg = (const float*)d_in[13];
    const float* wc = (const float*)d_in[14]; const float* bc = (const float*)d_in[15];

    size_t off = 0;
    auto carve = [&](size_t bytes) -> void* {
        void* pp = (char*)d_ws + off;
        off = (off + bytes + 255) & ~(size_t)255;
        return pp;
    };
    short* Abuf  = (short*)carve((size_t)BN * 24 * HW1 * 2);
    short* cen   = (short*)carve((size_t)BN * 3 * HW1 * 2);
    short* sk    = (short*)carve((size_t)BN * 3 * HW1 * 2);
    float* dlm   = (float*)carve((size_t)BN * HW1 * 4);
    float* Ebuf  = (float*)carve((size_t)BN * HW1 * 4);
    float* D0    = (float*)carve((size_t)BN * HW1 * 4);
    float* D1    = (float*)carve((size_t)BN * HW1 * 4);
    float* Dprev = (float*)carve((size_t)BN * HW1 * 4);
    size_t padElems = (size_t)BN * (H0 + 6) * (W0 + 2) * 64;
    short* padA = (short*)carve(padElems * 2 + 65536);
    short* padB = (short*)carve(padElems * 2 + 65536);
    short* xpad = (short*)carve((size_t)BN * (H0 + 6) * (W0 + 2) * 8 * 2 + 65536);
    short* WB1  = (short*)carve((size_t)18 * 4 * 512 * 2);
    short* WB2  = (short*)carve((size_t)18 * 4 * 512 * 2);
    short* WBh  = (short*)carve((size_t)18 * 2 * 512 * 2);
    short* WB0  = (short*)carve((size_t)3 * 4 * 512 * 2);
    float* hb   = (float*)carve(32 * 4);
    if (off > ws_size) return;

    wtr2_k<<<(18 * 4 * 512 + 255) / 256, 256, 0, stream>>>(w1, WB1);
    wtr2_k<<<(18 * 4 * 512 + 255) / 256, 256, 0, stream>>>(w2, WB2);
    whb_k<<<(18 * 2 * 512 + 255) / 256, 256, 0, stream>>>(wa, wg, wc, WBh);
    wtr0_k<<<(3 * 4 * 512 + 255) / 256, 256, 0, stream>>>(w0, WB0);
    hbias_k<<<1, 32, 0, stream>>>(ba, bg, bc, hb);

    const int scales[3] = {4, 2, 1};
    for (int si = 0; si < 3; si++) {
        int s = scales[si];
        int Hs = H0 / s, Ws = W0 / s, HW = Hs * Ws;
        int pw = Ws + 2;
        int nbp = (BN * HW + 255) / 256;
        int nprep = (BN * (Hs + 2) * pw + 255) / 256;

        if (s == 4)      prep_k<4><<<nprep, 256, 0, stream>>>(I, DL, ML, E, xpad, Ebuf, dlm, Hs, Ws);
        else if (s == 2) prep_k<2><<<nprep, 256, 0, stream>>>(I, DL, ML, E, xpad, Ebuf, dlm, Hs, Ws);
        else             prep_k<1><<<nprep, 256, 0, stream>>>(I, DL, ML, E, xpad, Ebuf, dlm, Hs, Ws);

        if (si == 0)
            dinit_first_k<<<nbp, 256, 0, stream>>>(Ebuf, D0, Hs, Ws);
        else
            dinit_blend_k<<<nbp, 256, 0, stream>>>(Dprev, Ebuf, D0, Hs, Ws);

        int nhalo = (4 * (2 * pw + 2 * Hs) + 255) / 256;
        halo0_k<<<nhalo, 256, 0, stream>>>(padA, padB, Hs, Ws);

        int tX = (Ws + 63) / 64;
        int tY = Hs / 4;
        dim3 gmm(tX * tY, BN);
        conv0mm_k<<<gmm, 256, 0, stream>>>(xpad, WB0, b0, padA, Hs, Ws, tX);
        convmm_k<4, 0><<<gmm, 256, 0, stream>>>(padA, WB1, b1, padB,
            nullptr, nullptr, nullptr, nullptr, nullptr, Hs, Ws, tX);
        convmm_k<4, 0><<<gmm, 256, 0, stream>>>(padB, WB2, b2, padA,
            nullptr, nullptr, nullptr, nullptr, nullptr, Hs, Ws, tX);
        convmm_k<2, 1><<<gmm, 256, 0, stream>>>(padA, WBh, hb, nullptr,
            Abuf, cen, sk, D0, wc, Hs, Ws, tX);

        float* Dc = D0;
        float* Dn = D1;
        float* fin = (si < 2) ? Dprev : (float*)d_out;
        for (int t = 0; t < 6; t++) {
            float* tgt = (t == 5) ? fin : Dn;
            prop_k<<<nbp, 256, 0, stream>>>(Dc, Abuf, cen, sk, dlm, tgt, Hs, Ws);
            if (t < 5) { float* tmp = Dc; Dc = Dn; Dn = tmp; }
        }
    }
}